// Round 2
// baseline (1160.374 us; speedup 1.0000x reference)
//
#include <hip/hip_runtime.h>
#include <math.h>

// Problem constants (match reference file)
#define NN 8000
#define EE 96000
#define HH 4
#define NBASIS 256
#define ECH 48
#define FFNH 128
#define CUTOFF_R 0.0792f
#define PI_F 3.14159265358979323846f
#define SPACING (CUTOFF_R/255.0f)
#define INV_STD (256.0f/CUTOFF_R)
#define MAXDEG 96
#define W1S 52   // padded LDS stride for W1 rows

typedef __bf16 bf16x8 __attribute__((ext_vector_type(8)));
typedef float  f32x4  __attribute__((ext_vector_type(4)));

__device__ __forceinline__ float silu_f(float x){ return x/(1.0f+expf(-x)); }

// ---------- fused weights: wsv = W_src@W_v, wdv = W_dst@W_v  (grid 32x256) ----------
__global__ void k_fusew(const float* __restrict__ Wsrc, const float* __restrict__ Wdst,
                        const float* __restrict__ Wv,
                        float* __restrict__ wsv, float* __restrict__ wdv){
  int gid = blockIdx.x*256 + threadIdx.x;
  int which = gid >> 12;
  int idx = gid & 4095;
  int r = idx >> 6, c = idx & 63;
  const float* A = which ? Wdst : Wsrc;
  float acc = 0.0f;
  #pragma unroll
  for (int k=0;k<64;k++) acc += A[r*64+k]*Wv[k*64+c];
  (which ? wdv : wsv)[idx] = acc;
}

// ---------- rms scale per node (grid NN x 256) ----------
__global__ void __launch_bounds__(256) k_rms(const float* __restrict__ x, float* __restrict__ rms1){
  int n = blockIdx.x;
  float4 v = ((const float4*)(x + (size_t)n*1024))[threadIdx.x];
  float ss = v.x*v.x+v.y*v.y+v.z*v.z+v.w*v.w;
  #pragma unroll
  for (int m=32;m>=1;m>>=1) ss += __shfl_xor(ss, m);
  __shared__ float red[4];
  if ((threadIdx.x & 63)==0) red[threadIdx.x>>6]=ss;
  __syncthreads();
  if (threadIdx.x==0)
    rms1[n] = 1.0f/sqrtf((red[0]+red[1]+red[2]+red[3])*(1.0f/1024.0f)+1e-6f);
}

// ---------- xs0[n,c], xd0[n,c] : l=0 row through W_src/W_dst (grid 2000x256) ----------
__global__ void __launch_bounds__(256) k_node0(const float* __restrict__ x, const float* __restrict__ rms1,
                        const float* __restrict__ Wsrc, const float* __restrict__ Wdst,
                        float* __restrict__ xs0, float* __restrict__ xd0){
  int t = blockIdx.x*256 + threadIdx.x;
  int n = t>>6, c = t&63;
  float sc = rms1[n];
  const float* xr = x + (size_t)n*1024;   // l = 0 row
  float as=0.0f, ad=0.0f;
  #pragma unroll 8
  for (int k=0;k<64;k++){
    float xv = xr[k]*sc;
    as += xv*Wsrc[k*64+c];
    ad += xv*Wdst[k*64+c];
  }
  xs0[t]=as; xd0[t]=ad;
}

// ---------- vs = xn@wsv, vd = xn@wdv over all rows N*L (grid 2000x256, 64 rows/block) ----------
__global__ void __launch_bounds__(256) k_node1(const float* __restrict__ x, const float* __restrict__ rms1,
                        const float* __restrict__ wsv, const float* __restrict__ wdv,
                        float* __restrict__ vs, float* __restrict__ vd){
  __shared__ float xt[64*65];
  __shared__ float wa[4096];
  __shared__ float wb[4096];
  int base = blockIdx.x*64;
  for (int i=threadIdx.x;i<4096;i+=256){
    int r = i>>6, k = i&63;
    int row = base + r;
    xt[r*65+k] = x[(size_t)row*64+k]*rms1[row>>4];
    wa[i] = wsv[i]; wb[i] = wdv[i];
  }
  __syncthreads();
  int r = threadIdx.x>>2, cg = threadIdx.x&3;
  float as[16], ad[16];
  #pragma unroll
  for (int j=0;j<16;j++){ as[j]=0.0f; ad[j]=0.0f; }
  for (int k=0;k<64;k++){
    float a = xt[r*65+k];
    const float* w1p = &wa[k*64+cg*16];
    const float* w2p = &wb[k*64+cg*16];
    #pragma unroll
    for (int j=0;j<16;j++){ as[j] += a*w1p[j]; ad[j] += a*w2p[j]; }
  }
  int row = base + r;
  float* vsp = vs + (size_t)row*64 + cg*16;
  float* vdp = vd + (size_t)row*64 + cg*16;
  #pragma unroll
  for (int j=0;j<16;j++){ vsp[j]=as[j]; vdp[j]=ad[j]; }
}

// ---------- edge RBF + 2-layer MLP -> e2[E,48] (grid 375x256) ----------
__global__ void __launch_bounds__(256) k_edgeA(const float* __restrict__ pos, const int* __restrict__ ei,
                        const float* __restrict__ W1, const float* __restrict__ b1,
                        const float* __restrict__ W2, const float* __restrict__ b2,
                        float* __restrict__ e2g){
  __shared__ float w1[NBASIS*W1S];
  __shared__ float w2[ECH*ECH];
  __shared__ float b1l[ECH], b2l[ECH];
  for (int i=threadIdx.x;i<NBASIS*ECH;i+=256){ int k=i/ECH, j=i-k*ECH; w1[k*W1S+j]=W1[i]; }
  for (int i=threadIdx.x;i<ECH*ECH;i+=256) w2[i]=W2[i];
  if (threadIdx.x<ECH){ b1l[threadIdx.x]=b1[threadIdx.x]; b2l[threadIdx.x]=b2[threadIdx.x]; }
  __syncthreads();
  int e = blockIdx.x*256 + threadIdx.x;   // grid exactly covers EE
  int s = ei[e], t = ei[EE+e];
  float dx = pos[3*s]-pos[3*t], dy = pos[3*s+1]-pos[3*t+1], dz = pos[3*s+2]-pos[3*t+2];
  float d = sqrtf(dx*dx+dy*dy+dz*dz+1e-12f);
  float acc[ECH];
  #pragma unroll
  for (int j=0;j<ECH;j++) acc[j]=b1l[j];
  if (d < CUTOFF_R){
    float env = 0.5f*(cosf(PI_F*(d/CUTOFF_R))+1.0f);
    int j0 = (int)floorf(d/SPACING);
    int klo = j0-9 > 0 ? j0-9 : 0;
    int khi = j0+10 < NBASIS-1 ? j0+10 : NBASIS-1;
    for (int k=klo;k<=khi;k++){
      float del = (d - k*SPACING)*INV_STD;
      float g = expf(-0.5f*del*del)*env;
      const float* wr = &w1[k*W1S];
      #pragma unroll
      for (int j=0;j<ECH;j++) acc[j] += g*wr[j];
    }
  }
  float e1[ECH];
  #pragma unroll
  for (int j=0;j<ECH;j++) e1[j] = silu_f(acc[j]);
  float* outp = e2g + (size_t)e*ECH;
  for (int j4=0;j4<ECH;j4+=4){
    float o[4];
    #pragma unroll
    for (int jj=0;jj<4;jj++){
      float a2 = b2l[j4+jj];
      #pragma unroll
      for (int k=0;k<ECH;k++) a2 += e1[k]*w2[k*ECH+j4+jj];
      o[jj] = silu_f(a2);
    }
    ((float4*)(outp+j4))[0] = make_float4(o[0],o[1],o[2],o[3]);
  }
}

// ---------- CSR build ----------
__global__ void k_hist(const int* __restrict__ ei, int* __restrict__ deg){
  int e = blockIdx.x*256 + threadIdx.x;
  atomicAdd(&deg[ei[EE+e]], 1);
}

__global__ void __launch_bounds__(1024) k_scan(const int* __restrict__ deg, int* __restrict__ off){
  __shared__ int sums[1024];
  int t = threadIdx.x;
  int base = t*8;
  int loc[8]; int s=0;
  #pragma unroll
  for (int i=0;i<8;i++){ int idx=base+i; int v = (idx<NN)? deg[idx]:0; loc[i]=v; s+=v; }
  sums[t]=s;
  __syncthreads();
  for (int d=1; d<1024; d<<=1){
    int v = (t>=d)? sums[t-d]:0;
    __syncthreads();
    sums[t] += v;
    __syncthreads();
  }
  int run = sums[t]-s;
  #pragma unroll
  for (int i=0;i<8;i++){ int idx=base+i; if (idx<NN) off[idx]=run; run+=loc[i]; }
  if (t==1023) off[NN]=sums[1023];
}

__global__ void k_fill(const int* __restrict__ ei, const int* __restrict__ off,
                       int* __restrict__ cursor, int* __restrict__ csr){
  int e = blockIdx.x*256 + threadIdx.x;
  int d = ei[EE+e];
  int slot = off[d] + atomicAdd(&cursor[d],1);
  csr[slot]=e;
}

// ---------- per-edge: e_c, s0, logits, v0 (grid 375x256) ----------
__global__ void __launch_bounds__(256) k_edgeB(const float* __restrict__ e2g, const int* __restrict__ ei,
                        const float* __restrict__ xs0, const float* __restrict__ xd0,
                        const float* __restrict__ W_edge, const float* __restrict__ W_alpha,
                        const float* __restrict__ v_alpha, const float* __restrict__ Wv,
                        float* __restrict__ logits_g, float* __restrict__ v0g){
  __shared__ float we[ECH*64];
  __shared__ float wv[4096];
  __shared__ float va[256];
  __shared__ float wab[64*68];   // transposed [j][k] chunk of W_alpha, padded stride 68
  for (int i=threadIdx.x;i<ECH*64;i+=256) we[i]=W_edge[i];
  for (int i=threadIdx.x;i<4096;i+=256) wv[i]=Wv[i];
  va[threadIdx.x]=v_alpha[threadIdx.x];
  __syncthreads();
  int e = blockIdx.x*256 + threadIdx.x;
  int s = ei[e], t = ei[EE+e];
  float e2r[ECH];
  {
    const float4* p = (const float4*)(e2g + (size_t)e*ECH);
    #pragma unroll
    for (int q=0;q<ECH/4;q++){
      float4 v4 = p[q];
      e2r[4*q+0]=v4.x; e2r[4*q+1]=v4.y; e2r[4*q+2]=v4.z; e2r[4*q+3]=v4.w;
    }
  }
  // s0 accumulates e_c first (static-index regs), then scaled by (xs0[src]+xd0[dst])
  float s0[64];
  #pragma unroll
  for (int c=0;c<64;c++) s0[c]=0.0f;
  for (int k=0;k<ECH;k++){
    float v = e2r[k];
    const float4* wr = (const float4*)&we[k*64];
    #pragma unroll
    for (int q=0;q<16;q++){
      float4 w4 = wr[q];
      s0[4*q+0] += v*w4.x; s0[4*q+1] += v*w4.y; s0[4*q+2] += v*w4.z; s0[4*q+3] += v*w4.w;
    }
  }
  {
    const float4* ps = (const float4*)(xs0 + (size_t)s*64);
    const float4* pd = (const float4*)(xd0 + (size_t)t*64);
    #pragma unroll
    for (int q=0;q<16;q++){
      float4 a4 = ps[q]; float4 b4 = pd[q];
      s0[4*q+0] *= (a4.x+b4.x);
      s0[4*q+1] *= (a4.y+b4.y);
      s0[4*q+2] *= (a4.z+b4.z);
      s0[4*q+3] *= (a4.w+b4.w);
    }
  }
  // logits: per head, stage transposed W_alpha chunk, dot + leaky_relu + v_alpha
  float lg[HH];
  for (int h=0;h<HH;h++){
    __syncthreads();
    for (int i=threadIdx.x;i<4096;i+=256){
      int k = i>>6, j = i&63;                  // read coalesced (consecutive j)
      wab[j*68+k] = W_alpha[k*256 + h*64 + j]; // store transposed
    }
    __syncthreads();
    float acc = 0.0f;
    for (int j=0;j<64;j++){
      const float4* wc = (const float4*)&wab[j*68];
      float tdot = 0.0f;
      #pragma unroll
      for (int q=0;q<16;q++){
        float4 w4 = wc[q];
        tdot += s0[4*q+0]*w4.x + s0[4*q+1]*w4.y + s0[4*q+2]*w4.z + s0[4*q+3]*w4.w;
      }
      acc += (tdot>0.0f ? tdot : 0.2f*tdot)*va[h*64+j];
    }
    lg[h]=acc;
  }
  ((float4*)(logits_g+(size_t)e*4))[0] = make_float4(lg[0],lg[1],lg[2],lg[3]);
  // v0 = s0 @ W_v
  float* vp = v0g + (size_t)e*64;
  for (int c=0;c<64;c+=4){
    float t0=0,t1=0,t2=0,t3=0;
    #pragma unroll
    for (int k=0;k<64;k++){
      float sv = s0[k];
      float4 w4 = *(const float4*)&wv[k*64+c];
      t0 += sv*w4.x; t1 += sv*w4.y; t2 += sv*w4.z; t3 += sv*w4.w;
    }
    ((float4*)(vp+c))[0] = make_float4(t0,t1,t2,t3);
  }
}

// ---------- per-node softmax + aggregation + x1 = x + agg@W_o (grid NN x 256) ----------
__global__ void __launch_bounds__(256) k_agg(const int* __restrict__ off, const int* __restrict__ csr,
                       const int* __restrict__ ei,
                       const float* __restrict__ logits_g, const float* __restrict__ v0g,
                       const float* __restrict__ vs, const float* __restrict__ vd,
                       const float* __restrict__ x, const float* __restrict__ Wo,
                       float* __restrict__ out){
  __shared__ float aggl[1024];
  __shared__ float alph[MAXDEG*HH];
  __shared__ int   eidl[MAXDEG];
  __shared__ int   srcl[MAXDEG];
  __shared__ float salpha[HH];
  int n = blockIdx.x;
  int o0 = off[n];
  int deg = off[n+1]-o0;
  if (deg > MAXDEG) deg = MAXDEG;
  if ((int)threadIdx.x < deg){
    int e = csr[o0+threadIdx.x];
    eidl[threadIdx.x]=e;
    srcl[threadIdx.x]=ei[e];
    #pragma unroll
    for (int h=0;h<HH;h++) alph[threadIdx.x*HH+h]=logits_g[(size_t)e*HH+h];
  }
  __syncthreads();
  if (threadIdx.x < HH){
    int h = threadIdx.x;
    float m = -1e30f;
    for (int i=0;i<deg;i++) m = fmaxf(m, alph[i*HH+h]);
    float ds = 0.0f;
    for (int i=0;i<deg;i++){ float w = expf(alph[i*HH+h]-m); alph[i*HH+h]=w; ds += w; }
    float inv = 1.0f/(ds+1e-9f);
    for (int i=0;i<deg;i++) alph[i*HH+h] *= inv;
    salpha[h] = ds*inv;
  }
  __syncthreads();
  int c = threadIdx.x & 63;
  int wg = threadIdx.x >> 6;
  int h = c >> 4;
  for (int lp=wg; lp<16; lp+=4){
    float acc = 0.0f;
    if (lp==0){
      for (int i=0;i<deg;i++) acc += alph[i*HH+h]*v0g[(size_t)eidl[i]*64+c];
    } else {
      for (int i=0;i<deg;i++) acc += alph[i*HH+h]*vs[(size_t)srcl[i]*1024 + lp*64 + c];
      acc += salpha[h]*vd[(size_t)n*1024 + lp*64 + c];
    }
    aggl[lp*64+c]=acc;
  }
  __syncthreads();
  for (int idx=threadIdx.x; idx<1024; idx+=256){
    int l = idx>>6, cc = idx&63;
    float acc = x[(size_t)n*1024+idx];
    const float* ar = &aggl[l*64];
    #pragma unroll 8
    for (int k=0;k<64;k++) acc += ar[k]*Wo[k*64+cc];
    out[(size_t)n*1024+idx]=acc;
  }
}

// ---------- FFN with bf16 MFMA: 4 nodes (64 SH rows) per block, grid 2000x256 ----------
__global__ void __launch_bounds__(256) k_ffn(const float* __restrict__ x1,
                       const float* __restrict__ Wg, const float* __restrict__ Wh,
                       const float* __restrict__ Wf, float* __restrict__ out){
  __shared__ __bf16 Abuf[64*72];    // y bf16, row stride 72 (144B, bank step 4)
  __shared__ __bf16 WhT[128*72];    // Wh transposed [n][k]
  __shared__ __bf16 Hbuf[64*136];   // hidden (gated) bf16, stride 136 (272B)
  __shared__ __bf16 WfT[64*136];    // Wf transposed [n][k]
  __shared__ float  gl[512];        // gate per node (4 x 128)
  __shared__ float  scl[4];
  int tid = threadIdx.x;
  int l = tid & 63, w = tid >> 6;
  const size_t base = (size_t)blockIdx.x*4096;
  const float* xb = x1 + base;

  // --- phase 1: per-node rms (wave w handles node w) ---
  {
    const float4* xp = (const float4*)(xb + w*1024);
    float ss = 0.0f;
    #pragma unroll
    for (int i=0;i<4;i++){
      float4 v = xp[l + 64*i];
      ss += v.x*v.x + v.y*v.y + v.z*v.z + v.w*v.w;
    }
    #pragma unroll
    for (int m=32;m>=1;m>>=1) ss += __shfl_xor(ss, m);
    if (l==0) scl[w] = 1.0f/sqrtf(ss*(1.0f/1024.0f) + 1e-6f);
  }
  __syncthreads();

  // --- phase 2: fill A (y bf16), WhT, WfT, gate ---
  for (int i=tid; i<1024; i+=256){     // float4 index over 4096 y values
    int m = i>>4, k4 = (i&15)*4;
    float s = scl[m>>4];
    float4 v = ((const float4*)xb)[i];
    __bf16* ap = &Abuf[m*72 + k4];
    ap[0]=(__bf16)(v.x*s); ap[1]=(__bf16)(v.y*s); ap[2]=(__bf16)(v.z*s); ap[3]=(__bf16)(v.w*s);
  }
  for (int i=tid; i<8192; i+=256){ int k=i>>7, nn=i&127; WhT[nn*72+k]  = (__bf16)Wh[i]; }
  for (int i=tid; i<8192; i+=256){ int k=i>>6, nn=i&63;  WfT[nn*136+k] = (__bf16)Wf[i]; }
  {
    // gate: g[nd][c] = silu(scl[nd] * sum_k x1[nd][0][k] Wg[k][c]); thread does 2 nodes
    int c = tid & 127;
    int half = tid >> 7;
    const float* xr0 = xb + (half*2)*1024;
    const float* xr1 = xr0 + 1024;
    float a0=0.0f, a1=0.0f;
    #pragma unroll 8
    for (int k=0;k<64;k++){
      float wgv = Wg[k*128 + c];
      a0 += xr0[k]*wgv; a1 += xr1[k]*wgv;
    }
    gl[(half*2)*128 + c]   = silu_f(a0*scl[half*2]);
    gl[(half*2+1)*128 + c] = silu_f(a1*scl[half*2+1]);
  }
  __syncthreads();

  // --- phase 3: H[64,128] = A[64,64] @ Wh[64,128], gate, -> bf16 LDS ---
  int lr = l & 15;   // row (A) / col (B)
  int lg = l >> 4;   // k-chunk
  {
    bf16x8 a0 = *(const bf16x8*)&Abuf[(w*16 + lr)*72 +      lg*8];
    bf16x8 a1 = *(const bf16x8*)&Abuf[(w*16 + lr)*72 + 32 + lg*8];
    f32x4 acc[8];
    #pragma unroll
    for (int nt=0;nt<8;nt++) acc[nt] = (f32x4){0.f,0.f,0.f,0.f};
    #pragma unroll
    for (int nt=0;nt<8;nt++){
      bf16x8 b0 = *(const bf16x8*)&WhT[(nt*16 + lr)*72 +      lg*8];
      bf16x8 b1 = *(const bf16x8*)&WhT[(nt*16 + lr)*72 + 32 + lg*8];
      acc[nt] = __builtin_amdgcn_mfma_f32_16x16x32_bf16(a0, b0, acc[nt], 0, 0, 0);
      acc[nt] = __builtin_amdgcn_mfma_f32_16x16x32_bf16(a1, b1, acc[nt], 0, 0, 0);
    }
    #pragma unroll
    for (int nt=0;nt<8;nt++){
      int colj = nt*16 + lr;
      float g = gl[w*128 + colj];
      #pragma unroll
      for (int r=0;r<4;r++){
        int row = lg*4 + r;
        Hbuf[(w*16+row)*136 + colj] = (__bf16)(acc[nt][r]*g);
      }
    }
  }
  __syncthreads();

  // --- phase 4: OUT[64,64] = H[64,128] @ Wf[128,64] + x1 ---
  {
    f32x4 o[4];
    #pragma unroll
    for (int nt=0;nt<4;nt++) o[nt] = (f32x4){0.f,0.f,0.f,0.f};
    #pragma unroll
    for (int kc=0;kc<4;kc++){
      bf16x8 a = *(const bf16x8*)&Hbuf[(w*16 + lr)*136 + kc*32 + lg*8];
      #pragma unroll
      for (int nt=0;nt<4;nt++){
        bf16x8 b = *(const bf16x8*)&WfT[(nt*16 + lr)*136 + kc*32 + lg*8];
        o[nt] = __builtin_amdgcn_mfma_f32_16x16x32_bf16(a, b, o[nt], 0, 0, 0);
      }
    }
    #pragma unroll
    for (int nt=0;nt<4;nt++){
      int col = nt*16 + lr;
      #pragma unroll
      for (int r=0;r<4;r++){
        int row = w*16 + lg*4 + r;
        out[base + row*64 + col] = xb[row*64 + col] + o[nt][r];
      }
    }
  }
}

extern "C" void kernel_launch(void* const* d_in, const int* in_sizes, int n_in,
                              void* d_out, int out_size, void* d_ws, size_t ws_size,
                              hipStream_t stream) {
  (void)in_sizes; (void)n_in; (void)out_size; (void)ws_size;
  const float* pos = (const float*)d_in[0];
  const float* x   = (const float*)d_in[1];
  const float* Wsrc= (const float*)d_in[2];
  const float* Wdst= (const float*)d_in[3];
  const float* W1  = (const float*)d_in[4];
  const float* b1  = (const float*)d_in[5];
  const float* W2  = (const float*)d_in[6];
  const float* b2  = (const float*)d_in[7];
  const float* We  = (const float*)d_in[8];
  const float* Wa  = (const float*)d_in[9];
  const float* va  = (const float*)d_in[10];
  const float* Wv  = (const float*)d_in[11];
  const float* Wo  = (const float*)d_in[12];
  const float* Wg  = (const float*)d_in[13];
  const float* Wh  = (const float*)d_in[14];
  const float* Wf  = (const float*)d_in[15];
  const int*   ei  = (const int*)d_in[16];
  float* out = (float*)d_out;

  char* wp = (char*)d_ws;
  auto alloc = [&](size_t elems)->char*{
    char* p = wp;
    wp += ((elems*4 + 255)/256)*256;
    return p;
  };
  float* rms1 = (float*)alloc(NN);
  float* wsv  = (float*)alloc(4096);
  float* wdv  = (float*)alloc(4096);
  float* xs0  = (float*)alloc((size_t)NN*64);
  float* xd0  = (float*)alloc((size_t)NN*64);
  float* vs   = (float*)alloc((size_t)NN*1024);
  float* vd   = (float*)alloc((size_t)NN*1024);
  float* e2g  = (float*)alloc((size_t)EE*ECH);
  float* v0g  = (float*)alloc((size_t)EE*64);
  float* lgts = (float*)alloc((size_t)EE*HH);
  int* deg    = (int*)alloc(NN);
  int* cursor = (int*)alloc(NN);
  int* off    = (int*)alloc(NN+1);
  int* csr    = (int*)alloc(EE);

  hipMemsetAsync(deg, 0, NN*sizeof(int), stream);
  hipMemsetAsync(cursor, 0, NN*sizeof(int), stream);

  k_fusew<<<32,256,0,stream>>>(Wsrc,Wdst,Wv,wsv,wdv);
  k_rms<<<NN,256,0,stream>>>(x,rms1);
  k_node0<<<NN*64/256,256,0,stream>>>(x,rms1,Wsrc,Wdst,xs0,xd0);
  k_node1<<<NN*16/64,256,0,stream>>>(x,rms1,wsv,wdv,vs,vd);
  k_edgeA<<<EE/256,256,0,stream>>>(pos,ei,W1,b1,W2,b2,e2g);
  k_hist<<<EE/256,256,0,stream>>>(ei,deg);
  k_scan<<<1,1024,0,stream>>>(deg,off);
  k_fill<<<EE/256,256,0,stream>>>(ei,off,cursor,csr);
  k_edgeB<<<EE/256,256,0,stream>>>(e2g,ei,xs0,xd0,We,Wa,va,Wv,lgts,v0g);
  k_agg<<<NN,256,0,stream>>>(off,csr,ei,lgts,v0g,vs,vd,x,Wo,out);
  k_ffn<<<NN/4,256,0,stream>>>(out,Wg,Wh,Wf,out);
}

// Round 3
// 431.660 us; speedup vs baseline: 2.6882x; 2.6882x over previous
//
#include <hip/hip_runtime.h>
#include <math.h>

// Problem constants (match reference file)
#define NN 8000
#define EE 96000
#define HH 4
#define NBASIS 256
#define ECH 48
#define FFNH 128
#define CUTOFF_R 0.0792f
#define PI_F 3.14159265358979323846f
#define SPACING (CUTOFF_R/255.0f)
#define INV_STD (256.0f/CUTOFF_R)
#define MAXDEG 96
#define W1S 52   // padded LDS stride for W1 rows

typedef __bf16 bf16x8 __attribute__((ext_vector_type(8)));
typedef float  f32x4  __attribute__((ext_vector_type(4)));

__device__ __forceinline__ float silu_f(float x){ return x/(1.0f+expf(-x)); }

// ---------- fused weights: wsv = W_src@W_v, wdv = W_dst@W_v  (grid 32x256) ----------
__global__ void k_fusew(const float* __restrict__ Wsrc, const float* __restrict__ Wdst,
                        const float* __restrict__ Wv,
                        float* __restrict__ wsv, float* __restrict__ wdv){
  int gid = blockIdx.x*256 + threadIdx.x;
  int which = gid >> 12;
  int idx = gid & 4095;
  int r = idx >> 6, c = idx & 63;
  const float* A = which ? Wdst : Wsrc;
  float acc = 0.0f;
  #pragma unroll
  for (int k=0;k<64;k++) acc += A[r*64+k]*Wv[k*64+c];
  (which ? wdv : wsv)[idx] = acc;
}

// ---------- rms scale per node (grid NN x 256) ----------
__global__ void __launch_bounds__(256) k_rms(const float* __restrict__ x, float* __restrict__ rms1){
  int n = blockIdx.x;
  float4 v = ((const float4*)(x + (size_t)n*1024))[threadIdx.x];
  float ss = v.x*v.x+v.y*v.y+v.z*v.z+v.w*v.w;
  #pragma unroll
  for (int m=32;m>=1;m>>=1) ss += __shfl_xor(ss, m);
  __shared__ float red[4];
  if ((threadIdx.x & 63)==0) red[threadIdx.x>>6]=ss;
  __syncthreads();
  if (threadIdx.x==0)
    rms1[n] = 1.0f/sqrtf((red[0]+red[1]+red[2]+red[3])*(1.0f/1024.0f)+1e-6f);
}

// ---------- xs0[n,c], xd0[n,c] : l=0 row through W_src/W_dst (grid 2000x256) ----------
__global__ void __launch_bounds__(256) k_node0(const float* __restrict__ x, const float* __restrict__ rms1,
                        const float* __restrict__ Wsrc, const float* __restrict__ Wdst,
                        float* __restrict__ xs0, float* __restrict__ xd0){
  int t = blockIdx.x*256 + threadIdx.x;
  int n = t>>6, c = t&63;
  float sc = rms1[n];
  const float* xr = x + (size_t)n*1024;   // l = 0 row
  float as=0.0f, ad=0.0f;
  #pragma unroll 8
  for (int k=0;k<64;k++){
    float xv = xr[k]*sc;
    as += xv*Wsrc[k*64+c];
    ad += xv*Wdst[k*64+c];
  }
  xs0[t]=as; xd0[t]=ad;
}

// ---------- vs = xn@wsv, vd = xn@wdv over all rows N*L (grid 2000x256, 64 rows/block) ----------
__global__ void __launch_bounds__(256) k_node1(const float* __restrict__ x, const float* __restrict__ rms1,
                        const float* __restrict__ wsv, const float* __restrict__ wdv,
                        float* __restrict__ vs, float* __restrict__ vd){
  __shared__ float xt[64*65];
  __shared__ float wa[4096];
  __shared__ float wb[4096];
  int base = blockIdx.x*64;
  for (int i=threadIdx.x;i<4096;i+=256){
    int r = i>>6, k = i&63;
    int row = base + r;
    xt[r*65+k] = x[(size_t)row*64+k]*rms1[row>>4];
    wa[i] = wsv[i]; wb[i] = wdv[i];
  }
  __syncthreads();
  int r = threadIdx.x>>2, cg = threadIdx.x&3;
  float as[16], ad[16];
  #pragma unroll
  for (int j=0;j<16;j++){ as[j]=0.0f; ad[j]=0.0f; }
  for (int k=0;k<64;k++){
    float a = xt[r*65+k];
    const float* w1p = &wa[k*64+cg*16];
    const float* w2p = &wb[k*64+cg*16];
    #pragma unroll
    for (int j=0;j<16;j++){ as[j] += a*w1p[j]; ad[j] += a*w2p[j]; }
  }
  int row = base + r;
  float* vsp = vs + (size_t)row*64 + cg*16;
  float* vdp = vd + (size_t)row*64 + cg*16;
  #pragma unroll
  for (int j=0;j<16;j++){ vsp[j]=as[j]; vdp[j]=ad[j]; }
}

// ---------- edge RBF + 2-layer MLP -> e2[E,48] (grid 375x256) ----------
__global__ void __launch_bounds__(256) k_edgeA(const float* __restrict__ pos, const int* __restrict__ ei,
                        const float* __restrict__ W1, const float* __restrict__ b1,
                        const float* __restrict__ W2, const float* __restrict__ b2,
                        float* __restrict__ e2g){
  __shared__ float w1[NBASIS*W1S];
  __shared__ float w2[ECH*ECH];
  __shared__ float b1l[ECH], b2l[ECH];
  for (int i=threadIdx.x;i<NBASIS*ECH;i+=256){ int k=i/ECH, j=i-k*ECH; w1[k*W1S+j]=W1[i]; }
  for (int i=threadIdx.x;i<ECH*ECH;i+=256) w2[i]=W2[i];
  if (threadIdx.x<ECH){ b1l[threadIdx.x]=b1[threadIdx.x]; b2l[threadIdx.x]=b2[threadIdx.x]; }
  __syncthreads();
  int e = blockIdx.x*256 + threadIdx.x;   // grid exactly covers EE
  int s = ei[e], t = ei[EE+e];
  float dx = pos[3*s]-pos[3*t], dy = pos[3*s+1]-pos[3*t+1], dz = pos[3*s+2]-pos[3*t+2];
  float d = sqrtf(dx*dx+dy*dy+dz*dz+1e-12f);
  float acc[ECH];
  #pragma unroll
  for (int j=0;j<ECH;j++) acc[j]=b1l[j];
  if (d < CUTOFF_R){
    float env = 0.5f*(cosf(PI_F*(d/CUTOFF_R))+1.0f);
    int j0 = (int)floorf(d/SPACING);
    int klo = j0-9 > 0 ? j0-9 : 0;
    int khi = j0+10 < NBASIS-1 ? j0+10 : NBASIS-1;
    for (int k=klo;k<=khi;k++){
      float del = (d - k*SPACING)*INV_STD;
      float g = expf(-0.5f*del*del)*env;
      const float* wr = &w1[k*W1S];
      #pragma unroll
      for (int j=0;j<ECH;j++) acc[j] += g*wr[j];
    }
  }
  float e1[ECH];
  #pragma unroll
  for (int j=0;j<ECH;j++) e1[j] = silu_f(acc[j]);
  float* outp = e2g + (size_t)e*ECH;
  for (int j4=0;j4<ECH;j4+=4){
    float o[4];
    #pragma unroll
    for (int jj=0;jj<4;jj++){
      float a2 = b2l[j4+jj];
      #pragma unroll
      for (int k=0;k<ECH;k++) a2 += e1[k]*w2[k*ECH+j4+jj];
      o[jj] = silu_f(a2);
    }
    ((float4*)(outp+j4))[0] = make_float4(o[0],o[1],o[2],o[3]);
  }
}

// ---------- CSR build ----------
__global__ void k_hist(const int* __restrict__ ei, int* __restrict__ deg){
  int e = blockIdx.x*256 + threadIdx.x;
  atomicAdd(&deg[ei[EE+e]], 1);
}

__global__ void __launch_bounds__(1024) k_scan(const int* __restrict__ deg, int* __restrict__ off){
  __shared__ int sums[1024];
  int t = threadIdx.x;
  int base = t*8;
  int loc[8]; int s=0;
  #pragma unroll
  for (int i=0;i<8;i++){ int idx=base+i; int v = (idx<NN)? deg[idx]:0; loc[i]=v; s+=v; }
  sums[t]=s;
  __syncthreads();
  for (int d=1; d<1024; d<<=1){
    int v = (t>=d)? sums[t-d]:0;
    __syncthreads();
    sums[t] += v;
    __syncthreads();
  }
  int run = sums[t]-s;
  #pragma unroll
  for (int i=0;i<8;i++){ int idx=base+i; if (idx<NN) off[idx]=run; run+=loc[i]; }
  if (t==1023) off[NN]=sums[1023];
}

__global__ void k_fill(const int* __restrict__ ei, const int* __restrict__ off,
                       int* __restrict__ cursor, int* __restrict__ csr){
  int e = blockIdx.x*256 + threadIdx.x;
  int d = ei[EE+e];
  int slot = off[d] + atomicAdd(&cursor[d],1);
  csr[slot]=e;
}

// ---------- per-edge: e_c, s0, logits, v0 (grid 375x256) — round-1 scalar version ----------
__global__ void __launch_bounds__(256) k_edgeB(const float* __restrict__ e2g, const int* __restrict__ ei,
                        const float* __restrict__ xs0, const float* __restrict__ xd0,
                        const float* __restrict__ W_edge, const float* __restrict__ W_alpha,
                        const float* __restrict__ v_alpha, const float* __restrict__ Wv,
                        float* __restrict__ logits_g, float* __restrict__ v0g){
  __shared__ float we[ECH*64];
  __shared__ float wv[4096];
  __shared__ float va[256];
  __shared__ float wab[64*68];   // transposed [j][k] chunk of W_alpha, padded stride 68
  for (int i=threadIdx.x;i<ECH*64;i+=256) we[i]=W_edge[i];
  for (int i=threadIdx.x;i<4096;i+=256) wv[i]=Wv[i];
  va[threadIdx.x]=v_alpha[threadIdx.x];
  __syncthreads();
  int e = blockIdx.x*256 + threadIdx.x;
  int s = ei[e], t = ei[EE+e];
  float e2r[ECH];
  {
    const float4* p = (const float4*)(e2g + (size_t)e*ECH);
    #pragma unroll
    for (int q=0;q<ECH/4;q++){
      float4 v4 = p[q];
      e2r[4*q+0]=v4.x; e2r[4*q+1]=v4.y; e2r[4*q+2]=v4.z; e2r[4*q+3]=v4.w;
    }
  }
  // s0 accumulates e_c first (static-index regs), then scaled by (xs0[src]+xd0[dst])
  float s0[64];
  #pragma unroll
  for (int c=0;c<64;c++) s0[c]=0.0f;
  for (int k=0;k<ECH;k++){
    float v = e2r[k];
    const float* wr = &we[k*64];
    #pragma unroll
    for (int c=0;c<64;c++) s0[c] += v*wr[c];
  }
  {
    const float4* ps = (const float4*)(xs0 + (size_t)s*64);
    const float4* pd = (const float4*)(xd0 + (size_t)t*64);
    #pragma unroll
    for (int q=0;q<16;q++){
      float4 a4 = ps[q]; float4 b4 = pd[q];
      s0[4*q+0] *= (a4.x+b4.x);
      s0[4*q+1] *= (a4.y+b4.y);
      s0[4*q+2] *= (a4.z+b4.z);
      s0[4*q+3] *= (a4.w+b4.w);
    }
  }
  // logits: per head, stage transposed W_alpha chunk, dot + leaky_relu + v_alpha
  float lg[HH];
  for (int h=0;h<HH;h++){
    __syncthreads();
    for (int i=threadIdx.x;i<4096;i+=256){
      int k = i>>6, j = i&63;                  // read coalesced (consecutive j)
      wab[j*68+k] = W_alpha[k*256 + h*64 + j]; // store transposed
    }
    __syncthreads();
    float acc = 0.0f;
    for (int j=0;j<64;j++){
      float tdot = 0.0f;
      const float* wc = &wab[j*68];
      #pragma unroll
      for (int k=0;k<64;k++) tdot += s0[k]*wc[k];
      acc += (tdot>0.0f ? tdot : 0.2f*tdot)*va[h*64+j];
    }
    lg[h]=acc;
  }
  ((float4*)(logits_g+(size_t)e*4))[0] = make_float4(lg[0],lg[1],lg[2],lg[3]);
  // v0 = s0 @ W_v
  float* vp = v0g + (size_t)e*64;
  for (int c=0;c<64;c+=4){
    float t0=0,t1=0,t2=0,t3=0;
    #pragma unroll
    for (int k=0;k<64;k++){
      float sv = s0[k];
      const float* wr = &wv[k*64+c];
      t0 += sv*wr[0]; t1 += sv*wr[1]; t2 += sv*wr[2]; t3 += sv*wr[3];
    }
    ((float4*)(vp+c))[0] = make_float4(t0,t1,t2,t3);
  }
}

// ---------- per-node softmax + aggregation + x1 = x + agg@W_o (grid NN x 256) ----------
__global__ void __launch_bounds__(256) k_agg(const int* __restrict__ off, const int* __restrict__ csr,
                       const int* __restrict__ ei,
                       const float* __restrict__ logits_g, const float* __restrict__ v0g,
                       const float* __restrict__ vs, const float* __restrict__ vd,
                       const float* __restrict__ x, const float* __restrict__ Wo,
                       float* __restrict__ out){
  __shared__ float aggl[1024];
  __shared__ float alph[MAXDEG*HH];
  __shared__ int   eidl[MAXDEG];
  __shared__ int   srcl[MAXDEG];
  __shared__ float salpha[HH];
  int n = blockIdx.x;
  int o0 = off[n];
  int deg = off[n+1]-o0;
  if (deg > MAXDEG) deg = MAXDEG;
  if ((int)threadIdx.x < deg){
    int e = csr[o0+threadIdx.x];
    eidl[threadIdx.x]=e;
    srcl[threadIdx.x]=ei[e];
    #pragma unroll
    for (int h=0;h<HH;h++) alph[threadIdx.x*HH+h]=logits_g[(size_t)e*HH+h];
  }
  __syncthreads();
  if (threadIdx.x < HH){
    int h = threadIdx.x;
    float m = -1e30f;
    for (int i=0;i<deg;i++) m = fmaxf(m, alph[i*HH+h]);
    float ds = 0.0f;
    for (int i=0;i<deg;i++){ float w = expf(alph[i*HH+h]-m); alph[i*HH+h]=w; ds += w; }
    float inv = 1.0f/(ds+1e-9f);
    for (int i=0;i<deg;i++) alph[i*HH+h] *= inv;
    salpha[h] = ds*inv;
  }
  __syncthreads();
  int c = threadIdx.x & 63;
  int wg = threadIdx.x >> 6;
  int h = c >> 4;
  for (int lp=wg; lp<16; lp+=4){
    float acc = 0.0f;
    if (lp==0){
      for (int i=0;i<deg;i++) acc += alph[i*HH+h]*v0g[(size_t)eidl[i]*64+c];
    } else {
      for (int i=0;i<deg;i++) acc += alph[i*HH+h]*vs[(size_t)srcl[i]*1024 + lp*64 + c];
      acc += salpha[h]*vd[(size_t)n*1024 + lp*64 + c];
    }
    aggl[lp*64+c]=acc;
  }
  __syncthreads();
  for (int idx=threadIdx.x; idx<1024; idx+=256){
    int l = idx>>6, cc = idx&63;
    float acc = x[(size_t)n*1024+idx];
    const float* ar = &aggl[l*64];
    #pragma unroll 8
    for (int k=0;k<64;k++) acc += ar[k]*Wo[k*64+cc];
    out[(size_t)n*1024+idx]=acc;
  }
}

// ---------- FFN with bf16 MFMA: 4 nodes (64 SH rows) per block, grid 2000x256 ----------
__global__ void __launch_bounds__(256) k_ffn(const float* __restrict__ x1,
                       const float* __restrict__ Wg, const float* __restrict__ Wh,
                       const float* __restrict__ Wf, float* __restrict__ out){
  __shared__ __bf16 Abuf[64*72];    // y bf16, row stride 72 (144B, bank step 4)
  __shared__ __bf16 WhT[128*72];    // Wh transposed [n][k]
  __shared__ __bf16 Hbuf[64*136];   // hidden (gated) bf16, stride 136 (272B)
  __shared__ __bf16 WfT[64*136];    // Wf transposed [n][k]
  __shared__ float  gl[512];        // gate per node (4 x 128)
  __shared__ float  scl[4];
  int tid = threadIdx.x;
  int l = tid & 63, w = tid >> 6;
  const size_t base = (size_t)blockIdx.x*4096;
  const float* xb = x1 + base;

  // --- phase 1: per-node rms (wave w handles node w) ---
  {
    const float4* xp = (const float4*)(xb + w*1024);
    float ss = 0.0f;
    #pragma unroll
    for (int i=0;i<4;i++){
      float4 v = xp[l + 64*i];
      ss += v.x*v.x + v.y*v.y + v.z*v.z + v.w*v.w;
    }
    #pragma unroll
    for (int m=32;m>=1;m>>=1) ss += __shfl_xor(ss, m);
    if (l==0) scl[w] = 1.0f/sqrtf(ss*(1.0f/1024.0f) + 1e-6f);
  }
  __syncthreads();

  // --- phase 2: fill A (y bf16), WhT, WfT, gate ---
  for (int i=tid; i<1024; i+=256){     // float4 index over 4096 y values
    int m = i>>4, k4 = (i&15)*4;
    float s = scl[m>>4];
    float4 v = ((const float4*)xb)[i];
    __bf16* ap = &Abuf[m*72 + k4];
    ap[0]=(__bf16)(v.x*s); ap[1]=(__bf16)(v.y*s); ap[2]=(__bf16)(v.z*s); ap[3]=(__bf16)(v.w*s);
  }
  for (int i=tid; i<8192; i+=256){ int k=i>>7, nn=i&127; WhT[nn*72+k]  = (__bf16)Wh[i]; }
  for (int i=tid; i<8192; i+=256){ int k=i>>6, nn=i&63;  WfT[nn*136+k] = (__bf16)Wf[i]; }
  {
    // gate: g[nd][c] = silu(scl[nd] * sum_k x1[nd][0][k] Wg[k][c]); thread does 2 nodes
    int c = tid & 127;
    int half = tid >> 7;
    const float* xr0 = xb + (half*2)*1024;
    const float* xr1 = xr0 + 1024;
    float a0=0.0f, a1=0.0f;
    #pragma unroll 8
    for (int k=0;k<64;k++){
      float wgv = Wg[k*128 + c];
      a0 += xr0[k]*wgv; a1 += xr1[k]*wgv;
    }
    gl[(half*2)*128 + c]   = silu_f(a0*scl[half*2]);
    gl[(half*2+1)*128 + c] = silu_f(a1*scl[half*2+1]);
  }
  __syncthreads();

  // --- phase 3: H[64,128] = A[64,64] @ Wh[64,128], gate, -> bf16 LDS ---
  int lr = l & 15;   // row (A) / col (B)
  int lg = l >> 4;   // k-chunk
  {
    bf16x8 a0 = *(const bf16x8*)&Abuf[(w*16 + lr)*72 +      lg*8];
    bf16x8 a1 = *(const bf16x8*)&Abuf[(w*16 + lr)*72 + 32 + lg*8];
    f32x4 acc[8];
    #pragma unroll
    for (int nt=0;nt<8;nt++) acc[nt] = (f32x4){0.f,0.f,0.f,0.f};
    #pragma unroll
    for (int nt=0;nt<8;nt++){
      bf16x8 b0 = *(const bf16x8*)&WhT[(nt*16 + lr)*72 +      lg*8];
      bf16x8 b1 = *(const bf16x8*)&WhT[(nt*16 + lr)*72 + 32 + lg*8];
      acc[nt] = __builtin_amdgcn_mfma_f32_16x16x32_bf16(a0, b0, acc[nt], 0, 0, 0);
      acc[nt] = __builtin_amdgcn_mfma_f32_16x16x32_bf16(a1, b1, acc[nt], 0, 0, 0);
    }
    #pragma unroll
    for (int nt=0;nt<8;nt++){
      int colj = nt*16 + lr;
      float g = gl[w*128 + colj];
      #pragma unroll
      for (int r=0;r<4;r++){
        int row = lg*4 + r;
        Hbuf[(w*16+row)*136 + colj] = (__bf16)(acc[nt][r]*g);
      }
    }
  }
  __syncthreads();

  // --- phase 4: OUT[64,64] = H[64,128] @ Wf[128,64] + x1 ---
  {
    f32x4 o[4];
    #pragma unroll
    for (int nt=0;nt<4;nt++) o[nt] = (f32x4){0.f,0.f,0.f,0.f};
    #pragma unroll
    for (int kc=0;kc<4;kc++){
      bf16x8 a = *(const bf16x8*)&Hbuf[(w*16 + lr)*136 + kc*32 + lg*8];
      #pragma unroll
      for (int nt=0;nt<4;nt++){
        bf16x8 b = *(const bf16x8*)&WfT[(nt*16 + lr)*136 + kc*32 + lg*8];
        o[nt] = __builtin_amdgcn_mfma_f32_16x16x32_bf16(a, b, o[nt], 0, 0, 0);
      }
    }
    #pragma unroll
    for (int nt=0;nt<4;nt++){
      int col = nt*16 + lr;
      #pragma unroll
      for (int r=0;r<4;r++){
        int row = w*16 + lg*4 + r;
        out[base + row*64 + col] = xb[row*64 + col] + o[nt][r];
      }
    }
  }
}

extern "C" void kernel_launch(void* const* d_in, const int* in_sizes, int n_in,
                              void* d_out, int out_size, void* d_ws, size_t ws_size,
                              hipStream_t stream) {
  (void)in_sizes; (void)n_in; (void)out_size; (void)ws_size;
  const float* pos = (const float*)d_in[0];
  const float* x   = (const float*)d_in[1];
  const float* Wsrc= (const float*)d_in[2];
  const float* Wdst= (const float*)d_in[3];
  const float* W1  = (const float*)d_in[4];
  const float* b1  = (const float*)d_in[5];
  const float* W2  = (const float*)d_in[6];
  const float* b2  = (const float*)d_in[7];
  const float* We  = (const float*)d_in[8];
  const float* Wa  = (const float*)d_in[9];
  const float* va  = (const float*)d_in[10];
  const float* Wv  = (const float*)d_in[11];
  const float* Wo  = (const float*)d_in[12];
  const float* Wg  = (const float*)d_in[13];
  const float* Wh  = (const float*)d_in[14];
  const float* Wf  = (const float*)d_in[15];
  const int*   ei  = (const int*)d_in[16];
  float* out = (float*)d_out;

  char* wp = (char*)d_ws;
  auto alloc = [&](size_t elems)->char*{
    char* p = wp;
    wp += ((elems*4 + 255)/256)*256;
    return p;
  };
  float* rms1 = (float*)alloc(NN);
  float* wsv  = (float*)alloc(4096);
  float* wdv  = (float*)alloc(4096);
  float* xs0  = (float*)alloc((size_t)NN*64);
  float* xd0  = (float*)alloc((size_t)NN*64);
  float* vs   = (float*)alloc((size_t)NN*1024);
  float* vd   = (float*)alloc((size_t)NN*1024);
  float* e2g  = (float*)alloc((size_t)EE*ECH);
  float* v0g  = (float*)alloc((size_t)EE*64);
  float* lgts = (float*)alloc((size_t)EE*HH);
  int* deg    = (int*)alloc(NN);
  int* cursor = (int*)alloc(NN);
  int* off    = (int*)alloc(NN+1);
  int* csr    = (int*)alloc(EE);

  hipMemsetAsync(deg, 0, NN*sizeof(int), stream);
  hipMemsetAsync(cursor, 0, NN*sizeof(int), stream);

  k_fusew<<<32,256,0,stream>>>(Wsrc,Wdst,Wv,wsv,wdv);
  k_rms<<<NN,256,0,stream>>>(x,rms1);
  k_node0<<<NN*64/256,256,0,stream>>>(x,rms1,Wsrc,Wdst,xs0,xd0);
  k_node1<<<NN*16/64,256,0,stream>>>(x,rms1,wsv,wdv,vs,vd);
  k_edgeA<<<EE/256,256,0,stream>>>(pos,ei,W1,b1,W2,b2,e2g);
  k_hist<<<EE/256,256,0,stream>>>(ei,deg);
  k_scan<<<1,1024,0,stream>>>(deg,off);
  k_fill<<<EE/256,256,0,stream>>>(ei,off,cursor,csr);
  k_edgeB<<<EE/256,256,0,stream>>>(e2g,ei,xs0,xd0,We,Wa,va,Wv,lgts,v0g);
  k_agg<<<NN,256,0,stream>>>(off,csr,ei,lgts,v0g,vs,vd,x,Wo,out);
  k_ffn<<<NN/4,256,0,stream>>>(out,Wg,Wh,Wf,out);
}

// Round 4
// 344.034 us; speedup vs baseline: 3.3728x; 1.2547x over previous
//
#include <hip/hip_runtime.h>
#include <math.h>

// Problem constants (match reference file)
#define NN 8000
#define EE 96000
#define HH 4
#define NBASIS 256
#define ECH 48
#define FFNH 128
#define CUTOFF_R 0.0792f
#define PI_F 3.14159265358979323846f
#define SPACING (CUTOFF_R/255.0f)
#define INV_STD (256.0f/CUTOFF_R)
#define MAXDEG 96
#define W1S 52   // padded LDS stride for W1 rows

typedef __bf16 bf16x8 __attribute__((ext_vector_type(8)));
typedef float  f32x4  __attribute__((ext_vector_type(4)));

__device__ __forceinline__ float silu_f(float x){ return x/(1.0f+expf(-x)); }

// ---------- fused weights: wsv = W_src@W_v, wdv = W_dst@W_v  (grid 32x256) ----------
__global__ void k_fusew(const float* __restrict__ Wsrc, const float* __restrict__ Wdst,
                        const float* __restrict__ Wv,
                        float* __restrict__ wsv, float* __restrict__ wdv){
  int gid = blockIdx.x*256 + threadIdx.x;
  int which = gid >> 12;
  int idx = gid & 4095;
  int r = idx >> 6, c = idx & 63;
  const float* A = which ? Wdst : Wsrc;
  float acc = 0.0f;
  #pragma unroll
  for (int k=0;k<64;k++) acc += A[r*64+k]*Wv[k*64+c];
  (which ? wdv : wsv)[idx] = acc;
}

// ---------- rms scale per node (grid NN x 256) ----------
__global__ void __launch_bounds__(256) k_rms(const float* __restrict__ x, float* __restrict__ rms1){
  int n = blockIdx.x;
  float4 v = ((const float4*)(x + (size_t)n*1024))[threadIdx.x];
  float ss = v.x*v.x+v.y*v.y+v.z*v.z+v.w*v.w;
  #pragma unroll
  for (int m=32;m>=1;m>>=1) ss += __shfl_xor(ss, m);
  __shared__ float red[4];
  if ((threadIdx.x & 63)==0) red[threadIdx.x>>6]=ss;
  __syncthreads();
  if (threadIdx.x==0)
    rms1[n] = 1.0f/sqrtf((red[0]+red[1]+red[2]+red[3])*(1.0f/1024.0f)+1e-6f);
}

// ---------- xs0[n,c], xd0[n,c] : l=0 row through W_src/W_dst (grid 2000x256) ----------
__global__ void __launch_bounds__(256) k_node0(const float* __restrict__ x, const float* __restrict__ rms1,
                        const float* __restrict__ Wsrc, const float* __restrict__ Wdst,
                        float* __restrict__ xs0, float* __restrict__ xd0){
  int t = blockIdx.x*256 + threadIdx.x;
  int n = t>>6, c = t&63;
  float sc = rms1[n];
  const float* xr = x + (size_t)n*1024;   // l = 0 row
  float as=0.0f, ad=0.0f;
  #pragma unroll 8
  for (int k=0;k<64;k++){
    float xv = xr[k]*sc;
    as += xv*Wsrc[k*64+c];
    ad += xv*Wdst[k*64+c];
  }
  xs0[t]=as; xd0[t]=ad;
}

// ---------- vs = xn@wsv, vd = xn@wdv over all rows N*L (grid 2000x256, 64 rows/block) ----------
__global__ void __launch_bounds__(256) k_node1(const float* __restrict__ x, const float* __restrict__ rms1,
                        const float* __restrict__ wsv, const float* __restrict__ wdv,
                        float* __restrict__ vs, float* __restrict__ vd){
  __shared__ float xt[64*65];
  __shared__ float wa[4096];
  __shared__ float wb[4096];
  int base = blockIdx.x*64;
  for (int i=threadIdx.x;i<4096;i+=256){
    int r = i>>6, k = i&63;
    int row = base + r;
    xt[r*65+k] = x[(size_t)row*64+k]*rms1[row>>4];
    wa[i] = wsv[i]; wb[i] = wdv[i];
  }
  __syncthreads();
  int r = threadIdx.x>>2, cg = threadIdx.x&3;
  float as[16], ad[16];
  #pragma unroll
  for (int j=0;j<16;j++){ as[j]=0.0f; ad[j]=0.0f; }
  for (int k=0;k<64;k++){
    float a = xt[r*65+k];
    const float* w1p = &wa[k*64+cg*16];
    const float* w2p = &wb[k*64+cg*16];
    #pragma unroll
    for (int j=0;j<16;j++){ as[j] += a*w1p[j]; ad[j] += a*w2p[j]; }
  }
  int row = base + r;
  float* vsp = vs + (size_t)row*64 + cg*16;
  float* vdp = vd + (size_t)row*64 + cg*16;
  #pragma unroll
  for (int j=0;j<16;j++){ vsp[j]=as[j]; vdp[j]=ad[j]; }
}

// ---------- edge RBF + 2-layer MLP -> e2[E,48] (grid 375x256) ----------
__global__ void __launch_bounds__(256) k_edgeA(const float* __restrict__ pos, const int* __restrict__ ei,
                        const float* __restrict__ W1, const float* __restrict__ b1,
                        const float* __restrict__ W2, const float* __restrict__ b2,
                        float* __restrict__ e2g){
  __shared__ float w1[NBASIS*W1S];
  __shared__ float w2[ECH*ECH];
  __shared__ float b1l[ECH], b2l[ECH];
  for (int i=threadIdx.x;i<NBASIS*ECH;i+=256){ int k=i/ECH, j=i-k*ECH; w1[k*W1S+j]=W1[i]; }
  for (int i=threadIdx.x;i<ECH*ECH;i+=256) w2[i]=W2[i];
  if (threadIdx.x<ECH){ b1l[threadIdx.x]=b1[threadIdx.x]; b2l[threadIdx.x]=b2[threadIdx.x]; }
  __syncthreads();
  int e = blockIdx.x*256 + threadIdx.x;   // grid exactly covers EE
  int s = ei[e], t = ei[EE+e];
  float dx = pos[3*s]-pos[3*t], dy = pos[3*s+1]-pos[3*t+1], dz = pos[3*s+2]-pos[3*t+2];
  float d = sqrtf(dx*dx+dy*dy+dz*dz+1e-12f);
  float acc[ECH];
  #pragma unroll
  for (int j=0;j<ECH;j++) acc[j]=b1l[j];
  if (d < CUTOFF_R){
    float env = 0.5f*(cosf(PI_F*(d/CUTOFF_R))+1.0f);
    int j0 = (int)floorf(d/SPACING);
    int klo = j0-9 > 0 ? j0-9 : 0;
    int khi = j0+10 < NBASIS-1 ? j0+10 : NBASIS-1;
    for (int k=klo;k<=khi;k++){
      float del = (d - k*SPACING)*INV_STD;
      float g = expf(-0.5f*del*del)*env;
      const float* wr = &w1[k*W1S];
      #pragma unroll
      for (int j=0;j<ECH;j++) acc[j] += g*wr[j];
    }
  }
  float e1[ECH];
  #pragma unroll
  for (int j=0;j<ECH;j++) e1[j] = silu_f(acc[j]);
  float* outp = e2g + (size_t)e*ECH;
  for (int j4=0;j4<ECH;j4+=4){
    float o[4];
    #pragma unroll
    for (int jj=0;jj<4;jj++){
      float a2 = b2l[j4+jj];
      #pragma unroll
      for (int k=0;k<ECH;k++) a2 += e1[k]*w2[k*ECH+j4+jj];
      o[jj] = silu_f(a2);
    }
    ((float4*)(outp+j4))[0] = make_float4(o[0],o[1],o[2],o[3]);
  }
}

// ---------- CSR build ----------
__global__ void k_hist(const int* __restrict__ ei, int* __restrict__ deg){
  int e = blockIdx.x*256 + threadIdx.x;
  atomicAdd(&deg[ei[EE+e]], 1);
}

__global__ void __launch_bounds__(1024) k_scan(const int* __restrict__ deg, int* __restrict__ off){
  __shared__ int sums[1024];
  int t = threadIdx.x;
  int base = t*8;
  int loc[8]; int s=0;
  #pragma unroll
  for (int i=0;i<8;i++){ int idx=base+i; int v = (idx<NN)? deg[idx]:0; loc[i]=v; s+=v; }
  sums[t]=s;
  __syncthreads();
  for (int d=1; d<1024; d<<=1){
    int v = (t>=d)? sums[t-d]:0;
    __syncthreads();
    sums[t] += v;
    __syncthreads();
  }
  int run = sums[t]-s;
  #pragma unroll
  for (int i=0;i<8;i++){ int idx=base+i; if (idx<NN) off[idx]=run; run+=loc[i]; }
  if (t==1023) off[NN]=sums[1023];
}

__global__ void k_fill(const int* __restrict__ ei, const int* __restrict__ off,
                       int* __restrict__ cursor, int* __restrict__ csr){
  int e = blockIdx.x*256 + threadIdx.x;
  int d = ei[EE+e];
  int slot = off[d] + atomicAdd(&cursor[d],1);
  csr[slot]=e;
}

// ---------- per-edge MFMA: s0 = (e2@We)*(xs0[s]+xd0[d]); logits = lrelu(s0@Wa)·va; v0 = s0@Wv
// 64 edges/block, 4 waves (wave w owns edge rows w*16..w*16+15). grid 1500x256
__global__ void __launch_bounds__(256) k_edgeB(const float* __restrict__ e2g, const int* __restrict__ ei,
                        const float* __restrict__ xs0, const float* __restrict__ xd0,
                        const float* __restrict__ W_edge, const float* __restrict__ W_alpha,
                        const float* __restrict__ v_alpha, const float* __restrict__ Wv,
                        float* __restrict__ logits_g, float* __restrict__ v0g){
  __shared__ __bf16 e2s[64*72];    // edges x k (48 padded to 64), stride 72
  __shared__ __bf16 s0s[64*72];
  __shared__ __bf16 wbuf[128*72];  // reused: WeT / WaT half / WvT, rows = out-col, cols = k
  __shared__ float  va_l[256];
  __shared__ int    srcd[128];     // [0:64) src, [64:128) dst
  int tid = threadIdx.x;
  int w = tid >> 6, l = tid & 63;
  int lr = l & 15, lg = l >> 4;
  int eb = blockIdx.x * 64;

  // ---- stage e2 (zero-padded K), WeT, va, src/dst ----
  for (int i=tid;i<4096;i+=256){
    int r=i>>6, k=i&63;
    e2s[r*72+k] = (k<ECH) ? (__bf16)e2g[(size_t)(eb+r)*ECH+k] : (__bf16)0.f;
  }
  for (int i=tid;i<4096;i+=256){
    int k=i>>6, c=i&63;    // coalesced read of We[k][c]
    wbuf[c*72+k] = (k<ECH) ? (__bf16)W_edge[(size_t)k*64+c] : (__bf16)0.f;
  }
  va_l[tid] = v_alpha[tid];
  if (tid<64){ srcd[tid]=ei[eb+tid]; srcd[64+tid]=ei[EE+eb+tid]; }
  __syncthreads();

  // ---- s0_pre = e2 @ We ----
  bf16x8 ea0 = *(const bf16x8*)&e2s[(w*16+lr)*72 + lg*8];
  bf16x8 ea1 = *(const bf16x8*)&e2s[(w*16+lr)*72 + 32 + lg*8];
  f32x4 sacc[4];
  #pragma unroll
  for (int nt=0;nt<4;nt++){
    sacc[nt] = (f32x4){0.f,0.f,0.f,0.f};
    bf16x8 b0 = *(const bf16x8*)&wbuf[(nt*16+lr)*72 + lg*8];
    bf16x8 b1 = *(const bf16x8*)&wbuf[(nt*16+lr)*72 + 32 + lg*8];
    sacc[nt] = __builtin_amdgcn_mfma_f32_16x16x32_bf16(ea0, b0, sacc[nt], 0, 0, 0);
    sacc[nt] = __builtin_amdgcn_mfma_f32_16x16x32_bf16(ea1, b1, sacc[nt], 0, 0, 0);
  }
  // ---- gather (xs0[src]+xd0[dst]) and scale; write s0 bf16 ----
  #pragma unroll
  for (int reg=0;reg<4;reg++){
    int localrow = w*16 + lg*4 + reg;
    int sI = srcd[localrow], dI = srcd[64+localrow];
    #pragma unroll
    for (int nt=0;nt<4;nt++){
      int col = nt*16 + lr;
      float m = xs0[(size_t)sI*64+col] + xd0[(size_t)dI*64+col];
      s0s[localrow*72+col] = (__bf16)(sacc[nt][reg]*m);
    }
  }
  __syncthreads();

  bf16x8 sa0 = *(const bf16x8*)&s0s[(w*16+lr)*72 + lg*8];
  bf16x8 sa1 = *(const bf16x8*)&s0s[(w*16+lr)*72 + 32 + lg*8];

  // ---- logits: two halves of W_alpha (128 cols each) ----
  #pragma unroll
  for (int half=0;half<2;half++){
    for (int i=tid;i<8192;i+=256){
      int k=i>>7, j=i&127;   // coalesced read of Wa[k][half*128+j]
      wbuf[j*72+k] = (__bf16)W_alpha[(size_t)k*256 + half*128 + j];
    }
    __syncthreads();
    float lg0[4]={0.f,0.f,0.f,0.f}, lg1[4]={0.f,0.f,0.f,0.f};
    #pragma unroll
    for (int nt=0;nt<8;nt++){
      f32x4 tacc = (f32x4){0.f,0.f,0.f,0.f};
      bf16x8 b0 = *(const bf16x8*)&wbuf[(nt*16+lr)*72 + lg*8];
      bf16x8 b1 = *(const bf16x8*)&wbuf[(nt*16+lr)*72 + 32 + lg*8];
      tacc = __builtin_amdgcn_mfma_f32_16x16x32_bf16(sa0, b0, tacc, 0, 0, 0);
      tacc = __builtin_amdgcn_mfma_f32_16x16x32_bf16(sa1, b1, tacc, 0, 0, 0);
      int gj = half*128 + nt*16 + lr;
      float vaj = va_l[gj];
      #pragma unroll
      for (int reg=0;reg<4;reg++){
        float t = tacc[reg];
        t = (t>0.0f) ? t : 0.2f*t;
        if (nt<4) lg0[reg] += t*vaj; else lg1[reg] += t*vaj;
      }
    }
    // reduce over the 16 cols (lane&15 dimension)
    #pragma unroll
    for (int reg=0;reg<4;reg++){
      #pragma unroll
      for (int m=1;m<16;m<<=1){
        lg0[reg] += __shfl_xor(lg0[reg], m);
        lg1[reg] += __shfl_xor(lg1[reg], m);
      }
    }
    if (lr==0){
      #pragma unroll
      for (int reg=0;reg<4;reg++){
        int e = eb + w*16 + lg*4 + reg;
        logits_g[(size_t)e*4 + half*2 + 0] = lg0[reg];
        logits_g[(size_t)e*4 + half*2 + 1] = lg1[reg];
      }
    }
    __syncthreads();
  }

  // ---- v0 = s0 @ Wv ----
  for (int i=tid;i<4096;i+=256){
    int k=i>>6, c=i&63;
    wbuf[c*72+k] = (__bf16)Wv[(size_t)k*64+c];
  }
  __syncthreads();
  #pragma unroll
  for (int nt=0;nt<4;nt++){
    f32x4 vacc = (f32x4){0.f,0.f,0.f,0.f};
    bf16x8 b0 = *(const bf16x8*)&wbuf[(nt*16+lr)*72 + lg*8];
    bf16x8 b1 = *(const bf16x8*)&wbuf[(nt*16+lr)*72 + 32 + lg*8];
    vacc = __builtin_amdgcn_mfma_f32_16x16x32_bf16(sa0, b0, vacc, 0, 0, 0);
    vacc = __builtin_amdgcn_mfma_f32_16x16x32_bf16(sa1, b1, vacc, 0, 0, 0);
    #pragma unroll
    for (int reg=0;reg<4;reg++){
      int e = eb + w*16 + lg*4 + reg;
      v0g[(size_t)e*64 + nt*16 + lr] = vacc[reg];
    }
  }
}

// ---------- per-node softmax + aggregation + x1 = x + agg@W_o (grid NN x 256) ----------
__global__ void __launch_bounds__(256) k_agg(const int* __restrict__ off, const int* __restrict__ csr,
                       const int* __restrict__ ei,
                       const float* __restrict__ logits_g, const float* __restrict__ v0g,
                       const float* __restrict__ vs, const float* __restrict__ vd,
                       const float* __restrict__ x, const float* __restrict__ Wo,
                       float* __restrict__ out){
  __shared__ float aggl[1024];
  __shared__ float alph[MAXDEG*HH];
  __shared__ int   eidl[MAXDEG];
  __shared__ int   srcl[MAXDEG];
  __shared__ float salpha[HH];
  int n = blockIdx.x;
  int o0 = off[n];
  int deg = off[n+1]-o0;
  if (deg > MAXDEG) deg = MAXDEG;
  if ((int)threadIdx.x < deg){
    int e = csr[o0+threadIdx.x];
    eidl[threadIdx.x]=e;
    srcl[threadIdx.x]=ei[e];
    #pragma unroll
    for (int h=0;h<HH;h++) alph[threadIdx.x*HH+h]=logits_g[(size_t)e*HH+h];
  }
  __syncthreads();
  if (threadIdx.x < HH){
    int h = threadIdx.x;
    float m = -1e30f;
    for (int i=0;i<deg;i++) m = fmaxf(m, alph[i*HH+h]);
    float ds = 0.0f;
    for (int i=0;i<deg;i++){ float w = expf(alph[i*HH+h]-m); alph[i*HH+h]=w; ds += w; }
    float inv = 1.0f/(ds+1e-9f);
    for (int i=0;i<deg;i++) alph[i*HH+h] *= inv;
    salpha[h] = ds*inv;
  }
  __syncthreads();
  int c = threadIdx.x & 63;
  int wg = threadIdx.x >> 6;
  int h = c >> 4;
  for (int lp=wg; lp<16; lp+=4){
    float acc = 0.0f;
    if (lp==0){
      for (int i=0;i<deg;i++) acc += alph[i*HH+h]*v0g[(size_t)eidl[i]*64+c];
    } else {
      for (int i=0;i<deg;i++) acc += alph[i*HH+h]*vs[(size_t)srcl[i]*1024 + lp*64 + c];
      acc += salpha[h]*vd[(size_t)n*1024 + lp*64 + c];
    }
    aggl[lp*64+c]=acc;
  }
  __syncthreads();
  for (int idx=threadIdx.x; idx<1024; idx+=256){
    int l = idx>>6, cc = idx&63;
    float acc = x[(size_t)n*1024+idx];
    const float* ar = &aggl[l*64];
    #pragma unroll 8
    for (int k=0;k<64;k++) acc += ar[k]*Wo[k*64+cc];
    out[(size_t)n*1024+idx]=acc;
  }
}

// ---------- FFN with bf16 MFMA: 4 nodes (64 SH rows) per block, grid 2000x256 ----------
__global__ void __launch_bounds__(256) k_ffn(const float* __restrict__ x1,
                       const float* __restrict__ Wg, const float* __restrict__ Wh,
                       const float* __restrict__ Wf, float* __restrict__ out){
  __shared__ __bf16 Abuf[64*72];    // y bf16, row stride 72 (144B, bank step 4)
  __shared__ __bf16 WhT[128*72];    // Wh transposed [n][k]
  __shared__ __bf16 Hbuf[64*136];   // hidden (gated) bf16, stride 136 (272B)
  __shared__ __bf16 WfT[64*136];    // Wf transposed [n][k]
  __shared__ float  gl[512];        // gate per node (4 x 128)
  __shared__ float  scl[4];
  int tid = threadIdx.x;
  int l = tid & 63, w = tid >> 6;
  const size_t base = (size_t)blockIdx.x*4096;
  const float* xb = x1 + base;

  // --- phase 1: per-node rms (wave w handles node w) ---
  {
    const float4* xp = (const float4*)(xb + w*1024);
    float ss = 0.0f;
    #pragma unroll
    for (int i=0;i<4;i++){
      float4 v = xp[l + 64*i];
      ss += v.x*v.x + v.y*v.y + v.z*v.z + v.w*v.w;
    }
    #pragma unroll
    for (int m=32;m>=1;m>>=1) ss += __shfl_xor(ss, m);
    if (l==0) scl[w] = 1.0f/sqrtf(ss*(1.0f/1024.0f) + 1e-6f);
  }
  __syncthreads();

  // --- phase 2: fill A (y bf16), WhT, WfT, gate ---
  for (int i=tid; i<1024; i+=256){     // float4 index over 4096 y values
    int m = i>>4, k4 = (i&15)*4;
    float s = scl[m>>4];
    float4 v = ((const float4*)xb)[i];
    __bf16* ap = &Abuf[m*72 + k4];
    ap[0]=(__bf16)(v.x*s); ap[1]=(__bf16)(v.y*s); ap[2]=(__bf16)(v.z*s); ap[3]=(__bf16)(v.w*s);
  }
  for (int i=tid; i<8192; i+=256){ int k=i>>7, nn=i&127; WhT[nn*72+k]  = (__bf16)Wh[i]; }
  for (int i=tid; i<8192; i+=256){ int k=i>>6, nn=i&63;  WfT[nn*136+k] = (__bf16)Wf[i]; }
  {
    // gate: g[nd][c] = silu(scl[nd] * sum_k x1[nd][0][k] Wg[k][c]); thread does 2 nodes
    int c = tid & 127;
    int half = tid >> 7;
    const float* xr0 = xb + (half*2)*1024;
    const float* xr1 = xr0 + 1024;
    float a0=0.0f, a1=0.0f;
    #pragma unroll 8
    for (int k=0;k<64;k++){
      float wgv = Wg[k*128 + c];
      a0 += xr0[k]*wgv; a1 += xr1[k]*wgv;
    }
    gl[(half*2)*128 + c]   = silu_f(a0*scl[half*2]);
    gl[(half*2+1)*128 + c] = silu_f(a1*scl[half*2+1]);
  }
  __syncthreads();

  // --- phase 3: H[64,128] = A[64,64] @ Wh[64,128], gate, -> bf16 LDS ---
  int lr = l & 15;   // row (A) / col (B)
  int lg = l >> 4;   // k-chunk
  {
    bf16x8 a0 = *(const bf16x8*)&Abuf[(w*16 + lr)*72 +      lg*8];
    bf16x8 a1 = *(const bf16x8*)&Abuf[(w*16 + lr)*72 + 32 + lg*8];
    f32x4 acc[8];
    #pragma unroll
    for (int nt=0;nt<8;nt++) acc[nt] = (f32x4){0.f,0.f,0.f,0.f};
    #pragma unroll
    for (int nt=0;nt<8;nt++){
      bf16x8 b0 = *(const bf16x8*)&WhT[(nt*16 + lr)*72 +      lg*8];
      bf16x8 b1 = *(const bf16x8*)&WhT[(nt*16 + lr)*72 + 32 + lg*8];
      acc[nt] = __builtin_amdgcn_mfma_f32_16x16x32_bf16(a0, b0, acc[nt], 0, 0, 0);
      acc[nt] = __builtin_amdgcn_mfma_f32_16x16x32_bf16(a1, b1, acc[nt], 0, 0, 0);
    }
    #pragma unroll
    for (int nt=0;nt<8;nt++){
      int colj = nt*16 + lr;
      float g = gl[w*128 + colj];
      #pragma unroll
      for (int r=0;r<4;r++){
        int row = lg*4 + r;
        Hbuf[(w*16+row)*136 + colj] = (__bf16)(acc[nt][r]*g);
      }
    }
  }
  __syncthreads();

  // --- phase 4: OUT[64,64] = H[64,128] @ Wf[128,64] + x1 ---
  {
    f32x4 o[4];
    #pragma unroll
    for (int nt=0;nt<4;nt++) o[nt] = (f32x4){0.f,0.f,0.f,0.f};
    #pragma unroll
    for (int kc=0;kc<4;kc++){
      bf16x8 a = *(const bf16x8*)&Hbuf[(w*16 + lr)*136 + kc*32 + lg*8];
      #pragma unroll
      for (int nt=0;nt<4;nt++){
        bf16x8 b = *(const bf16x8*)&WfT[(nt*16 + lr)*136 + kc*32 + lg*8];
        o[nt] = __builtin_amdgcn_mfma_f32_16x16x32_bf16(a, b, o[nt], 0, 0, 0);
      }
    }
    #pragma unroll
    for (int nt=0;nt<4;nt++){
      int col = nt*16 + lr;
      #pragma unroll
      for (int r=0;r<4;r++){
        int row = w*16 + lg*4 + r;
        out[base + row*64 + col] = xb[row*64 + col] + o[nt][r];
      }
    }
  }
}

extern "C" void kernel_launch(void* const* d_in, const int* in_sizes, int n_in,
                              void* d_out, int out_size, void* d_ws, size_t ws_size,
                              hipStream_t stream) {
  (void)in_sizes; (void)n_in; (void)out_size; (void)ws_size;
  const float* pos = (const float*)d_in[0];
  const float* x   = (const float*)d_in[1];
  const float* Wsrc= (const float*)d_in[2];
  const float* Wdst= (const float*)d_in[3];
  const float* W1  = (const float*)d_in[4];
  const float* b1  = (const float*)d_in[5];
  const float* W2  = (const float*)d_in[6];
  const float* b2  = (const float*)d_in[7];
  const float* We  = (const float*)d_in[8];
  const float* Wa  = (const float*)d_in[9];
  const float* va  = (const float*)d_in[10];
  const float* Wv  = (const float*)d_in[11];
  const float* Wo  = (const float*)d_in[12];
  const float* Wg  = (const float*)d_in[13];
  const float* Wh  = (const float*)d_in[14];
  const float* Wf  = (const float*)d_in[15];
  const int*   ei  = (const int*)d_in[16];
  float* out = (float*)d_out;

  char* wp = (char*)d_ws;
  auto alloc = [&](size_t elems)->char*{
    char* p = wp;
    wp += ((elems*4 + 255)/256)*256;
    return p;
  };
  float* rms1 = (float*)alloc(NN);
  float* wsv  = (float*)alloc(4096);
  float* wdv  = (float*)alloc(4096);
  float* xs0  = (float*)alloc((size_t)NN*64);
  float* xd0  = (float*)alloc((size_t)NN*64);
  float* vs   = (float*)alloc((size_t)NN*1024);
  float* vd   = (float*)alloc((size_t)NN*1024);
  float* e2g  = (float*)alloc((size_t)EE*ECH);
  float* v0g  = (float*)alloc((size_t)EE*64);
  float* lgts = (float*)alloc((size_t)EE*HH);
  int* deg    = (int*)alloc(NN);
  int* cursor = (int*)alloc(NN);
  int* off    = (int*)alloc(NN+1);
  int* csr    = (int*)alloc(EE);

  hipMemsetAsync(deg, 0, NN*sizeof(int), stream);
  hipMemsetAsync(cursor, 0, NN*sizeof(int), stream);

  k_fusew<<<32,256,0,stream>>>(Wsrc,Wdst,Wv,wsv,wdv);
  k_rms<<<NN,256,0,stream>>>(x,rms1);
  k_node0<<<NN*64/256,256,0,stream>>>(x,rms1,Wsrc,Wdst,xs0,xd0);
  k_node1<<<NN*16/64,256,0,stream>>>(x,rms1,wsv,wdv,vs,vd);
  k_edgeA<<<EE/256,256,0,stream>>>(pos,ei,W1,b1,W2,b2,e2g);
  k_hist<<<EE/256,256,0,stream>>>(ei,deg);
  k_scan<<<1,1024,0,stream>>>(deg,off);
  k_fill<<<EE/256,256,0,stream>>>(ei,off,cursor,csr);
  k_edgeB<<<EE/64,256,0,stream>>>(e2g,ei,xs0,xd0,We,Wa,va,Wv,lgts,v0g);
  k_agg<<<NN,256,0,stream>>>(off,csr,ei,lgts,v0g,vs,vd,x,Wo,out);
  k_ffn<<<NN/4,256,0,stream>>>(out,Wg,Wh,Wf,out);
}

// Round 5
// 273.279 us; speedup vs baseline: 4.2461x; 1.2589x over previous
//
#include <hip/hip_runtime.h>
#include <math.h>

// Problem constants (match reference file)
#define NN 8000
#define EE 96000
#define HH 4
#define NBASIS 256
#define ECH 48
#define FFNH 128
#define CUTOFF_R 0.0792f
#define PI_F 3.14159265358979323846f
#define SPACING (CUTOFF_R/255.0f)
#define INV_STD (256.0f/CUTOFF_R)
#define MAXDEG 96
#define W1S 52   // padded LDS stride for W1 rows

typedef __bf16 bf16x8 __attribute__((ext_vector_type(8)));
typedef __bf16 bf16x4 __attribute__((ext_vector_type(4)));
typedef float  f32x4  __attribute__((ext_vector_type(4)));

__device__ __forceinline__ float silu_f(float x){ return x/(1.0f+expf(-x)); }

// ---------- fused weights: wsv = W_src@W_v, wdv = W_dst@W_v  (grid 32x256) ----------
__global__ void k_fusew(const float* __restrict__ Wsrc, const float* __restrict__ Wdst,
                        const float* __restrict__ Wv,
                        float* __restrict__ wsv, float* __restrict__ wdv){
  int gid = blockIdx.x*256 + threadIdx.x;
  int which = gid >> 12;
  int idx = gid & 4095;
  int r = idx >> 6, c = idx & 63;
  const float* A = which ? Wdst : Wsrc;
  float acc = 0.0f;
  #pragma unroll
  for (int k=0;k<64;k++) acc += A[r*64+k]*Wv[k*64+c];
  (which ? wdv : wsv)[idx] = acc;
}

// ---------- rms scale per node (grid NN x 256) ----------
__global__ void __launch_bounds__(256) k_rms(const float* __restrict__ x, float* __restrict__ rms1){
  int n = blockIdx.x;
  float4 v = ((const float4*)(x + (size_t)n*1024))[threadIdx.x];
  float ss = v.x*v.x+v.y*v.y+v.z*v.z+v.w*v.w;
  #pragma unroll
  for (int m=32;m>=1;m>>=1) ss += __shfl_xor(ss, m);
  __shared__ float red[4];
  if ((threadIdx.x & 63)==0) red[threadIdx.x>>6]=ss;
  __syncthreads();
  if (threadIdx.x==0)
    rms1[n] = 1.0f/sqrtf((red[0]+red[1]+red[2]+red[3])*(1.0f/1024.0f)+1e-6f);
}

// ---------- xs0[n,c], xd0[n,c] : l=0 row through W_src/W_dst (grid 2000x256) ----------
__global__ void __launch_bounds__(256) k_node0(const float* __restrict__ x, const float* __restrict__ rms1,
                        const float* __restrict__ Wsrc, const float* __restrict__ Wdst,
                        float* __restrict__ xs0, float* __restrict__ xd0){
  int t = blockIdx.x*256 + threadIdx.x;
  int n = t>>6, c = t&63;
  float sc = rms1[n];
  const float* xr = x + (size_t)n*1024;   // l = 0 row
  float as=0.0f, ad=0.0f;
  #pragma unroll 8
  for (int k=0;k<64;k++){
    float xv = xr[k]*sc;
    as += xv*Wsrc[k*64+c];
    ad += xv*Wdst[k*64+c];
  }
  xs0[t]=as; xd0[t]=ad;
}

// ---------- vs = xn@wsv, vd = xn@wdv over all rows N*L, bf16 out (grid 2000x256) ----------
__global__ void __launch_bounds__(256) k_node1(const float* __restrict__ x, const float* __restrict__ rms1,
                        const float* __restrict__ wsv, const float* __restrict__ wdv,
                        __bf16* __restrict__ vs, __bf16* __restrict__ vd){
  __shared__ float xt[64*65];
  __shared__ float wa[4096];
  __shared__ float wb[4096];
  int base = blockIdx.x*64;
  for (int i=threadIdx.x;i<4096;i+=256){
    int r = i>>6, k = i&63;
    int row = base + r;
    xt[r*65+k] = x[(size_t)row*64+k]*rms1[row>>4];
    wa[i] = wsv[i]; wb[i] = wdv[i];
  }
  __syncthreads();
  int r = threadIdx.x>>2, cg = threadIdx.x&3;
  float as[16], ad[16];
  #pragma unroll
  for (int j=0;j<16;j++){ as[j]=0.0f; ad[j]=0.0f; }
  for (int k=0;k<64;k++){
    float a = xt[r*65+k];
    const float* w1p = &wa[k*64+cg*16];
    const float* w2p = &wb[k*64+cg*16];
    #pragma unroll
    for (int j=0;j<16;j++){ as[j] += a*w1p[j]; ad[j] += a*w2p[j]; }
  }
  int row = base + r;
  __bf16* vsp = vs + (size_t)row*64 + cg*16;
  __bf16* vdp = vd + (size_t)row*64 + cg*16;
  #pragma unroll
  for (int j=0;j<16;j+=4){
    bf16x4 t1 = {(__bf16)as[j],(__bf16)as[j+1],(__bf16)as[j+2],(__bf16)as[j+3]};
    bf16x4 t2 = {(__bf16)ad[j],(__bf16)ad[j+1],(__bf16)ad[j+2],(__bf16)ad[j+3]};
    *(bf16x4*)(vsp+j) = t1;
    *(bf16x4*)(vdp+j) = t2;
  }
}

// ---------- edge RBF + 2-layer MLP -> e2[E,48] (grid 375x256) ----------
__global__ void __launch_bounds__(256) k_edgeA(const float* __restrict__ pos, const int* __restrict__ ei,
                        const float* __restrict__ W1, const float* __restrict__ b1,
                        const float* __restrict__ W2, const float* __restrict__ b2,
                        float* __restrict__ e2g){
  __shared__ float w1[NBASIS*W1S];
  __shared__ float w2[ECH*ECH];
  __shared__ float b1l[ECH], b2l[ECH];
  for (int i=threadIdx.x;i<NBASIS*ECH;i+=256){ int k=i/ECH, j=i-k*ECH; w1[k*W1S+j]=W1[i]; }
  for (int i=threadIdx.x;i<ECH*ECH;i+=256) w2[i]=W2[i];
  if (threadIdx.x<ECH){ b1l[threadIdx.x]=b1[threadIdx.x]; b2l[threadIdx.x]=b2[threadIdx.x]; }
  __syncthreads();
  int e = blockIdx.x*256 + threadIdx.x;   // grid exactly covers EE
  int s = ei[e], t = ei[EE+e];
  float dx = pos[3*s]-pos[3*t], dy = pos[3*s+1]-pos[3*t+1], dz = pos[3*s+2]-pos[3*t+2];
  float d = sqrtf(dx*dx+dy*dy+dz*dz+1e-12f);
  float acc[ECH];
  #pragma unroll
  for (int j=0;j<ECH;j++) acc[j]=b1l[j];
  if (d < CUTOFF_R){
    float env = 0.5f*(cosf(PI_F*(d/CUTOFF_R))+1.0f);
    int j0 = (int)floorf(d/SPACING);
    int klo = j0-9 > 0 ? j0-9 : 0;
    int khi = j0+10 < NBASIS-1 ? j0+10 : NBASIS-1;
    for (int k=klo;k<=khi;k++){
      float del = (d - k*SPACING)*INV_STD;
      float g = expf(-0.5f*del*del)*env;
      const float* wr = &w1[k*W1S];
      #pragma unroll
      for (int j=0;j<ECH;j++) acc[j] += g*wr[j];
    }
  }
  float e1[ECH];
  #pragma unroll
  for (int j=0;j<ECH;j++) e1[j] = silu_f(acc[j]);
  float* outp = e2g + (size_t)e*ECH;
  for (int j4=0;j4<ECH;j4+=4){
    float o[4];
    #pragma unroll
    for (int jj=0;jj<4;jj++){
      float a2 = b2l[j4+jj];
      #pragma unroll
      for (int k=0;k<ECH;k++) a2 += e1[k]*w2[k*ECH+j4+jj];
      o[jj] = silu_f(a2);
    }
    ((float4*)(outp+j4))[0] = make_float4(o[0],o[1],o[2],o[3]);
  }
}

// ---------- CSR build ----------
__global__ void k_hist(const int* __restrict__ ei, int* __restrict__ deg){
  int e = blockIdx.x*256 + threadIdx.x;
  atomicAdd(&deg[ei[EE+e]], 1);
}

__global__ void __launch_bounds__(1024) k_scan(const int* __restrict__ deg, int* __restrict__ off){
  __shared__ int sums[1024];
  int t = threadIdx.x;
  int base = t*8;
  int loc[8]; int s=0;
  #pragma unroll
  for (int i=0;i<8;i++){ int idx=base+i; int v = (idx<NN)? deg[idx]:0; loc[i]=v; s+=v; }
  sums[t]=s;
  __syncthreads();
  for (int d=1; d<1024; d<<=1){
    int v = (t>=d)? sums[t-d]:0;
    __syncthreads();
    sums[t] += v;
    __syncthreads();
  }
  int run = sums[t]-s;
  #pragma unroll
  for (int i=0;i<8;i++){ int idx=base+i; if (idx<NN) off[idx]=run; run+=loc[i]; }
  if (t==1023) off[NN]=sums[1023];
}

__global__ void k_fill(const int* __restrict__ ei, const int* __restrict__ off,
                       int* __restrict__ cursor, int* __restrict__ csr){
  int e = blockIdx.x*256 + threadIdx.x;
  int d = ei[EE+e];
  int slot = off[d] + atomicAdd(&cursor[d],1);
  csr[slot]=e;
}

// ---------- per-edge MFMA: s0 = (e2@We)*(xs0[s]+xd0[d]); logits = lrelu(s0@Wa)·va; v0 = s0@Wv
// 64 edges/block, 4 waves. grid 1500x256
__global__ void __launch_bounds__(256) k_edgeB(const float* __restrict__ e2g, const int* __restrict__ ei,
                        const float* __restrict__ xs0, const float* __restrict__ xd0,
                        const float* __restrict__ W_edge, const float* __restrict__ W_alpha,
                        const float* __restrict__ v_alpha, const float* __restrict__ Wv,
                        float* __restrict__ logits_g, __bf16* __restrict__ v0g){
  __shared__ __bf16 e2s[64*72];    // edges x k (48 padded to 64), stride 72
  __shared__ __bf16 s0s[64*72];
  __shared__ __bf16 wbuf[128*72];  // reused: WeT / WaT half / WvT, rows = out-col, cols = k
  __shared__ float  va_l[256];
  __shared__ int    srcd[128];     // [0:64) src, [64:128) dst
  int tid = threadIdx.x;
  int w = tid >> 6, l = tid & 63;
  int lr = l & 15, lg = l >> 4;
  int eb = blockIdx.x * 64;

  // ---- stage e2 (zero-padded K), WeT, va, src/dst ----
  for (int i=tid;i<4096;i+=256){
    int r=i>>6, k=i&63;
    e2s[r*72+k] = (k<ECH) ? (__bf16)e2g[(size_t)(eb+r)*ECH+k] : (__bf16)0.f;
  }
  for (int i=tid;i<4096;i+=256){
    int k=i>>6, c=i&63;    // coalesced read of We[k][c]
    wbuf[c*72+k] = (k<ECH) ? (__bf16)W_edge[(size_t)k*64+c] : (__bf16)0.f;
  }
  va_l[tid] = v_alpha[tid];
  if (tid<64){ srcd[tid]=ei[eb+tid]; srcd[64+tid]=ei[EE+eb+tid]; }
  __syncthreads();

  // ---- s0_pre = e2 @ We ----
  bf16x8 ea0 = *(const bf16x8*)&e2s[(w*16+lr)*72 + lg*8];
  bf16x8 ea1 = *(const bf16x8*)&e2s[(w*16+lr)*72 + 32 + lg*8];
  f32x4 sacc[4];
  #pragma unroll
  for (int nt=0;nt<4;nt++){
    sacc[nt] = (f32x4){0.f,0.f,0.f,0.f};
    bf16x8 b0 = *(const bf16x8*)&wbuf[(nt*16+lr)*72 + lg*8];
    bf16x8 b1 = *(const bf16x8*)&wbuf[(nt*16+lr)*72 + 32 + lg*8];
    sacc[nt] = __builtin_amdgcn_mfma_f32_16x16x32_bf16(ea0, b0, sacc[nt], 0, 0, 0);
    sacc[nt] = __builtin_amdgcn_mfma_f32_16x16x32_bf16(ea1, b1, sacc[nt], 0, 0, 0);
  }
  // ---- gather (xs0[src]+xd0[dst]) and scale; write s0 bf16 ----
  #pragma unroll
  for (int reg=0;reg<4;reg++){
    int localrow = w*16 + lg*4 + reg;
    int sI = srcd[localrow], dI = srcd[64+localrow];
    #pragma unroll
    for (int nt=0;nt<4;nt++){
      int col = nt*16 + lr;
      float m = xs0[(size_t)sI*64+col] + xd0[(size_t)dI*64+col];
      s0s[localrow*72+col] = (__bf16)(sacc[nt][reg]*m);
    }
  }
  __syncthreads();

  bf16x8 sa0 = *(const bf16x8*)&s0s[(w*16+lr)*72 + lg*8];
  bf16x8 sa1 = *(const bf16x8*)&s0s[(w*16+lr)*72 + 32 + lg*8];

  // ---- logits: two halves of W_alpha (128 cols each) ----
  #pragma unroll
  for (int half=0;half<2;half++){
    for (int i=tid;i<8192;i+=256){
      int k=i>>7, j=i&127;   // coalesced read of Wa[k][half*128+j]
      wbuf[j*72+k] = (__bf16)W_alpha[(size_t)k*256 + half*128 + j];
    }
    __syncthreads();
    float lg0[4]={0.f,0.f,0.f,0.f}, lg1[4]={0.f,0.f,0.f,0.f};
    #pragma unroll
    for (int nt=0;nt<8;nt++){
      f32x4 tacc = (f32x4){0.f,0.f,0.f,0.f};
      bf16x8 b0 = *(const bf16x8*)&wbuf[(nt*16+lr)*72 + lg*8];
      bf16x8 b1 = *(const bf16x8*)&wbuf[(nt*16+lr)*72 + 32 + lg*8];
      tacc = __builtin_amdgcn_mfma_f32_16x16x32_bf16(sa0, b0, tacc, 0, 0, 0);
      tacc = __builtin_amdgcn_mfma_f32_16x16x32_bf16(sa1, b1, tacc, 0, 0, 0);
      int gj = half*128 + nt*16 + lr;
      float vaj = va_l[gj];
      #pragma unroll
      for (int reg=0;reg<4;reg++){
        float t = tacc[reg];
        t = (t>0.0f) ? t : 0.2f*t;
        if (nt<4) lg0[reg] += t*vaj; else lg1[reg] += t*vaj;
      }
    }
    // reduce over the 16 cols (lane&15 dimension)
    #pragma unroll
    for (int reg=0;reg<4;reg++){
      #pragma unroll
      for (int m=1;m<16;m<<=1){
        lg0[reg] += __shfl_xor(lg0[reg], m);
        lg1[reg] += __shfl_xor(lg1[reg], m);
      }
    }
    if (lr==0){
      #pragma unroll
      for (int reg=0;reg<4;reg++){
        int e = eb + w*16 + lg*4 + reg;
        logits_g[(size_t)e*4 + half*2 + 0] = lg0[reg];
        logits_g[(size_t)e*4 + half*2 + 1] = lg1[reg];
      }
    }
    __syncthreads();
  }

  // ---- v0 = s0 @ Wv (bf16 out) ----
  for (int i=tid;i<4096;i+=256){
    int k=i>>6, c=i&63;
    wbuf[c*72+k] = (__bf16)Wv[(size_t)k*64+c];
  }
  __syncthreads();
  #pragma unroll
  for (int nt=0;nt<4;nt++){
    f32x4 vacc = (f32x4){0.f,0.f,0.f,0.f};
    bf16x8 b0 = *(const bf16x8*)&wbuf[(nt*16+lr)*72 + lg*8];
    bf16x8 b1 = *(const bf16x8*)&wbuf[(nt*16+lr)*72 + 32 + lg*8];
    vacc = __builtin_amdgcn_mfma_f32_16x16x32_bf16(sa0, b0, vacc, 0, 0, 0);
    vacc = __builtin_amdgcn_mfma_f32_16x16x32_bf16(sa1, b1, vacc, 0, 0, 0);
    #pragma unroll
    for (int reg=0;reg<4;reg++){
      int e = eb + w*16 + lg*4 + reg;
      v0g[(size_t)e*64 + nt*16 + lr] = (__bf16)vacc[reg];
    }
  }
}

// ---------- per-node softmax + coalesced bf16 gather + MFMA Wo epilogue (grid NN x 256) ----------
__global__ void __launch_bounds__(256) k_agg(const int* __restrict__ off, const int* __restrict__ csr,
                       const int* __restrict__ ei,
                       const float* __restrict__ logits_g, const __bf16* __restrict__ v0g,
                       const __bf16* __restrict__ vs, const __bf16* __restrict__ vd,
                       const float* __restrict__ x, const float* __restrict__ Wo,
                       float* __restrict__ out){
  __shared__ float alph[MAXDEG*HH];
  __shared__ int   eidl[MAXDEG];
  __shared__ int   srcl[MAXDEG];
  __shared__ float salpha[HH];
  __shared__ __bf16 aggb[16*72];   // agg rows (l) x 64 c, stride 72
  __shared__ __bf16 WoT[64*72];    // Wo transposed [c_out][k]
  int tid = threadIdx.x;
  int n = blockIdx.x;
  int o0 = off[n];
  int deg = off[n+1]-o0;
  if (deg > MAXDEG) deg = MAXDEG;
  if (tid < deg){
    int e = csr[o0+tid];
    eidl[tid]=e;
    srcl[tid]=ei[e];
    #pragma unroll
    for (int h=0;h<HH;h++) alph[tid*HH+h]=logits_g[(size_t)e*HH+h];
  }
  for (int i=tid;i<4096;i+=256){
    int k=i>>6, c=i&63;
    WoT[c*72+k] = (__bf16)Wo[i];
  }
  __syncthreads();
  if (tid < HH){
    int h = tid;
    float m = -1e30f;
    for (int i=0;i<deg;i++) m = fmaxf(m, alph[i*HH+h]);
    float ds = 0.0f;
    for (int i=0;i<deg;i++){ float w = expf(alph[i*HH+h]-m); alph[i*HH+h]=w; ds += w; }
    float inv = 1.0f/(ds+1e-9f);
    for (int i=0;i<deg;i++) alph[i*HH+h] *= inv;
    salpha[h] = ds*inv;
  }
  __syncthreads();
  // gather: thread owns (l = tid>>4, quad = tid&15) -> channels quad*4..quad*4+3
  {
    int l = tid>>4, quad = tid&15;
    int h = quad>>2;
    float a0=0.f,a1=0.f,a2=0.f,a3=0.f;
    if (l==0){
      for (int i=0;i<deg;i++){
        float a = alph[i*HH+h];
        bf16x4 v = *(const bf16x4*)(v0g + (size_t)eidl[i]*64 + quad*4);
        a0 += a*(float)v[0]; a1 += a*(float)v[1]; a2 += a*(float)v[2]; a3 += a*(float)v[3];
      }
    } else {
      for (int i=0;i<deg;i++){
        float a = alph[i*HH+h];
        bf16x4 v = *(const bf16x4*)(vs + (size_t)srcl[i]*1024 + tid*4);
        a0 += a*(float)v[0]; a1 += a*(float)v[1]; a2 += a*(float)v[2]; a3 += a*(float)v[3];
      }
      float sa = salpha[h];
      bf16x4 v = *(const bf16x4*)(vd + (size_t)n*1024 + tid*4);
      a0 += sa*(float)v[0]; a1 += sa*(float)v[1]; a2 += sa*(float)v[2]; a3 += sa*(float)v[3];
    }
    bf16x4 t = {(__bf16)a0,(__bf16)a1,(__bf16)a2,(__bf16)a3};
    *(bf16x4*)(&aggb[l*72 + quad*4]) = t;
  }
  __syncthreads();
  // out[16 x 64] = agg @ Wo + x ; wave w does cols w*16..w*16+15
  {
    int w = tid>>6, lane = tid&63, lr = lane&15, lg = lane>>4;
    bf16x8 a0 = *(const bf16x8*)&aggb[lr*72 + lg*8];
    bf16x8 a1 = *(const bf16x8*)&aggb[lr*72 + 32 + lg*8];
    bf16x8 b0 = *(const bf16x8*)&WoT[(w*16+lr)*72 + lg*8];
    bf16x8 b1 = *(const bf16x8*)&WoT[(w*16+lr)*72 + 32 + lg*8];
    f32x4 o = (f32x4){0.f,0.f,0.f,0.f};
    o = __builtin_amdgcn_mfma_f32_16x16x32_bf16(a0, b0, o, 0, 0, 0);
    o = __builtin_amdgcn_mfma_f32_16x16x32_bf16(a1, b1, o, 0, 0, 0);
    const float* xr = x + (size_t)n*1024;
    float* outr = out + (size_t)n*1024;
    #pragma unroll
    for (int r=0;r<4;r++){
      int row = lg*4 + r, col = w*16 + lr;
      outr[row*64 + col] = xr[row*64 + col] + o[r];
    }
  }
}

// ---------- FFN with bf16 MFMA: 4 nodes (64 SH rows) per block, grid 2000x256 ----------
__global__ void __launch_bounds__(256) k_ffn(const float* __restrict__ x1,
                       const float* __restrict__ Wg, const float* __restrict__ Wh,
                       const float* __restrict__ Wf, float* __restrict__ out){
  __shared__ __bf16 Abuf[64*72];    // y bf16, row stride 72 (144B, bank step 4)
  __shared__ __bf16 WhT[128*72];    // Wh transposed [n][k]
  __shared__ __bf16 Hbuf[64*136];   // hidden (gated) bf16, stride 136 (272B)
  __shared__ __bf16 WfT[64*136];    // Wf transposed [n][k]
  __shared__ float  gl[512];        // gate per node (4 x 128)
  __shared__ float  scl[4];
  int tid = threadIdx.x;
  int l = tid & 63, w = tid >> 6;
  const size_t base = (size_t)blockIdx.x*4096;
  const float* xb = x1 + base;

  // --- phase 1: per-node rms (wave w handles node w) ---
  {
    const float4* xp = (const float4*)(xb + w*1024);
    float ss = 0.0f;
    #pragma unroll
    for (int i=0;i<4;i++){
      float4 v = xp[l + 64*i];
      ss += v.x*v.x + v.y*v.y + v.z*v.z + v.w*v.w;
    }
    #pragma unroll
    for (int m=32;m>=1;m>>=1) ss += __shfl_xor(ss, m);
    if (l==0) scl[w] = 1.0f/sqrtf(ss*(1.0f/1024.0f) + 1e-6f);
  }
  __syncthreads();

  // --- phase 2: fill A (y bf16), WhT, WfT, gate ---
  for (int i=tid; i<1024; i+=256){     // float4 index over 4096 y values
    int m = i>>4, k4 = (i&15)*4;
    float s = scl[m>>4];
    float4 v = ((const float4*)xb)[i];
    __bf16* ap = &Abuf[m*72 + k4];
    ap[0]=(__bf16)(v.x*s); ap[1]=(__bf16)(v.y*s); ap[2]=(__bf16)(v.z*s); ap[3]=(__bf16)(v.w*s);
  }
  for (int i=tid; i<8192; i+=256){ int k=i>>7, nn=i&127; WhT[nn*72+k]  = (__bf16)Wh[i]; }
  for (int i=tid; i<8192; i+=256){ int k=i>>6, nn=i&63;  WfT[nn*136+k] = (__bf16)Wf[i]; }
  {
    // gate: g[nd][c] = silu(scl[nd] * sum_k x1[nd][0][k] Wg[k][c]); thread does 2 nodes
    int c = tid & 127;
    int half = tid >> 7;
    const float* xr0 = xb + (half*2)*1024;
    const float* xr1 = xr0 + 1024;
    float a0=0.0f, a1=0.0f;
    #pragma unroll 8
    for (int k=0;k<64;k++){
      float wgv = Wg[k*128 + c];
      a0 += xr0[k]*wgv; a1 += xr1[k]*wgv;
    }
    gl[(half*2)*128 + c]   = silu_f(a0*scl[half*2]);
    gl[(half*2+1)*128 + c] = silu_f(a1*scl[half*2+1]);
  }
  __syncthreads();

  // --- phase 3: H[64,128] = A[64,64] @ Wh[64,128], gate, -> bf16 LDS ---
  int lr = l & 15;   // row (A) / col (B)
  int lg = l >> 4;   // k-chunk
  {
    bf16x8 a0 = *(const bf16x8*)&Abuf[(w*16 + lr)*72 +      lg*8];
    bf16x8 a1 = *(const bf16x8*)&Abuf[(w*16 + lr)*72 + 32 + lg*8];
    f32x4 acc[8];
    #pragma unroll
    for (int nt=0;nt<8;nt++) acc[nt] = (f32x4){0.f,0.f,0.f,0.f};
    #pragma unroll
    for (int nt=0;nt<8;nt++){
      bf16x8 b0 = *(const bf16x8*)&WhT[(nt*16 + lr)*72 +      lg*8];
      bf16x8 b1 = *(const bf16x8*)&WhT[(nt*16 + lr)*72 + 32 + lg*8];
      acc[nt] = __builtin_amdgcn_mfma_f32_16x16x32_bf16(a0, b0, acc[nt], 0, 0, 0);
      acc[nt] = __builtin_amdgcn_mfma_f32_16x16x32_bf16(a1, b1, acc[nt], 0, 0, 0);
    }
    #pragma unroll
    for (int nt=0;nt<8;nt++){
      int colj = nt*16 + lr;
      float g = gl[w*128 + colj];
      #pragma unroll
      for (int r=0;r<4;r++){
        int row = lg*4 + r;
        Hbuf[(w*16+row)*136 + colj] = (__bf16)(acc[nt][r]*g);
      }
    }
  }
  __syncthreads();

  // --- phase 4: OUT[64,64] = H[64,128] @ Wf[128,64] + x1 ---
  {
    f32x4 o[4];
    #pragma unroll
    for (int nt=0;nt<4;nt++) o[nt] = (f32x4){0.f,0.f,0.f,0.f};
    #pragma unroll
    for (int kc=0;kc<4;kc++){
      bf16x8 a = *(const bf16x8*)&Hbuf[(w*16 + lr)*136 + kc*32 + lg*8];
      #pragma unroll
      for (int nt=0;nt<4;nt++){
        bf16x8 b = *(const bf16x8*)&WfT[(nt*16 + lr)*136 + kc*32 + lg*8];
        o[nt] = __builtin_amdgcn_mfma_f32_16x16x32_bf16(a, b, o[nt], 0, 0, 0);
      }
    }
    #pragma unroll
    for (int nt=0;nt<4;nt++){
      int col = nt*16 + lr;
      #pragma unroll
      for (int r=0;r<4;r++){
        int row = w*16 + lg*4 + r;
        out[base + row*64 + col] = xb[row*64 + col] + o[nt][r];
      }
    }
  }
}

extern "C" void kernel_launch(void* const* d_in, const int* in_sizes, int n_in,
                              void* d_out, int out_size, void* d_ws, size_t ws_size,
                              hipStream_t stream) {
  (void)in_sizes; (void)n_in; (void)out_size; (void)ws_size;
  const float* pos = (const float*)d_in[0];
  const float* x   = (const float*)d_in[1];
  const float* Wsrc= (const float*)d_in[2];
  const float* Wdst= (const float*)d_in[3];
  const float* W1  = (const float*)d_in[4];
  const float* b1  = (const float*)d_in[5];
  const float* W2  = (const float*)d_in[6];
  const float* b2  = (const float*)d_in[7];
  const float* We  = (const float*)d_in[8];
  const float* Wa  = (const float*)d_in[9];
  const float* va  = (const float*)d_in[10];
  const float* Wv  = (const float*)d_in[11];
  const float* Wo  = (const float*)d_in[12];
  const float* Wg  = (const float*)d_in[13];
  const float* Wh  = (const float*)d_in[14];
  const float* Wf  = (const float*)d_in[15];
  const int*   ei  = (const int*)d_in[16];
  float* out = (float*)d_out;

  char* wp = (char*)d_ws;
  auto alloc = [&](size_t bytes)->char*{
    char* p = wp;
    wp += ((bytes + 255)/256)*256;
    return p;
  };
  float* rms1 = (float*)alloc((size_t)NN*4);
  float* wsv  = (float*)alloc(4096*4);
  float* wdv  = (float*)alloc(4096*4);
  float* xs0  = (float*)alloc((size_t)NN*64*4);
  float* xd0  = (float*)alloc((size_t)NN*64*4);
  __bf16* vs  = (__bf16*)alloc((size_t)NN*1024*2);
  __bf16* vd  = (__bf16*)alloc((size_t)NN*1024*2);
  float* e2g  = (float*)alloc((size_t)EE*ECH*4);
  __bf16* v0g = (__bf16*)alloc((size_t)EE*64*2);
  float* lgts = (float*)alloc((size_t)EE*HH*4);
  int* deg    = (int*)alloc((size_t)NN*4);
  int* cursor = (int*)alloc((size_t)NN*4);
  int* off    = (int*)alloc((size_t)(NN+1)*4);
  int* csr    = (int*)alloc((size_t)EE*4);

  hipMemsetAsync(deg, 0, NN*sizeof(int), stream);
  hipMemsetAsync(cursor, 0, NN*sizeof(int), stream);

  k_fusew<<<32,256,0,stream>>>(Wsrc,Wdst,Wv,wsv,wdv);
  k_rms<<<NN,256,0,stream>>>(x,rms1);
  k_node0<<<NN*64/256,256,0,stream>>>(x,rms1,Wsrc,Wdst,xs0,xd0);
  k_node1<<<NN*16/64,256,0,stream>>>(x,rms1,wsv,wdv,vs,vd);
  k_edgeA<<<EE/256,256,0,stream>>>(pos,ei,W1,b1,W2,b2,e2g);
  k_hist<<<EE/256,256,0,stream>>>(ei,deg);
  k_scan<<<1,1024,0,stream>>>(deg,off);
  k_fill<<<EE/256,256,0,stream>>>(ei,off,cursor,csr);
  k_edgeB<<<EE/64,256,0,stream>>>(e2g,ei,xs0,xd0,We,Wa,va,Wv,lgts,v0g);
  k_agg<<<NN,256,0,stream>>>(off,csr,ei,lgts,v0g,vs,vd,x,Wo,out);
  k_ffn<<<NN/4,256,0,stream>>>(out,Wg,Wh,Wf,out);
}

// Round 6
// 256.084 us; speedup vs baseline: 4.5312x; 1.0671x over previous
//
#include <hip/hip_runtime.h>
#include <math.h>

// Problem constants (match reference file)
#define NN 8000
#define EE 96000
#define HH 4
#define NBASIS 256
#define ECH 48
#define FFNH 128
#define CUTOFF_R 0.0792f
#define PI_F 3.14159265358979323846f
#define SPACING (CUTOFF_R/255.0f)
#define INV_STD (256.0f/CUTOFF_R)
#define MAXDEG 96

typedef __bf16 bf16x8 __attribute__((ext_vector_type(8)));
typedef __bf16 bf16x4 __attribute__((ext_vector_type(4)));
typedef __bf16 bf16x2 __attribute__((ext_vector_type(2)));
typedef float  f32x4  __attribute__((ext_vector_type(4)));

__device__ __forceinline__ float silu_f(float x){ return x/(1.0f+expf(-x)); }

// ---------- fused weights: wsv = W_src@W_v, wdv = W_dst@W_v  (grid 32x256) ----------
__global__ void k_fusew(const float* __restrict__ Wsrc, const float* __restrict__ Wdst,
                        const float* __restrict__ Wv,
                        float* __restrict__ wsv, float* __restrict__ wdv){
  int gid = blockIdx.x*256 + threadIdx.x;
  int which = gid >> 12;
  int idx = gid & 4095;
  int r = idx >> 6, c = idx & 63;
  const float* A = which ? Wdst : Wsrc;
  float acc = 0.0f;
  #pragma unroll
  for (int k=0;k<64;k++) acc += A[r*64+k]*Wv[k*64+c];
  (which ? wdv : wsv)[idx] = acc;
}

// ---------- rms scale per node (grid NN x 256) ----------
__global__ void __launch_bounds__(256) k_rms(const float* __restrict__ x, float* __restrict__ rms1){
  int n = blockIdx.x;
  float4 v = ((const float4*)(x + (size_t)n*1024))[threadIdx.x];
  float ss = v.x*v.x+v.y*v.y+v.z*v.z+v.w*v.w;
  #pragma unroll
  for (int m=32;m>=1;m>>=1) ss += __shfl_xor(ss, m);
  __shared__ float red[4];
  if ((threadIdx.x & 63)==0) red[threadIdx.x>>6]=ss;
  __syncthreads();
  if (threadIdx.x==0)
    rms1[n] = 1.0f/sqrtf((red[0]+red[1]+red[2]+red[3])*(1.0f/1024.0f)+1e-6f);
}

// ---------- xs0[n,c], xd0[n,c] : l=0 row through W_src/W_dst (grid 2000x256) ----------
__global__ void __launch_bounds__(256) k_node0(const float* __restrict__ x, const float* __restrict__ rms1,
                        const float* __restrict__ Wsrc, const float* __restrict__ Wdst,
                        float* __restrict__ xs0, float* __restrict__ xd0){
  int t = blockIdx.x*256 + threadIdx.x;
  int n = t>>6, c = t&63;
  float sc = rms1[n];
  const float* xr = x + (size_t)n*1024;   // l = 0 row
  float as=0.0f, ad=0.0f;
  #pragma unroll 8
  for (int k=0;k<64;k++){
    float xv = xr[k]*sc;
    as += xv*Wsrc[k*64+c];
    ad += xv*Wdst[k*64+c];
  }
  xs0[t]=as; xd0[t]=ad;
}

// ---------- vs = xn@wsv, vd = xn@wdv over all rows N*L, bf16 out (grid 2000x256) ----------
__global__ void __launch_bounds__(256) k_node1(const float* __restrict__ x, const float* __restrict__ rms1,
                        const float* __restrict__ wsv, const float* __restrict__ wdv,
                        __bf16* __restrict__ vs, __bf16* __restrict__ vd){
  __shared__ float xt[64*65];
  __shared__ float wa[4096];
  __shared__ float wb[4096];
  int base = blockIdx.x*64;
  for (int i=threadIdx.x;i<4096;i+=256){
    int r = i>>6, k = i&63;
    int row = base + r;
    xt[r*65+k] = x[(size_t)row*64+k]*rms1[row>>4];
    wa[i] = wsv[i]; wb[i] = wdv[i];
  }
  __syncthreads();
  int r = threadIdx.x>>2, cg = threadIdx.x&3;
  float as[16], ad[16];
  #pragma unroll
  for (int j=0;j<16;j++){ as[j]=0.0f; ad[j]=0.0f; }
  for (int k=0;k<64;k++){
    float a = xt[r*65+k];
    const float* w1p = &wa[k*64+cg*16];
    const float* w2p = &wb[k*64+cg*16];
    #pragma unroll
    for (int j=0;j<16;j++){ as[j] += a*w1p[j]; ad[j] += a*w2p[j]; }
  }
  int row = base + r;
  __bf16* vsp = vs + (size_t)row*64 + cg*16;
  __bf16* vdp = vd + (size_t)row*64 + cg*16;
  #pragma unroll
  for (int j=0;j<16;j+=4){
    bf16x4 t1 = {(__bf16)as[j],(__bf16)as[j+1],(__bf16)as[j+2],(__bf16)as[j+3]};
    bf16x4 t2 = {(__bf16)ad[j],(__bf16)ad[j+1],(__bf16)ad[j+2],(__bf16)ad[j+3]};
    *(bf16x4*)(vsp+j) = t1;
    *(bf16x4*)(vdp+j) = t2;
  }
}

// ---------- edge RBF + 2-layer MLP via MFMA: 64 edges/block, grid 1500x256 ----------
// G[64,256] built per-lane in registers (dense 256-tap gaussian*env, exact reference math),
// e1 = silu(G@W1 + b1)  (MFMA, K=256),  e2 = silu(e1@W2 + b2)  (MFMA, K=48 pad 64) -> bf16
__global__ void __launch_bounds__(256) k_edgeA(const float* __restrict__ pos, const int* __restrict__ ei,
                        const float* __restrict__ W1, const float* __restrict__ b1,
                        const float* __restrict__ W2, const float* __restrict__ b2,
                        __bf16* __restrict__ e2g){
  __shared__ __bf16 W1T[48*264];   // [j][k] stride 264
  __shared__ __bf16 W2T[64*72];    // [j][k] stride 72 (k>=48 zero)
  __shared__ __bf16 e1s[64*72];    // [edge][k] stride 72 (k>=48 zeroed)
  __shared__ float dl[64], envl[64];
  int tid = threadIdx.x;
  int w = tid>>6, l = tid&63, lr = l&15, lg = l>>4;
  int eb = blockIdx.x*64;

  if (tid < 64){
    int s = ei[eb+tid], t = ei[EE+eb+tid];
    float dx = pos[3*s]-pos[3*t], dy = pos[3*s+1]-pos[3*t+1], dz = pos[3*s+2]-pos[3*t+2];
    float d = sqrtf(dx*dx+dy*dy+dz*dz+1e-12f);
    dl[tid] = d;
    envl[tid] = 0.5f*(cosf(PI_F*fminf(d*(1.0f/CUTOFF_R),1.0f))+1.0f);
  }
  // stage W1T (pairs along k for b32 writes); reads coalesced over j
  for (int i=tid;i<48*128;i+=256){
    int kp = i/48, j = i - kp*48;
    bf16x2 p = {(__bf16)W1[(size_t)(2*kp)*48 + j], (__bf16)W1[(size_t)(2*kp+1)*48 + j]};
    *(bf16x2*)&W1T[j*264 + 2*kp] = p;
  }
  // stage W2T with zero pad
  for (int i=tid;i<4096;i+=256){
    int k=i>>6, j=i&63;
    W2T[j*72+k] = (j<ECH && k<ECH) ? (__bf16)W2[(size_t)k*ECH+j] : (__bf16)0.f;
  }
  // zero e1s k-pad
  for (int i=tid;i<1024;i+=256){
    int r=i>>4, c=48+(i&15);
    e1s[r*72+c] = (__bf16)0.f;
  }
  __syncthreads();

  // ---- layer 1: per-lane in-register A fragments, 8 k-chunks of 32 ----
  float d  = dl[w*16+lr];
  float ev = envl[w*16+lr];
  f32x4 acc[3];
  #pragma unroll
  for (int nt=0;nt<3;nt++) acc[nt] = (f32x4){0.f,0.f,0.f,0.f};
  #pragma unroll
  for (int c=0;c<8;c++){
    bf16x8 af;
    #pragma unroll
    for (int j=0;j<8;j++){
      float kk = (float)(c*32 + lg*8 + j);
      float del = (d - kk*SPACING)*INV_STD;
      af[j] = (__bf16)(exp2f(-0.72134752f*del*del)*ev);
    }
    #pragma unroll
    for (int nt=0;nt<3;nt++){
      bf16x8 bf_ = *(const bf16x8*)&W1T[(nt*16+lr)*264 + c*32 + lg*8];
      acc[nt] = __builtin_amdgcn_mfma_f32_16x16x32_bf16(af, bf_, acc[nt], 0, 0, 0);
    }
  }
  #pragma unroll
  for (int nt=0;nt<3;nt++){
    int col = nt*16+lr;
    float bb = b1[col];
    #pragma unroll
    for (int r=0;r<4;r++){
      int row = w*16 + lg*4 + r;
      e1s[row*72+col] = (__bf16)silu_f(acc[nt][r] + bb);
    }
  }
  __syncthreads();

  // ---- layer 2: e2 = silu(e1 @ W2 + b2) ----
  bf16x8 a0 = *(const bf16x8*)&e1s[(w*16+lr)*72 + lg*8];
  bf16x8 a1 = *(const bf16x8*)&e1s[(w*16+lr)*72 + 32 + lg*8];
  #pragma unroll
  for (int nt=0;nt<3;nt++){
    f32x4 o = (f32x4){0.f,0.f,0.f,0.f};
    bf16x8 b0 = *(const bf16x8*)&W2T[(nt*16+lr)*72 + lg*8];
    bf16x8 b1f= *(const bf16x8*)&W2T[(nt*16+lr)*72 + 32 + lg*8];
    o = __builtin_amdgcn_mfma_f32_16x16x32_bf16(a0, b0, o, 0, 0, 0);
    o = __builtin_amdgcn_mfma_f32_16x16x32_bf16(a1, b1f, o, 0, 0, 0);
    int col = nt*16+lr;
    float bb = b2[col];
    #pragma unroll
    for (int r=0;r<4;r++){
      int row = w*16 + lg*4 + r;
      e2g[(size_t)(eb+row)*ECH + col] = (__bf16)silu_f(o[r] + bb);
    }
  }
}

// ---------- CSR build ----------
__global__ void k_hist(const int* __restrict__ ei, int* __restrict__ deg){
  int e = blockIdx.x*256 + threadIdx.x;
  atomicAdd(&deg[ei[EE+e]], 1);
}

__global__ void __launch_bounds__(1024) k_scan(const int* __restrict__ deg, int* __restrict__ off){
  __shared__ int sums[1024];
  int t = threadIdx.x;
  int base = t*8;
  int loc[8]; int s=0;
  #pragma unroll
  for (int i=0;i<8;i++){ int idx=base+i; int v = (idx<NN)? deg[idx]:0; loc[i]=v; s+=v; }
  sums[t]=s;
  __syncthreads();
  for (int d=1; d<1024; d<<=1){
    int v = (t>=d)? sums[t-d]:0;
    __syncthreads();
    sums[t] += v;
    __syncthreads();
  }
  int run = sums[t]-s;
  #pragma unroll
  for (int i=0;i<8;i++){ int idx=base+i; if (idx<NN) off[idx]=run; run+=loc[i]; }
  if (t==1023) off[NN]=sums[1023];
}

__global__ void k_fill(const int* __restrict__ ei, const int* __restrict__ off,
                       int* __restrict__ cursor, int* __restrict__ csr){
  int e = blockIdx.x*256 + threadIdx.x;
  int d = ei[EE+e];
  int slot = off[d] + atomicAdd(&cursor[d],1);
  csr[slot]=e;
}

// ---------- per-edge MFMA: s0 = (e2@We)*(xs0[s]+xd0[d]); logits = lrelu(s0@Wa)·va; v0 = s0@Wv
// 64 edges/block, 4 waves. grid 1500x256
__global__ void __launch_bounds__(256) k_edgeB(const __bf16* __restrict__ e2g, const int* __restrict__ ei,
                        const float* __restrict__ xs0, const float* __restrict__ xd0,
                        const float* __restrict__ W_edge, const float* __restrict__ W_alpha,
                        const float* __restrict__ v_alpha, const float* __restrict__ Wv,
                        float* __restrict__ logits_g, __bf16* __restrict__ v0g){
  __shared__ __bf16 e2s[64*72];    // edges x k (48 padded to 64), stride 72
  __shared__ __bf16 s0s[64*72];
  __shared__ __bf16 wbuf[128*72];  // reused: WeT / WaT half / WvT, rows = out-col, cols = k
  __shared__ float  va_l[256];
  __shared__ int    srcd[128];     // [0:64) src, [64:128) dst
  int tid = threadIdx.x;
  int w = tid >> 6, l = tid & 63;
  int lr = l & 15, lg = l >> 4;
  int eb = blockIdx.x * 64;

  // ---- stage e2 (zero-padded K), WeT, va, src/dst ----
  for (int i=tid;i<4096;i+=256){
    int r=i>>6, k=i&63;
    e2s[r*72+k] = (k<ECH) ? e2g[(size_t)(eb+r)*ECH+k] : (__bf16)0.f;
  }
  for (int i=tid;i<4096;i+=256){
    int k=i>>6, c=i&63;    // coalesced read of We[k][c]
    wbuf[c*72+k] = (k<ECH) ? (__bf16)W_edge[(size_t)k*64+c] : (__bf16)0.f;
  }
  va_l[tid] = v_alpha[tid];
  if (tid<64){ srcd[tid]=ei[eb+tid]; srcd[64+tid]=ei[EE+eb+tid]; }
  __syncthreads();

  // ---- s0_pre = e2 @ We ----
  bf16x8 ea0 = *(const bf16x8*)&e2s[(w*16+lr)*72 + lg*8];
  bf16x8 ea1 = *(const bf16x8*)&e2s[(w*16+lr)*72 + 32 + lg*8];
  f32x4 sacc[4];
  #pragma unroll
  for (int nt=0;nt<4;nt++){
    sacc[nt] = (f32x4){0.f,0.f,0.f,0.f};
    bf16x8 b0 = *(const bf16x8*)&wbuf[(nt*16+lr)*72 + lg*8];
    bf16x8 b1 = *(const bf16x8*)&wbuf[(nt*16+lr)*72 + 32 + lg*8];
    sacc[nt] = __builtin_amdgcn_mfma_f32_16x16x32_bf16(ea0, b0, sacc[nt], 0, 0, 0);
    sacc[nt] = __builtin_amdgcn_mfma_f32_16x16x32_bf16(ea1, b1, sacc[nt], 0, 0, 0);
  }
  // ---- gather (xs0[src]+xd0[dst]) and scale; write s0 bf16 ----
  #pragma unroll
  for (int reg=0;reg<4;reg++){
    int localrow = w*16 + lg*4 + reg;
    int sI = srcd[localrow], dI = srcd[64+localrow];
    #pragma unroll
    for (int nt=0;nt<4;nt++){
      int col = nt*16 + lr;
      float m = xs0[(size_t)sI*64+col] + xd0[(size_t)dI*64+col];
      s0s[localrow*72+col] = (__bf16)(sacc[nt][reg]*m);
    }
  }
  __syncthreads();

  bf16x8 sa0 = *(const bf16x8*)&s0s[(w*16+lr)*72 + lg*8];
  bf16x8 sa1 = *(const bf16x8*)&s0s[(w*16+lr)*72 + 32 + lg*8];

  // ---- logits: two halves of W_alpha (128 cols each) ----
  #pragma unroll
  for (int half=0;half<2;half++){
    for (int i=tid;i<8192;i+=256){
      int k=i>>7, j=i&127;   // coalesced read of Wa[k][half*128+j]
      wbuf[j*72+k] = (__bf16)W_alpha[(size_t)k*256 + half*128 + j];
    }
    __syncthreads();
    float lg0[4]={0.f,0.f,0.f,0.f}, lg1[4]={0.f,0.f,0.f,0.f};
    #pragma unroll
    for (int nt=0;nt<8;nt++){
      f32x4 tacc = (f32x4){0.f,0.f,0.f,0.f};
      bf16x8 b0 = *(const bf16x8*)&wbuf[(nt*16+lr)*72 + lg*8];
      bf16x8 b1 = *(const bf16x8*)&wbuf[(nt*16+lr)*72 + 32 + lg*8];
      tacc = __builtin_amdgcn_mfma_f32_16x16x32_bf16(sa0, b0, tacc, 0, 0, 0);
      tacc = __builtin_amdgcn_mfma_f32_16x16x32_bf16(sa1, b1, tacc, 0, 0, 0);
      int gj = half*128 + nt*16 + lr;
      float vaj = va_l[gj];
      #pragma unroll
      for (int reg=0;reg<4;reg++){
        float t = tacc[reg];
        t = (t>0.0f) ? t : 0.2f*t;
        if (nt<4) lg0[reg] += t*vaj; else lg1[reg] += t*vaj;
      }
    }
    // reduce over the 16 cols (lane&15 dimension)
    #pragma unroll
    for (int reg=0;reg<4;reg++){
      #pragma unroll
      for (int m=1;m<16;m<<=1){
        lg0[reg] += __shfl_xor(lg0[reg], m);
        lg1[reg] += __shfl_xor(lg1[reg], m);
      }
    }
    if (lr==0){
      #pragma unroll
      for (int reg=0;reg<4;reg++){
        int e = eb + w*16 + lg*4 + reg;
        logits_g[(size_t)e*4 + half*2 + 0] = lg0[reg];
        logits_g[(size_t)e*4 + half*2 + 1] = lg1[reg];
      }
    }
    __syncthreads();
  }

  // ---- v0 = s0 @ Wv (bf16 out) ----
  for (int i=tid;i<4096;i+=256){
    int k=i>>6, c=i&63;
    wbuf[c*72+k] = (__bf16)Wv[(size_t)k*64+c];
  }
  __syncthreads();
  #pragma unroll
  for (int nt=0;nt<4;nt++){
    f32x4 vacc = (f32x4){0.f,0.f,0.f,0.f};
    bf16x8 b0 = *(const bf16x8*)&wbuf[(nt*16+lr)*72 + lg*8];
    bf16x8 b1 = *(const bf16x8*)&wbuf[(nt*16+lr)*72 + 32 + lg*8];
    vacc = __builtin_amdgcn_mfma_f32_16x16x32_bf16(sa0, b0, vacc, 0, 0, 0);
    vacc = __builtin_amdgcn_mfma_f32_16x16x32_bf16(sa1, b1, vacc, 0, 0, 0);
    #pragma unroll
    for (int reg=0;reg<4;reg++){
      int e = eb + w*16 + lg*4 + reg;
      v0g[(size_t)e*64 + nt*16 + lr] = (__bf16)vacc[reg];
    }
  }
}

// ---------- per-node softmax + coalesced bf16 gather + MFMA Wo epilogue (grid NN x 256) ----------
__global__ void __launch_bounds__(256) k_agg(const int* __restrict__ off, const int* __restrict__ csr,
                       const int* __restrict__ ei,
                       const float* __restrict__ logits_g, const __bf16* __restrict__ v0g,
                       const __bf16* __restrict__ vs, const __bf16* __restrict__ vd,
                       const float* __restrict__ x, const float* __restrict__ Wo,
                       float* __restrict__ out){
  __shared__ float alph[MAXDEG*HH];
  __shared__ int   eidl[MAXDEG];
  __shared__ int   srcl[MAXDEG];
  __shared__ float salpha[HH];
  __shared__ __bf16 aggb[16*72];   // agg rows (l) x 64 c, stride 72
  __shared__ __bf16 WoT[64*72];    // Wo transposed [c_out][k]
  int tid = threadIdx.x;
  int n = blockIdx.x;
  int o0 = off[n];
  int deg = off[n+1]-o0;
  if (deg > MAXDEG) deg = MAXDEG;
  if (tid < deg){
    int e = csr[o0+tid];
    eidl[tid]=e;
    srcl[tid]=ei[e];
    #pragma unroll
    for (int h=0;h<HH;h++) alph[tid*HH+h]=logits_g[(size_t)e*HH+h];
  }
  for (int i=tid;i<4096;i+=256){
    int k=i>>6, c=i&63;
    WoT[c*72+k] = (__bf16)Wo[i];
  }
  __syncthreads();
  if (tid < HH){
    int h = tid;
    float m = -1e30f;
    for (int i=0;i<deg;i++) m = fmaxf(m, alph[i*HH+h]);
    float ds = 0.0f;
    for (int i=0;i<deg;i++){ float w = expf(alph[i*HH+h]-m); alph[i*HH+h]=w; ds += w; }
    float inv = 1.0f/(ds+1e-9f);
    for (int i=0;i<deg;i++) alph[i*HH+h] *= inv;
    salpha[h] = ds*inv;
  }
  __syncthreads();
  // gather: thread owns (l = tid>>4, quad = tid&15) -> channels quad*4..quad*4+3
  {
    int l = tid>>4, quad = tid&15;
    int h = quad>>2;
    float a0=0.f,a1=0.f,a2=0.f,a3=0.f;
    if (l==0){
      for (int i=0;i<deg;i++){
        float a = alph[i*HH+h];
        bf16x4 v = *(const bf16x4*)(v0g + (size_t)eidl[i]*64 + quad*4);
        a0 += a*(float)v[0]; a1 += a*(float)v[1]; a2 += a*(float)v[2]; a3 += a*(float)v[3];
      }
    } else {
      for (int i=0;i<deg;i++){
        float a = alph[i*HH+h];
        bf16x4 v = *(const bf16x4*)(vs + (size_t)srcl[i]*1024 + tid*4);
        a0 += a*(float)v[0]; a1 += a*(float)v[1]; a2 += a*(float)v[2]; a3 += a*(float)v[3];
      }
      float sa = salpha[h];
      bf16x4 v = *(const bf16x4*)(vd + (size_t)n*1024 + tid*4);
      a0 += sa*(float)v[0]; a1 += sa*(float)v[1]; a2 += sa*(float)v[2]; a3 += sa*(float)v[3];
    }
    bf16x4 t = {(__bf16)a0,(__bf16)a1,(__bf16)a2,(__bf16)a3};
    *(bf16x4*)(&aggb[l*72 + quad*4]) = t;
  }
  __syncthreads();
  // out[16 x 64] = agg @ Wo + x ; wave w does cols w*16..w*16+15
  {
    int w = tid>>6, lane = tid&63, lr = lane&15, lg = lane>>4;
    bf16x8 a0 = *(const bf16x8*)&aggb[lr*72 + lg*8];
    bf16x8 a1 = *(const bf16x8*)&aggb[lr*72 + 32 + lg*8];
    bf16x8 b0 = *(const bf16x8*)&WoT[(w*16+lr)*72 + lg*8];
    bf16x8 b1 = *(const bf16x8*)&WoT[(w*16+lr)*72 + 32 + lg*8];
    f32x4 o = (f32x4){0.f,0.f,0.f,0.f};
    o = __builtin_amdgcn_mfma_f32_16x16x32_bf16(a0, b0, o, 0, 0, 0);
    o = __builtin_amdgcn_mfma_f32_16x16x32_bf16(a1, b1, o, 0, 0, 0);
    const float* xr = x + (size_t)n*1024;
    float* outr = out + (size_t)n*1024;
    #pragma unroll
    for (int r=0;r<4;r++){
      int row = lg*4 + r, col = w*16 + lr;
      outr[row*64 + col] = xr[row*64 + col] + o[r];
    }
  }
}

// ---------- FFN with bf16 MFMA: 4 nodes (64 SH rows) per block, grid 2000x256 ----------
__global__ void __launch_bounds__(256) k_ffn(const float* __restrict__ x1,
                       const float* __restrict__ Wg, const float* __restrict__ Wh,
                       const float* __restrict__ Wf, float* __restrict__ out){
  __shared__ __bf16 Abuf[64*72];    // y bf16, row stride 72 (144B, bank step 4)
  __shared__ __bf16 WhT[128*72];    // Wh transposed [n][k]
  __shared__ __bf16 Hbuf[64*136];   // hidden (gated) bf16, stride 136 (272B)
  __shared__ __bf16 WfT[64*136];    // Wf transposed [n][k]
  __shared__ float  gl[512];        // gate per node (4 x 128)
  __shared__ float  scl[4];
  int tid = threadIdx.x;
  int l = tid & 63, w = tid >> 6;
  const size_t base = (size_t)blockIdx.x*4096;
  const float* xb = x1 + base;

  // --- phase 1: per-node rms (wave w handles node w) ---
  {
    const float4* xp = (const float4*)(xb + w*1024);
    float ss = 0.0f;
    #pragma unroll
    for (int i=0;i<4;i++){
      float4 v = xp[l + 64*i];
      ss += v.x*v.x + v.y*v.y + v.z*v.z + v.w*v.w;
    }
    #pragma unroll
    for (int m=32;m>=1;m>>=1) ss += __shfl_xor(ss, m);
    if (l==0) scl[w] = 1.0f/sqrtf(ss*(1.0f/1024.0f) + 1e-6f);
  }
  __syncthreads();

  // --- phase 2: fill A (y bf16), WhT, WfT, gate ---
  for (int i=tid; i<1024; i+=256){     // float4 index over 4096 y values
    int m = i>>4, k4 = (i&15)*4;
    float s = scl[m>>4];
    float4 v = ((const float4*)xb)[i];
    __bf16* ap = &Abuf[m*72 + k4];
    ap[0]=(__bf16)(v.x*s); ap[1]=(__bf16)(v.y*s); ap[2]=(__bf16)(v.z*s); ap[3]=(__bf16)(v.w*s);
  }
  for (int i=tid; i<8192; i+=256){ int k=i>>7, nn=i&127; WhT[nn*72+k]  = (__bf16)Wh[i]; }
  for (int i=tid; i<8192; i+=256){ int k=i>>6, nn=i&63;  WfT[nn*136+k] = (__bf16)Wf[i]; }
  {
    // gate: g[nd][c] = silu(scl[nd] * sum_k x1[nd][0][k] Wg[k][c]); thread does 2 nodes
    int c = tid & 127;
    int half = tid >> 7;
    const float* xr0 = xb + (half*2)*1024;
    const float* xr1 = xr0 + 1024;
    float a0=0.0f, a1=0.0f;
    #pragma unroll 8
    for (int k=0;k<64;k++){
      float wgv = Wg[k*128 + c];
      a0 += xr0[k]*wgv; a1 += xr1[k]*wgv;
    }
    gl[(half*2)*128 + c]   = silu_f(a0*scl[half*2]);
    gl[(half*2+1)*128 + c] = silu_f(a1*scl[half*2+1]);
  }
  __syncthreads();

  // --- phase 3: H[64,128] = A[64,64] @ Wh[64,128], gate, -> bf16 LDS ---
  int lr = l & 15;   // row (A) / col (B)
  int lg = l >> 4;   // k-chunk
  {
    bf16x8 a0 = *(const bf16x8*)&Abuf[(w*16 + lr)*72 +      lg*8];
    bf16x8 a1 = *(const bf16x8*)&Abuf[(w*16 + lr)*72 + 32 + lg*8];
    f32x4 acc[8];
    #pragma unroll
    for (int nt=0;nt<8;nt++) acc[nt] = (f32x4){0.f,0.f,0.f,0.f};
    #pragma unroll
    for (int nt=0;nt<8;nt++){
      bf16x8 b0 = *(const bf16x8*)&WhT[(nt*16 + lr)*72 +      lg*8];
      bf16x8 b1 = *(const bf16x8*)&WhT[(nt*16 + lr)*72 + 32 + lg*8];
      acc[nt] = __builtin_amdgcn_mfma_f32_16x16x32_bf16(a0, b0, acc[nt], 0, 0, 0);
      acc[nt] = __builtin_amdgcn_mfma_f32_16x16x32_bf16(a1, b1, acc[nt], 0, 0, 0);
    }
    #pragma unroll
    for (int nt=0;nt<8;nt++){
      int colj = nt*16 + lr;
      float g = gl[w*128 + colj];
      #pragma unroll
      for (int r=0;r<4;r++){
        int row = lg*4 + r;
        Hbuf[(w*16+row)*136 + colj] = (__bf16)(acc[nt][r]*g);
      }
    }
  }
  __syncthreads();

  // --- phase 4: OUT[64,64] = H[64,128] @ Wf[128,64] + x1 ---
  {
    f32x4 o[4];
    #pragma unroll
    for (int nt=0;nt<4;nt++) o[nt] = (f32x4){0.f,0.f,0.f,0.f};
    #pragma unroll
    for (int kc=0;kc<4;kc++){
      bf16x8 a = *(const bf16x8*)&Hbuf[(w*16 + lr)*136 + kc*32 + lg*8];
      #pragma unroll
      for (int nt=0;nt<4;nt++){
        bf16x8 b = *(const bf16x8*)&WfT[(nt*16 + lr)*136 + kc*32 + lg*8];
        o[nt] = __builtin_amdgcn_mfma_f32_16x16x32_bf16(a, b, o[nt], 0, 0, 0);
      }
    }
    #pragma unroll
    for (int nt=0;nt<4;nt++){
      int col = nt*16 + lr;
      #pragma unroll
      for (int r=0;r<4;r++){
        int row = w*16 + lg*4 + r;
        out[base + row*64 + col] = xb[row*64 + col] + o[nt][r];
      }
    }
  }
}

extern "C" void kernel_launch(void* const* d_in, const int* in_sizes, int n_in,
                              void* d_out, int out_size, void* d_ws, size_t ws_size,
                              hipStream_t stream) {
  (void)in_sizes; (void)n_in; (void)out_size; (void)ws_size;
  const float* pos = (const float*)d_in[0];
  const float* x   = (const float*)d_in[1];
  const float* Wsrc= (const float*)d_in[2];
  const float* Wdst= (const float*)d_in[3];
  const float* W1  = (const float*)d_in[4];
  const float* b1  = (const float*)d_in[5];
  const float* W2  = (const float*)d_in[6];
  const float* b2  = (const float*)d_in[7];
  const float* We  = (const float*)d_in[8];
  const float* Wa  = (const float*)d_in[9];
  const float* va  = (const float*)d_in[10];
  const float* Wv  = (const float*)d_in[11];
  const float* Wo  = (const float*)d_in[12];
  const float* Wg  = (const float*)d_in[13];
  const float* Wh  = (const float*)d_in[14];
  const float* Wf  = (const float*)d_in[15];
  const int*   ei  = (const int*)d_in[16];
  float* out = (float*)d_out;

  char* wp = (char*)d_ws;
  auto alloc = [&](size_t bytes)->char*{
    char* p = wp;
    wp += ((bytes + 255)/256)*256;
    return p;
  };
  float* rms1 = (float*)alloc((size_t)NN*4);
  float* wsv  = (float*)alloc(4096*4);
  float* wdv  = (float*)alloc(4096*4);
  float* xs0  = (float*)alloc((size_t)NN*64*4);
  float* xd0  = (float*)alloc((size_t)NN*64*4);
  __bf16* vs  = (__bf16*)alloc((size_t)NN*1024*2);
  __bf16* vd  = (__bf16*)alloc((size_t)NN*1024*2);
  __bf16* e2g = (__bf16*)alloc((size_t)EE*ECH*2);
  __bf16* v0g = (__bf16*)alloc((size_t)EE*64*2);
  float* lgts = (float*)alloc((size_t)EE*HH*4);
  int* deg    = (int*)alloc((size_t)NN*4);
  int* cursor = (int*)alloc((size_t)NN*4);
  int* off    = (int*)alloc((size_t)(NN+1)*4);
  int* csr    = (int*)alloc((size_t)EE*4);

  hipMemsetAsync(deg, 0, NN*sizeof(int), stream);
  hipMemsetAsync(cursor, 0, NN*sizeof(int), stream);

  k_fusew<<<32,256,0,stream>>>(Wsrc,Wdst,Wv,wsv,wdv);
  k_rms<<<NN,256,0,stream>>>(x,rms1);
  k_node0<<<NN*64/256,256,0,stream>>>(x,rms1,Wsrc,Wdst,xs0,xd0);
  k_node1<<<NN*16/64,256,0,stream>>>(x,rms1,wsv,wdv,vs,vd);
  k_edgeA<<<EE/64,256,0,stream>>>(pos,ei,W1,b1,W2,b2,e2g);
  k_hist<<<EE/256,256,0,stream>>>(ei,deg);
  k_scan<<<1,1024,0,stream>>>(deg,off);
  k_fill<<<EE/256,256,0,stream>>>(ei,off,cursor,csr);
  k_edgeB<<<EE/64,256,0,stream>>>(e2g,ei,xs0,xd0,We,Wa,va,Wv,lgts,v0g);
  k_agg<<<NN,256,0,stream>>>(off,csr,ei,lgts,v0g,vs,vd,x,Wo,out);
  k_ffn<<<NN/4,256,0,stream>>>(out,Wg,Wh,Wf,out);
}

// Round 9
// 226.001 us; speedup vs baseline: 5.1344x; 1.1331x over previous
//
#include <hip/hip_runtime.h>
#include <math.h>

// Problem constants (match reference file)
#define NN 8000
#define EE 96000
#define HH 4
#define NBASIS 256
#define ECH 48
#define FFNH 128
#define CUTOFF_R 0.0792f
#define PI_F 3.14159265358979323846f
#define SPACING (CUTOFF_R/255.0f)
#define INV_STD (256.0f/CUTOFF_R)
#define MAXDEG 64

typedef __bf16 bf16x8 __attribute__((ext_vector_type(8)));
typedef __bf16 bf16x4 __attribute__((ext_vector_type(4)));
typedef __bf16 bf16x2 __attribute__((ext_vector_type(2)));
typedef float  f32x4  __attribute__((ext_vector_type(4)));

__device__ __forceinline__ float silu_f(float x){ return x/(1.0f+expf(-x)); }

// ---------- fused weights: wsv = W_src@W_v, wdv = W_dst@W_v, bf16 out (grid 32x256) ----------
__global__ void k_fusew(const float* __restrict__ Wsrc, const float* __restrict__ Wdst,
                        const float* __restrict__ Wv,
                        __bf16* __restrict__ wsv, __bf16* __restrict__ wdv){
  int gid = blockIdx.x*256 + threadIdx.x;
  int which = gid >> 12;
  int idx = gid & 4095;
  int r = idx >> 6, c = idx & 63;
  const float* A = which ? Wdst : Wsrc;
  float acc = 0.0f;
  #pragma unroll
  for (int k=0;k<64;k++) acc += A[r*64+k]*Wv[k*64+c];
  (which ? wdv : wsv)[idx] = (__bf16)acc;
}

// ---------- fused pre: rms + xs0/xd0 + vs/vd MFMA. 4 nodes/block, grid 2000x256 ----------
__global__ void __launch_bounds__(256) k_pre(const float* __restrict__ x,
                        const float* __restrict__ Wsrc, const float* __restrict__ Wdst,
                        const __bf16* __restrict__ wsv, const __bf16* __restrict__ wdv,
                        float* __restrict__ xs0, float* __restrict__ xd0,
                        __bf16* __restrict__ vs, __bf16* __restrict__ vd){
  __shared__ __bf16 xbuf[64*72];   // 4 nodes x 16 l rows, rms-scaled bf16
  __shared__ float  xl0[4][64];    // fp32 l=0 rows (unscaled)
  __shared__ __bf16 wsb[64*72];    // wsvT [c][k]
  __shared__ __bf16 wdb[64*72];
  __shared__ float  red[16];       // [wave][q]
  int tid = threadIdx.x;
  int w = tid>>6, l = tid&63, lr = l&15, lg = l>>4;
  int n0 = blockIdx.x*4;
  const float4* xp = (const float4*)(x + (size_t)n0*1024);

  // load 4 float4 (one per node), partial ss
  float4 v[4]; float ssq[4];
  #pragma unroll
  for (int q=0;q<4;q++){
    v[q] = xp[tid + q*256];
    ssq[q] = v[q].x*v[q].x + v[q].y*v[q].y + v[q].z*v[q].z + v[q].w*v[q].w;
  }
  #pragma unroll
  for (int q=0;q<4;q++){
    #pragma unroll
    for (int m=32;m>=1;m>>=1) ssq[q] += __shfl_xor(ssq[q], m);
  }
  if (l==0){
    #pragma unroll
    for (int q=0;q<4;q++) red[w*4+q] = ssq[q];
  }
  // stage weights meanwhile
  for (int i=tid;i<4096;i+=256){
    int k=i>>6, c=i&63;
    wsb[c*72+k] = wsv[i];
    wdb[c*72+k] = wdv[i];
  }
  // xl0 (fp32, unscaled)
  if (tid < 16){
    #pragma unroll
    for (int q=0;q<4;q++){
      float4 t = v[q];
      float* p = &xl0[q][(tid&15)*4];
      p[0]=t.x; p[1]=t.y; p[2]=t.z; p[3]=t.w;
    }
  }
  __syncthreads();
  float scl[4];
  #pragma unroll
  for (int q=0;q<4;q++)
    scl[q] = 1.0f/sqrtf((red[q]+red[4+q]+red[8+q]+red[12+q])*(1.0f/1024.0f)+1e-6f);
  // write xbuf (bf16, scaled)
  {
    int r = tid>>4, k4 = (tid&15)*4;
    #pragma unroll
    for (int q=0;q<4;q++){
      float s = scl[q];
      bf16x4 t = {(__bf16)(v[q].x*s),(__bf16)(v[q].y*s),(__bf16)(v[q].z*s),(__bf16)(v[q].w*s)};
      *(bf16x4*)&xbuf[(q*16+r)*72 + k4] = t;
    }
  }
  __syncthreads();

  // xs0/xd0: thread (nd=tid>>6, c=tid&63)
  {
    int nd = w, c = l;
    float s = scl[nd];
    float as=0.f, ad=0.f;
    #pragma unroll 8
    for (int k=0;k<64;k++){
      float xv = xl0[nd][k]*s;
      as += xv*Wsrc[k*64+c];
      ad += xv*Wdst[k*64+c];
    }
    xs0[(size_t)(n0+nd)*64 + c] = as;
    xd0[(size_t)(n0+nd)*64 + c] = ad;
  }

  // vs/vd MFMA: wave w = node w (rows w*16..w*16+15)
  {
    bf16x8 a0 = *(const bf16x8*)&xbuf[(w*16+lr)*72 + lg*8];
    bf16x8 a1 = *(const bf16x8*)&xbuf[(w*16+lr)*72 + 32 + lg*8];
    #pragma unroll
    for (int nt=0;nt<4;nt++){
      f32x4 os = (f32x4){0.f,0.f,0.f,0.f};
      f32x4 od = (f32x4){0.f,0.f,0.f,0.f};
      bf16x8 bs0 = *(const bf16x8*)&wsb[(nt*16+lr)*72 + lg*8];
      bf16x8 bs1 = *(const bf16x8*)&wsb[(nt*16+lr)*72 + 32 + lg*8];
      bf16x8 bd0 = *(const bf16x8*)&wdb[(nt*16+lr)*72 + lg*8];
      bf16x8 bd1 = *(const bf16x8*)&wdb[(nt*16+lr)*72 + 32 + lg*8];
      os = __builtin_amdgcn_mfma_f32_16x16x32_bf16(a0, bs0, os, 0, 0, 0);
      os = __builtin_amdgcn_mfma_f32_16x16x32_bf16(a1, bs1, os, 0, 0, 0);
      od = __builtin_amdgcn_mfma_f32_16x16x32_bf16(a0, bd0, od, 0, 0, 0);
      od = __builtin_amdgcn_mfma_f32_16x16x32_bf16(a1, bd1, od, 0, 0, 0);
      #pragma unroll
      for (int r=0;r<4;r++){
        size_t row = (size_t)(n0+w)*16 + lg*4 + r;
        vs[row*64 + nt*16 + lr] = (__bf16)os[r];
        vd[row*64 + nt*16 + lr] = (__bf16)od[r];
      }
    }
  }
}

// ---------- edge RBF + 2-layer MLP via MFMA: 64 edges/block, grid 1500x256 ----------
__global__ void __launch_bounds__(256) k_edgeA(const float* __restrict__ pos, const int* __restrict__ ei,
                        const float* __restrict__ W1, const float* __restrict__ b1,
                        const float* __restrict__ W2, const float* __restrict__ b2,
                        __bf16* __restrict__ e2g){
  __shared__ __bf16 W1T[48*264];   // [j][k] stride 264
  __shared__ __bf16 W2T[64*72];    // [j][k] stride 72 (k>=48 zero)
  __shared__ __bf16 e1s[64*72];    // [edge][k] stride 72 (k>=48 zeroed)
  __shared__ float dl[64], envl[64];
  int tid = threadIdx.x;
  int w = tid>>6, l = tid&63, lr = l&15, lg = l>>4;
  int eb = blockIdx.x*64;

  if (tid < 64){
    int s = ei[eb+tid], t = ei[EE+eb+tid];
    float dx = pos[3*s]-pos[3*t], dy = pos[3*s+1]-pos[3*t+1], dz = pos[3*s+2]-pos[3*t+2];
    float d = sqrtf(dx*dx+dy*dy+dz*dz+1e-12f);
    dl[tid] = d;
    envl[tid] = 0.5f*(cosf(PI_F*fminf(d*(1.0f/CUTOFF_R),1.0f))+1.0f);
  }
  for (int i=tid;i<48*128;i+=256){
    int kp = i/48, j = i - kp*48;
    bf16x2 p = {(__bf16)W1[(size_t)(2*kp)*48 + j], (__bf16)W1[(size_t)(2*kp+1)*48 + j]};
    *(bf16x2*)&W1T[j*264 + 2*kp] = p;
  }
  for (int i=tid;i<4096;i+=256){
    int k=i>>6, j=i&63;
    W2T[j*72+k] = (j<ECH && k<ECH) ? (__bf16)W2[(size_t)k*ECH+j] : (__bf16)0.f;
  }
  for (int i=tid;i<1024;i+=256){
    int r=i>>4, c=48+(i&15);
    e1s[r*72+c] = (__bf16)0.f;
  }
  __syncthreads();

  float d  = dl[w*16+lr];
  float ev = envl[w*16+lr];
  f32x4 acc[3];
  #pragma unroll
  for (int nt=0;nt<3;nt++) acc[nt] = (f32x4){0.f,0.f,0.f,0.f};
  #pragma unroll
  for (int c=0;c<8;c++){
    bf16x8 af;
    #pragma unroll
    for (int j=0;j<8;j++){
      float kk = (float)(c*32 + lg*8 + j);
      float del = (d - kk*SPACING)*INV_STD;
      af[j] = (__bf16)(exp2f(-0.72134752f*del*del)*ev);
    }
    #pragma unroll
    for (int nt=0;nt<3;nt++){
      bf16x8 bf_ = *(const bf16x8*)&W1T[(nt*16+lr)*264 + c*32 + lg*8];
      acc[nt] = __builtin_amdgcn_mfma_f32_16x16x32_bf16(af, bf_, acc[nt], 0, 0, 0);
    }
  }
  #pragma unroll
  for (int nt=0;nt<3;nt++){
    int col = nt*16+lr;
    float bb = b1[col];
    #pragma unroll
    for (int r=0;r<4;r++){
      int row = w*16 + lg*4 + r;
      e1s[row*72+col] = (__bf16)silu_f(acc[nt][r] + bb);
    }
  }
  __syncthreads();

  bf16x8 a0 = *(const bf16x8*)&e1s[(w*16+lr)*72 + lg*8];
  bf16x8 a1 = *(const bf16x8*)&e1s[(w*16+lr)*72 + 32 + lg*8];
  #pragma unroll
  for (int nt=0;nt<3;nt++){
    f32x4 o = (f32x4){0.f,0.f,0.f,0.f};
    bf16x8 b0 = *(const bf16x8*)&W2T[(nt*16+lr)*72 + lg*8];
    bf16x8 b1f= *(const bf16x8*)&W2T[(nt*16+lr)*72 + 32 + lg*8];
    o = __builtin_amdgcn_mfma_f32_16x16x32_bf16(a0, b0, o, 0, 0, 0);
    o = __builtin_amdgcn_mfma_f32_16x16x32_bf16(a1, b1f, o, 0, 0, 0);
    int col = nt*16+lr;
    float bb = b2[col];
    #pragma unroll
    for (int r=0;r<4;r++){
      int row = w*16 + lg*4 + r;
      e2g[(size_t)(eb+row)*ECH + col] = (__bf16)silu_f(o[r] + bb);
    }
  }
}

// ---------- CSR build ----------
__global__ void k_hist(const int* __restrict__ ei, int* __restrict__ deg){
  int e = blockIdx.x*256 + threadIdx.x;
  atomicAdd(&deg[ei[EE+e]], 1);
}

__global__ void __launch_bounds__(1024) k_scan(const int* __restrict__ deg, int* __restrict__ off){
  __shared__ int sums[1024];
  int t = threadIdx.x;
  int base = t*8;
  int loc[8]; int s=0;
  #pragma unroll
  for (int i=0;i<8;i++){ int idx=base+i; int v = (idx<NN)? deg[idx]:0; loc[i]=v; s+=v; }
  sums[t]=s;
  __syncthreads();
  for (int d=1; d<1024; d<<=1){
    int v = (t>=d)? sums[t-d]:0;
    __syncthreads();
    sums[t] += v;
    __syncthreads();
  }
  int run = sums[t]-s;
  #pragma unroll
  for (int i=0;i<8;i++){ int idx=base+i; if (idx<NN) off[idx]=run; run+=loc[i]; }
  if (t==1023) off[NN]=sums[1023];
}

__global__ void k_fill(const int* __restrict__ ei, const int* __restrict__ off,
                       int* __restrict__ cursor, int* __restrict__ csr){
  int e = blockIdx.x*256 + threadIdx.x;
  int d = ei[EE+e];
  int slot = off[d] + atomicAdd(&cursor[d],1);
  csr[slot]=e;
}

// ---------- per-edge MFMA: s0 = (e2@We)*(xs0[s]+xd0[d]); logits = lrelu(s0@Wa)·va; v0 = s0@Wv
// 64 edges/block, 4 waves. grid 1500x256
__global__ void __launch_bounds__(256) k_edgeB(const __bf16* __restrict__ e2g, const int* __restrict__ ei,
                        const float* __restrict__ xs0, const float* __restrict__ xd0,
                        const float* __restrict__ W_edge, const float* __restrict__ W_alpha,
                        const float* __restrict__ v_alpha, const float* __restrict__ Wv,
                        float* __restrict__ logits_g, __bf16* __restrict__ v0g){
  __shared__ __bf16 e2s[64*72];
  __shared__ __bf16 s0s[64*72];
  __shared__ __bf16 wbuf[128*72];
  __shared__ float  va_l[256];
  __shared__ int    srcd[128];
  int tid = threadIdx.x;
  int w = tid >> 6, l = tid & 63;
  int lr = l & 15, lg = l >> 4;
  int eb = blockIdx.x * 64;

  for (int i=tid;i<4096;i+=256){
    int r=i>>6, k=i&63;
    e2s[r*72+k] = (k<ECH) ? e2g[(size_t)(eb+r)*ECH+k] : (__bf16)0.f;
  }
  for (int i=tid;i<4096;i+=256){
    int k=i>>6, c=i&63;
    wbuf[c*72+k] = (k<ECH) ? (__bf16)W_edge[(size_t)k*64+c] : (__bf16)0.f;
  }
  va_l[tid] = v_alpha[tid];
  if (tid<64){ srcd[tid]=ei[eb+tid]; srcd[64+tid]=ei[EE+eb+tid]; }
  __syncthreads();

  bf16x8 ea0 = *(const bf16x8*)&e2s[(w*16+lr)*72 + lg*8];
  bf16x8 ea1 = *(const bf16x8*)&e2s[(w*16+lr)*72 + 32 + lg*8];
  f32x4 sacc[4];
  #pragma unroll
  for (int nt=0;nt<4;nt++){
    sacc[nt] = (f32x4){0.f,0.f,0.f,0.f};
    bf16x8 b0 = *(const bf16x8*)&wbuf[(nt*16+lr)*72 + lg*8];
    bf16x8 b1 = *(const bf16x8*)&wbuf[(nt*16+lr)*72 + 32 + lg*8];
    sacc[nt] = __builtin_amdgcn_mfma_f32_16x16x32_bf16(ea0, b0, sacc[nt], 0, 0, 0);
    sacc[nt] = __builtin_amdgcn_mfma_f32_16x16x32_bf16(ea1, b1, sacc[nt], 0, 0, 0);
  }
  #pragma unroll
  for (int reg=0;reg<4;reg++){
    int localrow = w*16 + lg*4 + reg;
    int sI = srcd[localrow], dI = srcd[64+localrow];
    #pragma unroll
    for (int nt=0;nt<4;nt++){
      int col = nt*16 + lr;
      float m = xs0[(size_t)sI*64+col] + xd0[(size_t)dI*64+col];
      s0s[localrow*72+col] = (__bf16)(sacc[nt][reg]*m);
    }
  }
  __syncthreads();

  bf16x8 sa0 = *(const bf16x8*)&s0s[(w*16+lr)*72 + lg*8];
  bf16x8 sa1 = *(const bf16x8*)&s0s[(w*16+lr)*72 + 32 + lg*8];

  #pragma unroll
  for (int half=0;half<2;half++){
    for (int i=tid;i<8192;i+=256){
      int k=i>>7, j=i&127;
      wbuf[j*72+k] = (__bf16)W_alpha[(size_t)k*256 + half*128 + j];
    }
    __syncthreads();
    float lg0[4]={0.f,0.f,0.f,0.f}, lg1[4]={0.f,0.f,0.f,0.f};
    #pragma unroll
    for (int nt=0;nt<8;nt++){
      f32x4 tacc = (f32x4){0.f,0.f,0.f,0.f};
      bf16x8 b0 = *(const bf16x8*)&wbuf[(nt*16+lr)*72 + lg*8];
      bf16x8 b1 = *(const bf16x8*)&wbuf[(nt*16+lr)*72 + 32 + lg*8];
      tacc = __builtin_amdgcn_mfma_f32_16x16x32_bf16(sa0, b0, tacc, 0, 0, 0);
      tacc = __builtin_amdgcn_mfma_f32_16x16x32_bf16(sa1, b1, tacc, 0, 0, 0);
      int gj = half*128 + nt*16 + lr;
      float vaj = va_l[gj];
      #pragma unroll
      for (int reg=0;reg<4;reg++){
        float t = tacc[reg];
        t = (t>0.0f) ? t : 0.2f*t;
        if (nt<4) lg0[reg] += t*vaj; else lg1[reg] += t*vaj;
      }
    }
    #pragma unroll
    for (int reg=0;reg<4;reg++){
      #pragma unroll
      for (int m=1;m<16;m<<=1){
        lg0[reg] += __shfl_xor(lg0[reg], m);
        lg1[reg] += __shfl_xor(lg1[reg], m);
      }
    }
    if (lr==0){
      #pragma unroll
      for (int reg=0;reg<4;reg++){
        int e = eb + w*16 + lg*4 + reg;
        logits_g[(size_t)e*4 + half*2 + 0] = lg0[reg];
        logits_g[(size_t)e*4 + half*2 + 1] = lg1[reg];
      }
    }
    __syncthreads();
  }

  for (int i=tid;i<4096;i+=256){
    int k=i>>6, c=i&63;
    wbuf[c*72+k] = (__bf16)Wv[(size_t)k*64+c];
  }
  __syncthreads();
  #pragma unroll
  for (int nt=0;nt<4;nt++){
    f32x4 vacc = (f32x4){0.f,0.f,0.f,0.f};
    bf16x8 b0 = *(const bf16x8*)&wbuf[(nt*16+lr)*72 + lg*8];
    bf16x8 b1 = *(const bf16x8*)&wbuf[(nt*16+lr)*72 + 32 + lg*8];
    vacc = __builtin_amdgcn_mfma_f32_16x16x32_bf16(sa0, b0, vacc, 0, 0, 0);
    vacc = __builtin_amdgcn_mfma_f32_16x16x32_bf16(sa1, b1, vacc, 0, 0, 0);
    #pragma unroll
    for (int reg=0;reg<4;reg++){
      int e = eb + w*16 + lg*4 + reg;
      v0g[(size_t)e*64 + nt*16 + lr] = (__bf16)vacc[reg];
    }
  }
}

// ---------- fused post: softmax + gather + Wo + residual + rms + gated FFN + out
// 4 nodes/block, grid 2000x256
__global__ void __launch_bounds__(256) k_post(const int* __restrict__ off, const int* __restrict__ csr,
                       const int* __restrict__ ei,
                       const float* __restrict__ logits_g, const __bf16* __restrict__ v0g,
                       const __bf16* __restrict__ vs, const __bf16* __restrict__ vd,
                       const float* __restrict__ x, const float* __restrict__ Wo,
                       const float* __restrict__ Wg, const float* __restrict__ Wh,
                       const float* __restrict__ Wf, float* __restrict__ out){
  __shared__ float  alph[4*MAXDEG*HH];   // 4KB
  __shared__ int    eidl[4*MAXDEG];      // 1KB
  __shared__ int    srcl[4*MAXDEG];      // 1KB
  __shared__ float  salpha[4][HH];
  __shared__ int    degl[4];
  __shared__ __bf16 wbuf[128*72];        // WoT -> WhT -> WfT (18.4KB)
  __shared__ __bf16 aggyb[64*72];        // aggb -> ybuf (9.2KB)
  __shared__ __bf16 Hbuf[64*136];        // 17.4KB
  __shared__ float  gl[512];             // 2KB
  int tid = threadIdx.x;
  int w = tid>>6, lane = tid&63, lr = lane&15, lg = lane>>4;
  int n0 = blockIdx.x*4;

  // ---- phase 1: stage WoT, CSR lists, logits ----
  for (int i=tid;i<4096;i+=256){
    int k=i>>6, c=i&63;
    wbuf[c*72+k] = (__bf16)Wo[i];
  }
  if (tid<4){
    int o0 = off[n0+tid];
    int dg = off[n0+tid+1]-o0;
    degl[tid] = dg>MAXDEG ? MAXDEG : dg;
  }
  __syncthreads();
  #pragma unroll
  for (int nd=0;nd<4;nd++){
    int dg = degl[nd];
    if (tid < dg){
      int e = csr[off[n0+nd]+tid];
      eidl[nd*MAXDEG+tid]=e;
      srcl[nd*MAXDEG+tid]=ei[e];
      float4 lgv = *(const float4*)(logits_g + (size_t)e*4);
      float* ap = &alph[(nd*MAXDEG+tid)*4];
      ap[0]=lgv.x; ap[1]=lgv.y; ap[2]=lgv.z; ap[3]=lgv.w;
    }
  }
  __syncthreads();

  // ---- phase 2: softmax, 16-lane group per (nd=w, h) ----
  {
    int nd = w, h = (tid>>4)&3, i0 = tid&15;
    int dg = degl[nd];
    float m = -1e30f;
    for (int i=i0;i<dg;i+=16) m = fmaxf(m, alph[(nd*MAXDEG+i)*4+h]);
    #pragma unroll
    for (int s=1;s<16;s<<=1) m = fmaxf(m, __shfl_xor(m, s));
    float ds = 0.0f;
    for (int i=i0;i<dg;i+=16){
      float wv = expf(alph[(nd*MAXDEG+i)*4+h]-m);
      alph[(nd*MAXDEG+i)*4+h]=wv; ds += wv;
    }
    #pragma unroll
    for (int s=1;s<16;s<<=1) ds += __shfl_xor(ds, s);
    float inv = 1.0f/(ds+1e-9f);
    for (int i=i0;i<dg;i+=16) alph[(nd*MAXDEG+i)*4+h] *= inv;
    if (i0==0) salpha[nd][h] = ds*inv;
  }
  __syncthreads();

  // ---- phase 3: gather -> aggyb (aggb), 4 nodes ----
  {
    int l = tid>>4, quad = tid&15;
    int h = quad>>2;
    #pragma unroll
    for (int nd=0;nd<4;nd++){
      int dg = degl[nd];
      float a0=0.f,a1=0.f,a2=0.f,a3=0.f;
      if (l==0){
        for (int i=0;i<dg;i++){
          float a = alph[(nd*MAXDEG+i)*4+h];
          bf16x4 vv = *(const bf16x4*)(v0g + (size_t)eidl[nd*MAXDEG+i]*64 + quad*4);
          a0 += a*(float)vv[0]; a1 += a*(float)vv[1]; a2 += a*(float)vv[2]; a3 += a*(float)vv[3];
        }
      } else {
        for (int i=0;i<dg;i++){
          float a = alph[(nd*MAXDEG+i)*4+h];
          bf16x4 vv = *(const bf16x4*)(vs + (size_t)srcl[nd*MAXDEG+i]*1024 + l*64 + quad*4);
          a0 += a*(float)vv[0]; a1 += a*(float)vv[1]; a2 += a*(float)vv[2]; a3 += a*(float)vv[3];
        }
        float sa = salpha[nd][h];
        bf16x4 vv = *(const bf16x4*)(vd + (size_t)(n0+nd)*1024 + l*64 + quad*4);
        a0 += sa*(float)vv[0]; a1 += sa*(float)vv[1]; a2 += sa*(float)vv[2]; a3 += sa*(float)vv[3];
      }
      bf16x4 t = {(__bf16)a0,(__bf16)a1,(__bf16)a2,(__bf16)a3};
      *(bf16x4*)(&aggyb[(nd*16+l)*72 + quad*4]) = t;
    }
  }
  __syncthreads();

  // ---- phase 4: x1 = x + agg@Wo (regs), wave w = node w; rms (wave-local) ----
  f32x4 x1r[4];
  float scl_w;
  {
    bf16x8 a0 = *(const bf16x8*)&aggyb[(w*16+lr)*72 + lg*8];
    bf16x8 a1 = *(const bf16x8*)&aggyb[(w*16+lr)*72 + 32 + lg*8];
    const float* xr = x + (size_t)(n0+w)*1024;
    float ss = 0.0f;
    #pragma unroll
    for (int nt=0;nt<4;nt++){
      f32x4 o = (f32x4){0.f,0.f,0.f,0.f};
      bf16x8 b0 = *(const bf16x8*)&wbuf[(nt*16+lr)*72 + lg*8];
      bf16x8 b1 = *(const bf16x8*)&wbuf[(nt*16+lr)*72 + 32 + lg*8];
      o = __builtin_amdgcn_mfma_f32_16x16x32_bf16(a0, b0, o, 0, 0, 0);
      o = __builtin_amdgcn_mfma_f32_16x16x32_bf16(a1, b1, o, 0, 0, 0);
      #pragma unroll
      for (int r=0;r<4;r++){
        float xv = xr[(lg*4+r)*64 + nt*16 + lr] + o[r];
        o[r] = xv;
        ss += xv*xv;
      }
      x1r[nt] = o;
    }
    #pragma unroll
    for (int m=32;m>=1;m>>=1) ss += __shfl_xor(ss, m);
    scl_w = 1.0f/sqrtf(ss*(1.0f/1024.0f)+1e-6f);
  }
  __syncthreads();   // aggyb fully consumed; wbuf consumed

  // ---- phase 5: ybuf = bf16(x1*scl) into aggyb; stage WhT ----
  #pragma unroll
  for (int nt=0;nt<4;nt++){
    #pragma unroll
    for (int r=0;r<4;r++){
      aggyb[(w*16+lg*4+r)*72 + nt*16+lr] = (__bf16)(x1r[nt][r]*scl_w);
    }
  }
  for (int i=tid;i<8192;i+=256){
    int k=i>>7, j=i&127;
    wbuf[j*72+k] = (__bf16)Wh[i];
  }
  __syncthreads();

  // ---- phase 5b: gate ----
  {
    int c = tid&127, half = tid>>7;
    #pragma unroll
    for (int q=0;q<2;q++){
      int nd = half*2+q;
      float acc = 0.0f;
      #pragma unroll 8
      for (int k=0;k<64;k++) acc += (float)aggyb[(nd*16)*72 + k] * Wg[k*128+c];
      gl[nd*128+c] = silu_f(acc);
    }
  }
  __syncthreads();

  // ---- phase 6: H = y@Wh gated -> Hbuf ----
  {
    bf16x8 a0 = *(const bf16x8*)&aggyb[(w*16+lr)*72 + lg*8];
    bf16x8 a1 = *(const bf16x8*)&aggyb[(w*16+lr)*72 + 32 + lg*8];
    #pragma unroll
    for (int nt=0;nt<8;nt++){
      f32x4 o = (f32x4){0.f,0.f,0.f,0.f};
      bf16x8 b0 = *(const bf16x8*)&wbuf[(nt*16+lr)*72 + lg*8];
      bf16x8 b1 = *(const bf16x8*)&wbuf[(nt*16+lr)*72 + 32 + lg*8];
      o = __builtin_amdgcn_mfma_f32_16x16x32_bf16(a0, b0, o, 0, 0, 0);
      o = __builtin_amdgcn_mfma_f32_16x16x32_bf16(a1, b1, o, 0, 0, 0);
      int col = nt*16+lr;
      float g = gl[w*128+col];
      #pragma unroll
      for (int r=0;r<4;r++){
        Hbuf[(w*16+lg*4+r)*136 + col] = (__bf16)(o[r]*g);
      }
    }
  }
  __syncthreads();   // wbuf (WhT) consumed

  // ---- phase 7: stage WfT (Wf is [128][64] = 8192 elements!) ----
  for (int i=tid;i<8192;i+=256){
    int k=i>>6, j=i&63;
    wbuf[j*136+k] = (__bf16)Wf[i];
  }
  __syncthreads();

  // ---- phase 8: out = x1 + H@Wf ----
  {
    f32x4 o2[4];
    #pragma unroll
    for (int nt=0;nt<4;nt++) o2[nt] = (f32x4){0.f,0.f,0.f,0.f};
    #pragma unroll
    for (int kc=0;kc<4;kc++){
      bf16x8 a = *(const bf16x8*)&Hbuf[(w*16+lr)*136 + kc*32 + lg*8];
      #pragma unroll
      for (int nt=0;nt<4;nt++){
        bf16x8 b = *(const bf16x8*)&wbuf[(nt*16+lr)*136 + kc*32 + lg*8];
        o2[nt] = __builtin_amdgcn_mfma_f32_16x16x32_bf16(a, b, o2[nt], 0, 0, 0);
      }
    }
    float* outr = out + (size_t)(n0+w)*1024;
    #pragma unroll
    for (int nt=0;nt<4;nt++){
      #pragma unroll
      for (int r=0;r<4;r++){
        outr[(lg*4+r)*64 + nt*16+lr] = x1r[nt][r] + o2[nt][r];
      }
    }
  }
}

extern "C" void kernel_launch(void* const* d_in, const int* in_sizes, int n_in,
                              void* d_out, int out_size, void* d_ws, size_t ws_size,
                              hipStream_t stream) {
  (void)in_sizes; (void)n_in; (void)out_size; (void)ws_size;
  const float* pos = (const float*)d_in[0];
  const float* x   = (const float*)d_in[1];
  const float* Wsrc= (const float*)d_in[2];
  const float* Wdst= (const float*)d_in[3];
  const float* W1  = (const float*)d_in[4];
  const float* b1  = (const float*)d_in[5];
  const float* W2  = (const float*)d_in[6];
  const float* b2  = (const float*)d_in[7];
  const float* We  = (const float*)d_in[8];
  const float* Wa  = (const float*)d_in[9];
  const float* va  = (const float*)d_in[10];
  const float* Wv  = (const float*)d_in[11];
  const float* Wo  = (const float*)d_in[12];
  const float* Wg  = (const float*)d_in[13];
  const float* Wh  = (const float*)d_in[14];
  const float* Wf  = (const float*)d_in[15];
  const int*   ei  = (const int*)d_in[16];
  float* out = (float*)d_out;

  char* wp = (char*)d_ws;
  auto alloc = [&](size_t bytes)->char*{
    char* p = wp;
    wp += ((bytes + 255)/256)*256;
    return p;
  };
  __bf16* wsv = (__bf16*)alloc(4096*2);
  __bf16* wdv = (__bf16*)alloc(4096*2);
  float* xs0  = (float*)alloc((size_t)NN*64*4);
  float* xd0  = (float*)alloc((size_t)NN*64*4);
  __bf16* vs  = (__bf16*)alloc((size_t)NN*1024*2);
  __bf16* vd  = (__bf16*)alloc((size_t)NN*1024*2);
  __bf16* e2g = (__bf16*)alloc((size_t)EE*ECH*2);
  __bf16* v0g = (__bf16*)alloc((size_t)EE*64*2);
  float* lgts = (float*)alloc((size_t)EE*HH*4);
  int* deg    = (int*)alloc((size_t)NN*4);
  int* cursor = (int*)alloc((size_t)NN*4);
  int* off    = (int*)alloc((size_t)(NN+1)*4);
  int* csr    = (int*)alloc((size_t)EE*4);

  hipMemsetAsync(deg, 0, NN*sizeof(int), stream);
  hipMemsetAsync(cursor, 0, NN*sizeof(int), stream);

  k_fusew<<<32,256,0,stream>>>(Wsrc,Wdst,Wv,wsv,wdv);
  k_pre<<<NN/4,256,0,stream>>>(x,Wsrc,Wdst,wsv,wdv,xs0,xd0,vs,vd);
  k_edgeA<<<EE/64,256,0,stream>>>(pos,ei,W1,b1,W2,b2,e2g);
  k_hist<<<EE/256,256,0,stream>>>(ei,deg);
  k_scan<<<1,1024,0,stream>>>(deg,off);
  k_fill<<<EE/256,256,0,stream>>>(ei,off,cursor,csr);
  k_edgeB<<<EE/64,256,0,stream>>>(e2g,ei,xs0,xd0,We,Wa,va,Wv,lgts,v0g);
  k_post<<<NN/4,256,0,stream>>>(off,csr,ei,lgts,v0g,vs,vd,x,Wo,Wg,Wh,Wf,out);
}

// Round 10
// 216.137 us; speedup vs baseline: 5.3687x; 1.0456x over previous
//
#include <hip/hip_runtime.h>
#include <math.h>

// Problem constants (match reference file)
#define NN 8000
#define EE 96000
#define HH 4
#define NBASIS 256
#define ECH 48
#define FFNH 128
#define CUTOFF_R 0.0792f
#define PI_F 3.14159265358979323846f
#define SPACING (CUTOFF_R/255.0f)
#define INV_STD (256.0f/CUTOFF_R)
#define MAXDEG 48

typedef __bf16 bf16x8 __attribute__((ext_vector_type(8)));
typedef __bf16 bf16x4 __attribute__((ext_vector_type(4)));
typedef __bf16 bf16x2 __attribute__((ext_vector_type(2)));
typedef float  f32x4  __attribute__((ext_vector_type(4)));

__device__ __forceinline__ float silu_f(float x){ return x/(1.0f+expf(-x)); }

// ---------- fused weights: wsv = W_src@W_v, wdv = W_dst@W_v, bf16 out (grid 32x256) ----------
__global__ void k_fusew(const float* __restrict__ Wsrc, const float* __restrict__ Wdst,
                        const float* __restrict__ Wv,
                        __bf16* __restrict__ wsv, __bf16* __restrict__ wdv){
  int gid = blockIdx.x*256 + threadIdx.x;
  int which = gid >> 12;
  int idx = gid & 4095;
  int r = idx >> 6, c = idx & 63;
  const float* A = which ? Wdst : Wsrc;
  float acc = 0.0f;
  #pragma unroll
  for (int k=0;k<64;k++) acc += A[r*64+k]*Wv[k*64+c];
  (which ? wdv : wsv)[idx] = (__bf16)acc;
}

// ---------- fused pre: rms + xs0/xd0 + vs/vd MFMA. 4 nodes/block, grid 2000x256 ----------
__global__ void __launch_bounds__(256) k_pre(const float* __restrict__ x,
                        const float* __restrict__ Wsrc, const float* __restrict__ Wdst,
                        const __bf16* __restrict__ wsv, const __bf16* __restrict__ wdv,
                        float* __restrict__ xs0, float* __restrict__ xd0,
                        __bf16* __restrict__ vs, __bf16* __restrict__ vd){
  __shared__ __bf16 xbuf[64*72];   // 4 nodes x 16 l rows, rms-scaled bf16
  __shared__ float  xl0[4][64];    // fp32 l=0 rows (unscaled)
  __shared__ __bf16 wsb[64*72];    // wsvT [c][k]
  __shared__ __bf16 wdb[64*72];
  __shared__ float  red[16];       // [wave][q]
  int tid = threadIdx.x;
  int w = tid>>6, l = tid&63, lr = l&15, lg = l>>4;
  int n0 = blockIdx.x*4;
  const float4* xp = (const float4*)(x + (size_t)n0*1024);

  // load 4 float4 (one per node), partial ss
  float4 v[4]; float ssq[4];
  #pragma unroll
  for (int q=0;q<4;q++){
    v[q] = xp[tid + q*256];
    ssq[q] = v[q].x*v[q].x + v[q].y*v[q].y + v[q].z*v[q].z + v[q].w*v[q].w;
  }
  #pragma unroll
  for (int q=0;q<4;q++){
    #pragma unroll
    for (int m=32;m>=1;m>>=1) ssq[q] += __shfl_xor(ssq[q], m);
  }
  if (l==0){
    #pragma unroll
    for (int q=0;q<4;q++) red[w*4+q] = ssq[q];
  }
  // stage weights meanwhile
  for (int i=tid;i<4096;i+=256){
    int k=i>>6, c=i&63;
    wsb[c*72+k] = wsv[i];
    wdb[c*72+k] = wdv[i];
  }
  // xl0 (fp32, unscaled)
  if (tid < 16){
    #pragma unroll
    for (int q=0;q<4;q++){
      float4 t = v[q];
      float* p = &xl0[q][(tid&15)*4];
      p[0]=t.x; p[1]=t.y; p[2]=t.z; p[3]=t.w;
    }
  }
  __syncthreads();
  float scl[4];
  #pragma unroll
  for (int q=0;q<4;q++)
    scl[q] = 1.0f/sqrtf((red[q]+red[4+q]+red[8+q]+red[12+q])*(1.0f/1024.0f)+1e-6f);
  // write xbuf (bf16, scaled)
  {
    int r = tid>>4, k4 = (tid&15)*4;
    #pragma unroll
    for (int q=0;q<4;q++){
      float s = scl[q];
      bf16x4 t = {(__bf16)(v[q].x*s),(__bf16)(v[q].y*s),(__bf16)(v[q].z*s),(__bf16)(v[q].w*s)};
      *(bf16x4*)&xbuf[(q*16+r)*72 + k4] = t;
    }
  }
  __syncthreads();

  // xs0/xd0: thread (nd=tid>>6, c=tid&63)
  {
    int nd = w, c = l;
    float s = scl[nd];
    float as=0.f, ad=0.f;
    #pragma unroll 8
    for (int k=0;k<64;k++){
      float xv = xl0[nd][k]*s;
      as += xv*Wsrc[k*64+c];
      ad += xv*Wdst[k*64+c];
    }
    xs0[(size_t)(n0+nd)*64 + c] = as;
    xd0[(size_t)(n0+nd)*64 + c] = ad;
  }

  // vs/vd MFMA: wave w = node w (rows w*16..w*16+15)
  {
    bf16x8 a0 = *(const bf16x8*)&xbuf[(w*16+lr)*72 + lg*8];
    bf16x8 a1 = *(const bf16x8*)&xbuf[(w*16+lr)*72 + 32 + lg*8];
    #pragma unroll
    for (int nt=0;nt<4;nt++){
      f32x4 os = (f32x4){0.f,0.f,0.f,0.f};
      f32x4 od = (f32x4){0.f,0.f,0.f,0.f};
      bf16x8 bs0 = *(const bf16x8*)&wsb[(nt*16+lr)*72 + lg*8];
      bf16x8 bs1 = *(const bf16x8*)&wsb[(nt*16+lr)*72 + 32 + lg*8];
      bf16x8 bd0 = *(const bf16x8*)&wdb[(nt*16+lr)*72 + lg*8];
      bf16x8 bd1 = *(const bf16x8*)&wdb[(nt*16+lr)*72 + 32 + lg*8];
      os = __builtin_amdgcn_mfma_f32_16x16x32_bf16(a0, bs0, os, 0, 0, 0);
      os = __builtin_amdgcn_mfma_f32_16x16x32_bf16(a1, bs1, os, 0, 0, 0);
      od = __builtin_amdgcn_mfma_f32_16x16x32_bf16(a0, bd0, od, 0, 0, 0);
      od = __builtin_amdgcn_mfma_f32_16x16x32_bf16(a1, bd1, od, 0, 0, 0);
      #pragma unroll
      for (int r=0;r<4;r++){
        size_t row = (size_t)(n0+w)*16 + lg*4 + r;
        vs[row*64 + nt*16 + lr] = (__bf16)os[r];
        vd[row*64 + nt*16 + lr] = (__bf16)od[r];
      }
    }
  }
}

// ---------- edge RBF + 2-layer MLP via MFMA: 64 edges/block, grid 1500x256 ----------
__global__ void __launch_bounds__(256) k_edgeA(const float* __restrict__ pos, const int* __restrict__ ei,
                        const float* __restrict__ W1, const float* __restrict__ b1,
                        const float* __restrict__ W2, const float* __restrict__ b2,
                        __bf16* __restrict__ e2g){
  __shared__ __bf16 W1T[48*264];   // [j][k] stride 264
  __shared__ __bf16 W2T[64*72];    // [j][k] stride 72 (k>=48 zero)
  __shared__ __bf16 e1s[64*72];    // [edge][k] stride 72 (k>=48 zeroed)
  __shared__ float dl[64], envl[64];
  int tid = threadIdx.x;
  int w = tid>>6, l = tid&63, lr = l&15, lg = l>>4;
  int eb = blockIdx.x*64;

  if (tid < 64){
    int s = ei[eb+tid], t = ei[EE+eb+tid];
    float dx = pos[3*s]-pos[3*t], dy = pos[3*s+1]-pos[3*t+1], dz = pos[3*s+2]-pos[3*t+2];
    float d = sqrtf(dx*dx+dy*dy+dz*dz+1e-12f);
    dl[tid] = d;
    envl[tid] = 0.5f*(cosf(PI_F*fminf(d*(1.0f/CUTOFF_R),1.0f))+1.0f);
  }
  for (int i=tid;i<48*128;i+=256){
    int kp = i/48, j = i - kp*48;
    bf16x2 p = {(__bf16)W1[(size_t)(2*kp)*48 + j], (__bf16)W1[(size_t)(2*kp+1)*48 + j]};
    *(bf16x2*)&W1T[j*264 + 2*kp] = p;
  }
  for (int i=tid;i<4096;i+=256){
    int k=i>>6, j=i&63;
    W2T[j*72+k] = (j<ECH && k<ECH) ? (__bf16)W2[(size_t)k*ECH+j] : (__bf16)0.f;
  }
  for (int i=tid;i<1024;i+=256){
    int r=i>>4, c=48+(i&15);
    e1s[r*72+c] = (__bf16)0.f;
  }
  __syncthreads();

  float d  = dl[w*16+lr];
  float ev = envl[w*16+lr];
  f32x4 acc[3];
  #pragma unroll
  for (int nt=0;nt<3;nt++) acc[nt] = (f32x4){0.f,0.f,0.f,0.f};
  #pragma unroll
  for (int c=0;c<8;c++){
    bf16x8 af;
    #pragma unroll
    for (int j=0;j<8;j++){
      float kk = (float)(c*32 + lg*8 + j);
      float del = (d - kk*SPACING)*INV_STD;
      af[j] = (__bf16)(exp2f(-0.72134752f*del*del)*ev);
    }
    #pragma unroll
    for (int nt=0;nt<3;nt++){
      bf16x8 bf_ = *(const bf16x8*)&W1T[(nt*16+lr)*264 + c*32 + lg*8];
      acc[nt] = __builtin_amdgcn_mfma_f32_16x16x32_bf16(af, bf_, acc[nt], 0, 0, 0);
    }
  }
  #pragma unroll
  for (int nt=0;nt<3;nt++){
    int col = nt*16+lr;
    float bb = b1[col];
    #pragma unroll
    for (int r=0;r<4;r++){
      int row = w*16 + lg*4 + r;
      e1s[row*72+col] = (__bf16)silu_f(acc[nt][r] + bb);
    }
  }
  __syncthreads();

  bf16x8 a0 = *(const bf16x8*)&e1s[(w*16+lr)*72 + lg*8];
  bf16x8 a1 = *(const bf16x8*)&e1s[(w*16+lr)*72 + 32 + lg*8];
  #pragma unroll
  for (int nt=0;nt<3;nt++){
    f32x4 o = (f32x4){0.f,0.f,0.f,0.f};
    bf16x8 b0 = *(const bf16x8*)&W2T[(nt*16+lr)*72 + lg*8];
    bf16x8 b1f= *(const bf16x8*)&W2T[(nt*16+lr)*72 + 32 + lg*8];
    o = __builtin_amdgcn_mfma_f32_16x16x32_bf16(a0, b0, o, 0, 0, 0);
    o = __builtin_amdgcn_mfma_f32_16x16x32_bf16(a1, b1f, o, 0, 0, 0);
    int col = nt*16+lr;
    float bb = b2[col];
    #pragma unroll
    for (int r=0;r<4;r++){
      int row = w*16 + lg*4 + r;
      e2g[(size_t)(eb+row)*ECH + col] = (__bf16)silu_f(o[r] + bb);
    }
  }
}

// ---------- CSR build ----------
__global__ void k_hist(const int* __restrict__ ei, int* __restrict__ deg){
  int e = blockIdx.x*256 + threadIdx.x;
  atomicAdd(&deg[ei[EE+e]], 1);
}

__global__ void __launch_bounds__(1024) k_scan(const int* __restrict__ deg, int* __restrict__ off){
  __shared__ int sums[1024];
  int t = threadIdx.x;
  int base = t*8;
  int loc[8]; int s=0;
  #pragma unroll
  for (int i=0;i<8;i++){ int idx=base+i; int v = (idx<NN)? deg[idx]:0; loc[i]=v; s+=v; }
  sums[t]=s;
  __syncthreads();
  for (int d=1; d<1024; d<<=1){
    int v = (t>=d)? sums[t-d]:0;
    __syncthreads();
    sums[t] += v;
    __syncthreads();
  }
  int run = sums[t]-s;
  #pragma unroll
  for (int i=0;i<8;i++){ int idx=base+i; if (idx<NN) off[idx]=run; run+=loc[i]; }
  if (t==1023) off[NN]=sums[1023];
}

__global__ void k_fill(const int* __restrict__ ei, const int* __restrict__ off,
                       int* __restrict__ cursor, int* __restrict__ csr){
  int e = blockIdx.x*256 + threadIdx.x;
  int d = ei[EE+e];
  int slot = off[d] + atomicAdd(&cursor[d],1);
  csr[slot]=e;
}

// ---------- per-edge MFMA: s0 = (e2@We)*(xs0[s]+xd0[d]); logits = lrelu(s0@Wa)·va; v0 = s0@Wv
// 64 edges/block, 4 waves. grid 1500x256
__global__ void __launch_bounds__(256) k_edgeB(const __bf16* __restrict__ e2g, const int* __restrict__ ei,
                        const float* __restrict__ xs0, const float* __restrict__ xd0,
                        const float* __restrict__ W_edge, const float* __restrict__ W_alpha,
                        const float* __restrict__ v_alpha, const float* __restrict__ Wv,
                        float* __restrict__ logits_g, __bf16* __restrict__ v0g){
  __shared__ __bf16 e2s[64*72];
  __shared__ __bf16 s0s[64*72];
  __shared__ __bf16 wbuf[128*72];
  __shared__ float  va_l[256];
  __shared__ int    srcd[128];
  int tid = threadIdx.x;
  int w = tid >> 6, l = tid & 63;
  int lr = l & 15, lg = l >> 4;
  int eb = blockIdx.x * 64;

  for (int i=tid;i<4096;i+=256){
    int r=i>>6, k=i&63;
    e2s[r*72+k] = (k<ECH) ? e2g[(size_t)(eb+r)*ECH+k] : (__bf16)0.f;
  }
  for (int i=tid;i<4096;i+=256){
    int k=i>>6, c=i&63;
    wbuf[c*72+k] = (k<ECH) ? (__bf16)W_edge[(size_t)k*64+c] : (__bf16)0.f;
  }
  va_l[tid] = v_alpha[tid];
  if (tid<64){ srcd[tid]=ei[eb+tid]; srcd[64+tid]=ei[EE+eb+tid]; }
  __syncthreads();

  bf16x8 ea0 = *(const bf16x8*)&e2s[(w*16+lr)*72 + lg*8];
  bf16x8 ea1 = *(const bf16x8*)&e2s[(w*16+lr)*72 + 32 + lg*8];
  f32x4 sacc[4];
  #pragma unroll
  for (int nt=0;nt<4;nt++){
    sacc[nt] = (f32x4){0.f,0.f,0.f,0.f};
    bf16x8 b0 = *(const bf16x8*)&wbuf[(nt*16+lr)*72 + lg*8];
    bf16x8 b1 = *(const bf16x8*)&wbuf[(nt*16+lr)*72 + 32 + lg*8];
    sacc[nt] = __builtin_amdgcn_mfma_f32_16x16x32_bf16(ea0, b0, sacc[nt], 0, 0, 0);
    sacc[nt] = __builtin_amdgcn_mfma_f32_16x16x32_bf16(ea1, b1, sacc[nt], 0, 0, 0);
  }
  #pragma unroll
  for (int reg=0;reg<4;reg++){
    int localrow = w*16 + lg*4 + reg;
    int sI = srcd[localrow], dI = srcd[64+localrow];
    #pragma unroll
    for (int nt=0;nt<4;nt++){
      int col = nt*16 + lr;
      float m = xs0[(size_t)sI*64+col] + xd0[(size_t)dI*64+col];
      s0s[localrow*72+col] = (__bf16)(sacc[nt][reg]*m);
    }
  }
  __syncthreads();

  bf16x8 sa0 = *(const bf16x8*)&s0s[(w*16+lr)*72 + lg*8];
  bf16x8 sa1 = *(const bf16x8*)&s0s[(w*16+lr)*72 + 32 + lg*8];

  #pragma unroll
  for (int half=0;half<2;half++){
    for (int i=tid;i<8192;i+=256){
      int k=i>>7, j=i&127;
      wbuf[j*72+k] = (__bf16)W_alpha[(size_t)k*256 + half*128 + j];
    }
    __syncthreads();
    float lg0[4]={0.f,0.f,0.f,0.f}, lg1[4]={0.f,0.f,0.f,0.f};
    #pragma unroll
    for (int nt=0;nt<8;nt++){
      f32x4 tacc = (f32x4){0.f,0.f,0.f,0.f};
      bf16x8 b0 = *(const bf16x8*)&wbuf[(nt*16+lr)*72 + lg*8];
      bf16x8 b1 = *(const bf16x8*)&wbuf[(nt*16+lr)*72 + 32 + lg*8];
      tacc = __builtin_amdgcn_mfma_f32_16x16x32_bf16(sa0, b0, tacc, 0, 0, 0);
      tacc = __builtin_amdgcn_mfma_f32_16x16x32_bf16(sa1, b1, tacc, 0, 0, 0);
      int gj = half*128 + nt*16 + lr;
      float vaj = va_l[gj];
      #pragma unroll
      for (int reg=0;reg<4;reg++){
        float t = tacc[reg];
        t = (t>0.0f) ? t : 0.2f*t;
        if (nt<4) lg0[reg] += t*vaj; else lg1[reg] += t*vaj;
      }
    }
    #pragma unroll
    for (int reg=0;reg<4;reg++){
      #pragma unroll
      for (int m=1;m<16;m<<=1){
        lg0[reg] += __shfl_xor(lg0[reg], m);
        lg1[reg] += __shfl_xor(lg1[reg], m);
      }
    }
    if (lr==0){
      #pragma unroll
      for (int reg=0;reg<4;reg++){
        int e = eb + w*16 + lg*4 + reg;
        logits_g[(size_t)e*4 + half*2 + 0] = lg0[reg];
        logits_g[(size_t)e*4 + half*2 + 1] = lg1[reg];
      }
    }
    __syncthreads();
  }

  for (int i=tid;i<4096;i+=256){
    int k=i>>6, c=i&63;
    wbuf[c*72+k] = (__bf16)Wv[(size_t)k*64+c];
  }
  __syncthreads();
  #pragma unroll
  for (int nt=0;nt<4;nt++){
    f32x4 vacc = (f32x4){0.f,0.f,0.f,0.f};
    bf16x8 b0 = *(const bf16x8*)&wbuf[(nt*16+lr)*72 + lg*8];
    bf16x8 b1 = *(const bf16x8*)&wbuf[(nt*16+lr)*72 + 32 + lg*8];
    vacc = __builtin_amdgcn_mfma_f32_16x16x32_bf16(sa0, b0, vacc, 0, 0, 0);
    vacc = __builtin_amdgcn_mfma_f32_16x16x32_bf16(sa1, b1, vacc, 0, 0, 0);
    #pragma unroll
    for (int reg=0;reg<4;reg++){
      int e = eb + w*16 + lg*4 + reg;
      v0g[(size_t)e*64 + nt*16 + lr] = (__bf16)vacc[reg];
    }
  }
}

// ---------- fused post (slim LDS): softmax + gather + Wo + residual + rms + gated FFN + out
// 4 nodes/block, grid 2000x256. LDS ~29.7KB -> 5 blocks/CU.
__global__ void __launch_bounds__(256) k_post(const int* __restrict__ off, const int* __restrict__ csr,
                       const int* __restrict__ ei,
                       const float* __restrict__ logits_g, const __bf16* __restrict__ v0g,
                       const __bf16* __restrict__ vs, const __bf16* __restrict__ vd,
                       const float* __restrict__ x, const float* __restrict__ Wo,
                       const float* __restrict__ Wg, const float* __restrict__ Wh,
                       const float* __restrict__ Wf, float* __restrict__ out){
  __shared__ __bf16 wbuf[64*72];         // 9216B: WoT -> WhT.h -> WfT.h (rotating)
  __shared__ __bf16 aggyb[64*72];        // 9216B: agg -> ybuf
  __shared__ float  gl[512];             // 2048B
  union UShared {
    struct {
      float alph[4*MAXDEG*HH];           // 3072B
      int   eidl[4*MAXDEG];              // 768B
      int   srcl[4*MAXDEG];              // 768B
      float salpha[4][HH];               // 64B
      int   degl[4];                     // 16B
    } a;
    __bf16 hbuf[64*72];                  // 9216B (live only after a.* is dead)
  };
  __shared__ UShared u;
  int tid = threadIdx.x;
  int w = tid>>6, lane = tid&63, lr = lane&15, lg = lane>>4;
  int n0 = blockIdx.x*4;

  // ---- phase 1: stage WoT, degl ----
  for (int i=tid;i<4096;i+=256){
    int k=i>>6, c=i&63;
    wbuf[c*72+k] = (__bf16)Wo[i];
  }
  if (tid<4){
    int o0 = off[n0+tid];
    int dg = off[n0+tid+1]-o0;
    u.a.degl[tid] = dg>MAXDEG ? MAXDEG : dg;
  }
  __syncthreads();
  // ---- phase 1b: CSR lists + logits ----
  #pragma unroll
  for (int nd=0;nd<4;nd++){
    int dg = u.a.degl[nd];
    if (tid < dg){
      int e = csr[off[n0+nd]+tid];
      u.a.eidl[nd*MAXDEG+tid]=e;
      u.a.srcl[nd*MAXDEG+tid]=ei[e];
      float4 lgv = *(const float4*)(logits_g + (size_t)e*4);
      float* ap = &u.a.alph[(nd*MAXDEG+tid)*4];
      ap[0]=lgv.x; ap[1]=lgv.y; ap[2]=lgv.z; ap[3]=lgv.w;
    }
  }
  __syncthreads();

  // ---- phase 2: softmax, 16-lane group per (nd=w, h) ----
  {
    int nd = w, h = (tid>>4)&3, i0 = tid&15;
    int dg = u.a.degl[nd];
    float m = -1e30f;
    for (int i=i0;i<dg;i+=16) m = fmaxf(m, u.a.alph[(nd*MAXDEG+i)*4+h]);
    #pragma unroll
    for (int s=1;s<16;s<<=1) m = fmaxf(m, __shfl_xor(m, s));
    float ds = 0.0f;
    for (int i=i0;i<dg;i+=16){
      float wv = expf(u.a.alph[(nd*MAXDEG+i)*4+h]-m);
      u.a.alph[(nd*MAXDEG+i)*4+h]=wv; ds += wv;
    }
    #pragma unroll
    for (int s=1;s<16;s<<=1) ds += __shfl_xor(ds, s);
    float inv = 1.0f/(ds+1e-9f);
    for (int i=i0;i<dg;i+=16) u.a.alph[(nd*MAXDEG+i)*4+h] *= inv;
    if (i0==0) u.a.salpha[nd][h] = ds*inv;
  }
  __syncthreads();

  // ---- phase 3: gather -> aggyb, 4 nodes (LAST use of u.a.*) ----
  {
    int l = tid>>4, quad = tid&15;
    int h = quad>>2;
    #pragma unroll
    for (int nd=0;nd<4;nd++){
      int dg = u.a.degl[nd];
      float a0=0.f,a1=0.f,a2=0.f,a3=0.f;
      if (l==0){
        for (int i=0;i<dg;i++){
          float a = u.a.alph[(nd*MAXDEG+i)*4+h];
          bf16x4 vv = *(const bf16x4*)(v0g + (size_t)u.a.eidl[nd*MAXDEG+i]*64 + quad*4);
          a0 += a*(float)vv[0]; a1 += a*(float)vv[1]; a2 += a*(float)vv[2]; a3 += a*(float)vv[3];
        }
      } else {
        for (int i=0;i<dg;i++){
          float a = u.a.alph[(nd*MAXDEG+i)*4+h];
          bf16x4 vv = *(const bf16x4*)(vs + (size_t)u.a.srcl[nd*MAXDEG+i]*1024 + l*64 + quad*4);
          a0 += a*(float)vv[0]; a1 += a*(float)vv[1]; a2 += a*(float)vv[2]; a3 += a*(float)vv[3];
        }
        float sa = u.a.salpha[nd][h];
        bf16x4 vv = *(const bf16x4*)(vd + (size_t)(n0+nd)*1024 + l*64 + quad*4);
        a0 += sa*(float)vv[0]; a1 += sa*(float)vv[1]; a2 += sa*(float)vv[2]; a3 += sa*(float)vv[3];
      }
      bf16x4 t = {(__bf16)a0,(__bf16)a1,(__bf16)a2,(__bf16)a3};
      *(bf16x4*)(&aggyb[(nd*16+l)*72 + quad*4]) = t;
    }
  }
  __syncthreads();

  // ---- phase 4: x1 = x + agg@Wo (regs), wave w = node w; rms (wave-local) ----
  f32x4 x1r[4];
  float scl_w;
  {
    bf16x8 a0 = *(const bf16x8*)&aggyb[(w*16+lr)*72 + lg*8];
    bf16x8 a1 = *(const bf16x8*)&aggyb[(w*16+lr)*72 + 32 + lg*8];
    const float* xr = x + (size_t)(n0+w)*1024;
    float ss = 0.0f;
    #pragma unroll
    for (int nt=0;nt<4;nt++){
      f32x4 o = (f32x4){0.f,0.f,0.f,0.f};
      bf16x8 b0 = *(const bf16x8*)&wbuf[(nt*16+lr)*72 + lg*8];
      bf16x8 b1 = *(const bf16x8*)&wbuf[(nt*16+lr)*72 + 32 + lg*8];
      o = __builtin_amdgcn_mfma_f32_16x16x32_bf16(a0, b0, o, 0, 0, 0);
      o = __builtin_amdgcn_mfma_f32_16x16x32_bf16(a1, b1, o, 0, 0, 0);
      #pragma unroll
      for (int r=0;r<4;r++){
        float xv = xr[(lg*4+r)*64 + nt*16 + lr] + o[r];
        o[r] = xv;
        ss += xv*xv;
      }
      x1r[nt] = o;
    }
    #pragma unroll
    for (int m=32;m>=1;m>>=1) ss += __shfl_xor(ss, m);
    scl_w = 1.0f/sqrtf(ss*(1.0f/1024.0f)+1e-6f);
  }
  __syncthreads();   // aggyb + wbuf consumed

  // ---- phase 5: ybuf = bf16(x1*scl) into aggyb ----
  #pragma unroll
  for (int nt=0;nt<4;nt++){
    #pragma unroll
    for (int r=0;r<4;r++){
      aggyb[(w*16+lg*4+r)*72 + nt*16+lr] = (__bf16)(x1r[nt][r]*scl_w);
    }
  }
  __syncthreads();

  // ---- phase 5b: gate (reads ybuf row 0 per node) ----
  {
    int c = tid&127, half = tid>>7;
    #pragma unroll
    for (int q=0;q<2;q++){
      int nd = half*2+q;
      float acc = 0.0f;
      #pragma unroll 8
      for (int k=0;k<64;k++) acc += (float)aggyb[(nd*16)*72 + k] * Wg[k*128+c];
      gl[nd*128+c] = silu_f(acc);
    }
  }

  // ---- phases 6-8: FFN in two column-halves of Wh / row-halves of Wf ----
  f32x4 o2[4];
  #pragma unroll
  for (int nt=0;nt<4;nt++) o2[nt] = (f32x4){0.f,0.f,0.f,0.f};
  bf16x8 ya0 = *(const bf16x8*)&aggyb[(w*16+lr)*72 + lg*8];      // loaded after ph5 sync? need sync first
  // NOTE: ya0/ya1 loaded below inside loop after barrier instead.
  #pragma unroll
  for (int hf=0; hf<2; hf++){
    __syncthreads();   // gl ready (hf=0) / wbuf reads of phase 8 done (hf=1)
    // stage WhT half: cols hf*64..hf*64+63
    for (int i=tid;i<4096;i+=256){
      int k=i>>6, j=i&63;
      wbuf[j*72+k] = (__bf16)Wh[(size_t)k*128 + hf*64 + j];
    }
    __syncthreads();
    // H half = y @ WhT.h, gated -> u.hbuf [64 rows][64 cols] stride 72
    {
      bf16x8 a0 = *(const bf16x8*)&aggyb[(w*16+lr)*72 + lg*8];
      bf16x8 a1 = *(const bf16x8*)&aggyb[(w*16+lr)*72 + 32 + lg*8];
      #pragma unroll
      for (int nt=0;nt<4;nt++){
        f32x4 o = (f32x4){0.f,0.f,0.f,0.f};
        bf16x8 b0 = *(const bf16x8*)&wbuf[(nt*16+lr)*72 + lg*8];
        bf16x8 b1 = *(const bf16x8*)&wbuf[(nt*16+lr)*72 + 32 + lg*8];
        o = __builtin_amdgcn_mfma_f32_16x16x32_bf16(a0, b0, o, 0, 0, 0);
        o = __builtin_amdgcn_mfma_f32_16x16x32_bf16(a1, b1, o, 0, 0, 0);
        int col = nt*16+lr;
        float g = gl[w*128 + hf*64 + col];
        #pragma unroll
        for (int r=0;r<4;r++){
          u.hbuf[(w*16+lg*4+r)*72 + col] = (__bf16)(o[r]*g);
        }
      }
    }
    __syncthreads();
    // stage WfT half: Wf rows hf*64..hf*64+63 -> [j][k] stride 72
    for (int i=tid;i<4096;i+=256){
      int k=i>>6, j=i&63;
      wbuf[j*72+k] = (__bf16)Wf[(size_t)(hf*64+k)*64 + j];
    }
    __syncthreads();
    // o2 += H.h @ Wf.h  (K=64)
    {
      bf16x8 a0 = *(const bf16x8*)&u.hbuf[(w*16+lr)*72 + lg*8];
      bf16x8 a1 = *(const bf16x8*)&u.hbuf[(w*16+lr)*72 + 32 + lg*8];
      #pragma unroll
      for (int nt=0;nt<4;nt++){
        bf16x8 b0 = *(const bf16x8*)&wbuf[(nt*16+lr)*72 + lg*8];
        bf16x8 b1 = *(const bf16x8*)&wbuf[(nt*16+lr)*72 + 32 + lg*8];
        o2[nt] = __builtin_amdgcn_mfma_f32_16x16x32_bf16(a0, b0, o2[nt], 0, 0, 0);
        o2[nt] = __builtin_amdgcn_mfma_f32_16x16x32_bf16(a1, b1, o2[nt], 0, 0, 0);
      }
    }
  }

  // ---- final store: out = x1 + o2 ----
  {
    float* outr = out + (size_t)(n0+w)*1024;
    #pragma unroll
    for (int nt=0;nt<4;nt++){
      #pragma unroll
      for (int r=0;r<4;r++){
        outr[(lg*4+r)*64 + nt*16+lr] = x1r[nt][r] + o2[nt][r];
      }
    }
  }
}

extern "C" void kernel_launch(void* const* d_in, const int* in_sizes, int n_in,
                              void* d_out, int out_size, void* d_ws, size_t ws_size,
                              hipStream_t stream) {
  (void)in_sizes; (void)n_in; (void)out_size; (void)ws_size;
  const float* pos = (const float*)d_in[0];
  const float* x   = (const float*)d_in[1];
  const float* Wsrc= (const float*)d_in[2];
  const float* Wdst= (const float*)d_in[3];
  const float* W1  = (const float*)d_in[4];
  const float* b1  = (const float*)d_in[5];
  const float* W2  = (const float*)d_in[6];
  const float* b2  = (const float*)d_in[7];
  const float* We  = (const float*)d_in[8];
  const float* Wa  = (const float*)d_in[9];
  const float* va  = (const float*)d_in[10];
  const float* Wv  = (const float*)d_in[11];
  const float* Wo  = (const float*)d_in[12];
  const float* Wg  = (const float*)d_in[13];
  const float* Wh  = (const float*)d_in[14];
  const float* Wf  = (const float*)d_in[15];
  const int*   ei  = (const int*)d_in[16];
  float* out = (float*)d_out;

  char* wp = (char*)d_ws;
  auto alloc = [&](size_t bytes)->char*{
    char* p = wp;
    wp += ((bytes + 255)/256)*256;
    return p;
  };
  __bf16* wsv = (__bf16*)alloc(4096*2);
  __bf16* wdv = (__bf16*)alloc(4096*2);
  float* xs0  = (float*)alloc((size_t)NN*64*4);
  float* xd0  = (float*)alloc((size_t)NN*64*4);
  __bf16* vs  = (__bf16*)alloc((size_t)NN*1024*2);
  __bf16* vd  = (__bf16*)alloc((size_t)NN*1024*2);
  __bf16* e2g = (__bf16*)alloc((size_t)EE*ECH*2);
  __bf16* v0g = (__bf16*)alloc((size_t)EE*64*2);
  float* lgts = (float*)alloc((size_t)EE*HH*4);
  int* deg    = (int*)alloc((size_t)NN*4);
  int* cursor = (int*)alloc((size_t)NN*4);
  int* off    = (int*)alloc((size_t)(NN+1)*4);
  int* csr    = (int*)alloc((size_t)EE*4);

  hipMemsetAsync(deg, 0, NN*sizeof(int), stream);
  hipMemsetAsync(cursor, 0, NN*sizeof(int), stream);

  k_fusew<<<32,256,0,stream>>>(Wsrc,Wdst,Wv,wsv,wdv);
  k_pre<<<NN/4,256,0,stream>>>(x,Wsrc,Wdst,wsv,wdv,xs0,xd0,vs,vd);
  k_edgeA<<<EE/64,256,0,stream>>>(pos,ei,W1,b1,W2,b2,e2g);
  k_hist<<<EE/256,256,0,stream>>>(ei,deg);
  k_scan<<<1,1024,0,stream>>>(deg,off);
  k_fill<<<EE/256,256,0,stream>>>(ei,off,cursor,csr);
  k_edgeB<<<EE/64,256,0,stream>>>(e2g,ei,xs0,xd0,We,Wa,va,Wv,lgts,v0g);
  k_post<<<NN/4,256,0,stream>>>(off,csr,ei,lgts,v0g,vs,vd,x,Wo,Wg,Wh,Wf,out);
}

// Round 11
// 209.821 us; speedup vs baseline: 5.5303x; 1.0301x over previous
//
#include <hip/hip_runtime.h>
#include <math.h>

// Problem constants (match reference file)
#define NN 8000
#define EE 96000
#define HH 4
#define NBASIS 256
#define ECH 48
#define FFNH 128
#define CUTOFF_R 0.0792f
#define PI_F 3.14159265358979323846f
#define SPACING (CUTOFF_R/255.0f)
#define INV_STD (256.0f/CUTOFF_R)
#define MAXDEG 48

typedef __bf16 bf16x8 __attribute__((ext_vector_type(8)));
typedef __bf16 bf16x4 __attribute__((ext_vector_type(4)));
typedef __bf16 bf16x2 __attribute__((ext_vector_type(2)));
typedef float  f32x4  __attribute__((ext_vector_type(4)));

__device__ __forceinline__ float silu_f(float x){ return x/(1.0f+expf(-x)); }

// ---------- fused weights: wsv = W_src@W_v, wdv = W_dst@W_v, bf16 out (grid 32x256) ----------
__global__ void k_fusew(const float* __restrict__ Wsrc, const float* __restrict__ Wdst,
                        const float* __restrict__ Wv,
                        __bf16* __restrict__ wsv, __bf16* __restrict__ wdv){
  int gid = blockIdx.x*256 + threadIdx.x;
  int which = gid >> 12;
  int idx = gid & 4095;
  int r = idx >> 6, c = idx & 63;
  const float* A = which ? Wdst : Wsrc;
  float acc = 0.0f;
  #pragma unroll
  for (int k=0;k<64;k++) acc += A[r*64+k]*Wv[k*64+c];
  (which ? wdv : wsv)[idx] = (__bf16)acc;
}

// ---------- fused pre: rms + xs0/xd0 + vs/vd MFMA. 4 nodes/block, grid 2000x256 ----------
__global__ void __launch_bounds__(256) k_pre(const float* __restrict__ x,
                        const float* __restrict__ Wsrc, const float* __restrict__ Wdst,
                        const __bf16* __restrict__ wsv, const __bf16* __restrict__ wdv,
                        float* __restrict__ xs0, float* __restrict__ xd0,
                        __bf16* __restrict__ vs, __bf16* __restrict__ vd){
  __shared__ __bf16 xbuf[64*72];   // 4 nodes x 16 l rows, rms-scaled bf16
  __shared__ float  xl0[4][64];    // fp32 l=0 rows (unscaled)
  __shared__ __bf16 wsb[64*72];    // wsvT [c][k]
  __shared__ __bf16 wdb[64*72];
  __shared__ float  red[16];       // [wave][q]
  int tid = threadIdx.x;
  int w = tid>>6, l = tid&63, lr = l&15, lg = l>>4;
  int n0 = blockIdx.x*4;
  const float4* xp = (const float4*)(x + (size_t)n0*1024);

  float4 v[4]; float ssq[4];
  #pragma unroll
  for (int q=0;q<4;q++){
    v[q] = xp[tid + q*256];
    ssq[q] = v[q].x*v[q].x + v[q].y*v[q].y + v[q].z*v[q].z + v[q].w*v[q].w;
  }
  #pragma unroll
  for (int q=0;q<4;q++){
    #pragma unroll
    for (int m=32;m>=1;m>>=1) ssq[q] += __shfl_xor(ssq[q], m);
  }
  if (l==0){
    #pragma unroll
    for (int q=0;q<4;q++) red[w*4+q] = ssq[q];
  }
  for (int i=tid;i<4096;i+=256){
    int k=i>>6, c=i&63;
    wsb[c*72+k] = wsv[i];
    wdb[c*72+k] = wdv[i];
  }
  if (tid < 16){
    #pragma unroll
    for (int q=0;q<4;q++){
      float4 t = v[q];
      float* p = &xl0[q][(tid&15)*4];
      p[0]=t.x; p[1]=t.y; p[2]=t.z; p[3]=t.w;
    }
  }
  __syncthreads();
  float scl[4];
  #pragma unroll
  for (int q=0;q<4;q++)
    scl[q] = 1.0f/sqrtf((red[q]+red[4+q]+red[8+q]+red[12+q])*(1.0f/1024.0f)+1e-6f);
  {
    int r = tid>>4, k4 = (tid&15)*4;
    #pragma unroll
    for (int q=0;q<4;q++){
      float s = scl[q];
      bf16x4 t = {(__bf16)(v[q].x*s),(__bf16)(v[q].y*s),(__bf16)(v[q].z*s),(__bf16)(v[q].w*s)};
      *(bf16x4*)&xbuf[(q*16+r)*72 + k4] = t;
    }
  }
  __syncthreads();

  {
    int nd = w, c = l;
    float s = scl[nd];
    float as=0.f, ad=0.f;
    #pragma unroll 8
    for (int k=0;k<64;k++){
      float xv = xl0[nd][k]*s;
      as += xv*Wsrc[k*64+c];
      ad += xv*Wdst[k*64+c];
    }
    xs0[(size_t)(n0+nd)*64 + c] = as;
    xd0[(size_t)(n0+nd)*64 + c] = ad;
  }

  {
    bf16x8 a0 = *(const bf16x8*)&xbuf[(w*16+lr)*72 + lg*8];
    bf16x8 a1 = *(const bf16x8*)&xbuf[(w*16+lr)*72 + 32 + lg*8];
    #pragma unroll
    for (int nt=0;nt<4;nt++){
      f32x4 os = (f32x4){0.f,0.f,0.f,0.f};
      f32x4 od = (f32x4){0.f,0.f,0.f,0.f};
      bf16x8 bs0 = *(const bf16x8*)&wsb[(nt*16+lr)*72 + lg*8];
      bf16x8 bs1 = *(const bf16x8*)&wsb[(nt*16+lr)*72 + 32 + lg*8];
      bf16x8 bd0 = *(const bf16x8*)&wdb[(nt*16+lr)*72 + lg*8];
      bf16x8 bd1 = *(const bf16x8*)&wdb[(nt*16+lr)*72 + 32 + lg*8];
      os = __builtin_amdgcn_mfma_f32_16x16x32_bf16(a0, bs0, os, 0, 0, 0);
      os = __builtin_amdgcn_mfma_f32_16x16x32_bf16(a1, bs1, os, 0, 0, 0);
      od = __builtin_amdgcn_mfma_f32_16x16x32_bf16(a0, bd0, od, 0, 0, 0);
      od = __builtin_amdgcn_mfma_f32_16x16x32_bf16(a1, bd1, od, 0, 0, 0);
      #pragma unroll
      for (int r=0;r<4;r++){
        size_t row = (size_t)(n0+w)*16 + lg*4 + r;
        vs[row*64 + nt*16 + lr] = (__bf16)os[r];
        vd[row*64 + nt*16 + lr] = (__bf16)od[r];
      }
    }
  }
}

// ---------- edge RBF + 2-layer MLP via MFMA: 64 edges/block, grid 1500x256 ----------
__global__ void __launch_bounds__(256) k_edgeA(const float* __restrict__ pos, const int* __restrict__ ei,
                        const float* __restrict__ W1, const float* __restrict__ b1,
                        const float* __restrict__ W2, const float* __restrict__ b2,
                        __bf16* __restrict__ e2g){
  __shared__ __bf16 W1T[48*264];   // [j][k] stride 264
  __shared__ __bf16 W2T[64*72];    // [j][k] stride 72 (k>=48 zero)
  __shared__ __bf16 e1s[64*72];    // [edge][k] stride 72 (k>=48 zeroed)
  __shared__ float dl[64], envl[64];
  int tid = threadIdx.x;
  int w = tid>>6, l = tid&63, lr = l&15, lg = l>>4;
  int eb = blockIdx.x*64;

  if (tid < 64){
    int s = ei[eb+tid], t = ei[EE+eb+tid];
    float dx = pos[3*s]-pos[3*t], dy = pos[3*s+1]-pos[3*t+1], dz = pos[3*s+2]-pos[3*t+2];
    float d = sqrtf(dx*dx+dy*dy+dz*dz+1e-12f);
    dl[tid] = d;
    envl[tid] = 0.5f*(cosf(PI_F*fminf(d*(1.0f/CUTOFF_R),1.0f))+1.0f);
  }
  for (int i=tid;i<48*128;i+=256){
    int kp = i/48, j = i - kp*48;
    bf16x2 p = {(__bf16)W1[(size_t)(2*kp)*48 + j], (__bf16)W1[(size_t)(2*kp+1)*48 + j]};
    *(bf16x2*)&W1T[j*264 + 2*kp] = p;
  }
  for (int i=tid;i<4096;i+=256){
    int k=i>>6, j=i&63;
    W2T[j*72+k] = (j<ECH && k<ECH) ? (__bf16)W2[(size_t)k*ECH+j] : (__bf16)0.f;
  }
  for (int i=tid;i<1024;i+=256){
    int r=i>>4, c=48+(i&15);
    e1s[r*72+c] = (__bf16)0.f;
  }
  __syncthreads();

  float d  = dl[w*16+lr];
  float ev = envl[w*16+lr];
  f32x4 acc[3];
  #pragma unroll
  for (int nt=0;nt<3;nt++) acc[nt] = (f32x4){0.f,0.f,0.f,0.f};
  #pragma unroll
  for (int c=0;c<8;c++){
    bf16x8 af;
    #pragma unroll
    for (int j=0;j<8;j++){
      float kk = (float)(c*32 + lg*8 + j);
      float del = (d - kk*SPACING)*INV_STD;
      af[j] = (__bf16)(exp2f(-0.72134752f*del*del)*ev);
    }
    #pragma unroll
    for (int nt=0;nt<3;nt++){
      bf16x8 bf_ = *(const bf16x8*)&W1T[(nt*16+lr)*264 + c*32 + lg*8];
      acc[nt] = __builtin_amdgcn_mfma_f32_16x16x32_bf16(af, bf_, acc[nt], 0, 0, 0);
    }
  }
  #pragma unroll
  for (int nt=0;nt<3;nt++){
    int col = nt*16+lr;
    float bb = b1[col];
    #pragma unroll
    for (int r=0;r<4;r++){
      int row = w*16 + lg*4 + r;
      e1s[row*72+col] = (__bf16)silu_f(acc[nt][r] + bb);
    }
  }
  __syncthreads();

  bf16x8 a0 = *(const bf16x8*)&e1s[(w*16+lr)*72 + lg*8];
  bf16x8 a1 = *(const bf16x8*)&e1s[(w*16+lr)*72 + 32 + lg*8];
  #pragma unroll
  for (int nt=0;nt<3;nt++){
    f32x4 o = (f32x4){0.f,0.f,0.f,0.f};
    bf16x8 b0 = *(const bf16x8*)&W2T[(nt*16+lr)*72 + lg*8];
    bf16x8 b1f= *(const bf16x8*)&W2T[(nt*16+lr)*72 + 32 + lg*8];
    o = __builtin_amdgcn_mfma_f32_16x16x32_bf16(a0, b0, o, 0, 0, 0);
    o = __builtin_amdgcn_mfma_f32_16x16x32_bf16(a1, b1f, o, 0, 0, 0);
    int col = nt*16+lr;
    float bb = b2[col];
    #pragma unroll
    for (int r=0;r<4;r++){
      int row = w*16 + lg*4 + r;
      e2g[(size_t)(eb+row)*ECH + col] = (__bf16)silu_f(o[r] + bb);
    }
  }
}

// ---------- CSR build ----------
__global__ void k_hist(const int* __restrict__ ei, int* __restrict__ deg){
  int e = blockIdx.x*256 + threadIdx.x;
  atomicAdd(&deg[ei[EE+e]], 1);
}

__global__ void __launch_bounds__(1024) k_scan(const int* __restrict__ deg, int* __restrict__ off){
  __shared__ int sums[1024];
  int t = threadIdx.x;
  int base = t*8;
  int loc[8]; int s=0;
  #pragma unroll
  for (int i=0;i<8;i++){ int idx=base+i; int v = (idx<NN)? deg[idx]:0; loc[i]=v; s+=v; }
  sums[t]=s;
  __syncthreads();
  for (int d=1; d<1024; d<<=1){
    int v = (t>=d)? sums[t-d]:0;
    __syncthreads();
    sums[t] += v;
    __syncthreads();
  }
  int run = sums[t]-s;
  #pragma unroll
  for (int i=0;i<8;i++){ int idx=base+i; if (idx<NN) off[idx]=run; run+=loc[i]; }
  if (t==1023) off[NN]=sums[1023];
}

__global__ void k_fill(const int* __restrict__ ei, const int* __restrict__ off,
                       int* __restrict__ cursor, int* __restrict__ csr){
  int e = blockIdx.x*256 + threadIdx.x;
  int d = ei[EE+e];
  int slot = off[d] + atomicAdd(&cursor[d],1);
  csr[slot]=e;
}

// ---------- per-edge MFMA: s0 = (e2@We)*(xs0[s]+xd0[d]); logits = lrelu(s0@Wa)·va; v0 = s0@Wv
// 64 edges/block, 4 waves. grid 1500x256
__global__ void __launch_bounds__(256) k_edgeB(const __bf16* __restrict__ e2g, const int* __restrict__ ei,
                        const float* __restrict__ xs0, const float* __restrict__ xd0,
                        const float* __restrict__ W_edge, const float* __restrict__ W_alpha,
                        const float* __restrict__ v_alpha, const float* __restrict__ Wv,
                        float* __restrict__ logits_g, __bf16* __restrict__ v0g){
  __shared__ __bf16 e2s[64*72];
  __shared__ __bf16 s0s[64*72];
  __shared__ __bf16 wbuf[128*72];
  __shared__ float  va_l[256];
  __shared__ int    srcd[128];
  int tid = threadIdx.x;
  int w = tid >> 6, l = tid & 63;
  int lr = l & 15, lg = l >> 4;
  int eb = blockIdx.x * 64;

  for (int i=tid;i<4096;i+=256){
    int r=i>>6, k=i&63;
    e2s[r*72+k] = (k<ECH) ? e2g[(size_t)(eb+r)*ECH+k] : (__bf16)0.f;
  }
  for (int i=tid;i<4096;i+=256){
    int k=i>>6, c=i&63;
    wbuf[c*72+k] = (k<ECH) ? (__bf16)W_edge[(size_t)k*64+c] : (__bf16)0.f;
  }
  va_l[tid] = v_alpha[tid];
  if (tid<64){ srcd[tid]=ei[eb+tid]; srcd[64+tid]=ei[EE+eb+tid]; }
  __syncthreads();

  bf16x8 ea0 = *(const bf16x8*)&e2s[(w*16+lr)*72 + lg*8];
  bf16x8 ea1 = *(const bf16x8*)&e2s[(w*16+lr)*72 + 32 + lg*8];
  f32x4 sacc[4];
  #pragma unroll
  for (int nt=0;nt<4;nt++){
    sacc[nt] = (f32x4){0.f,0.f,0.f,0.f};
    bf16x8 b0 = *(const bf16x8*)&wbuf[(nt*16+lr)*72 + lg*8];
    bf16x8 b1 = *(const bf16x8*)&wbuf[(nt*16+lr)*72 + 32 + lg*8];
    sacc[nt] = __builtin_amdgcn_mfma_f32_16x16x32_bf16(ea0, b0, sacc[nt], 0, 0, 0);
    sacc[nt] = __builtin_amdgcn_mfma_f32_16x16x32_bf16(ea1, b1, sacc[nt], 0, 0, 0);
  }
  #pragma unroll
  for (int reg=0;reg<4;reg++){
    int localrow = w*16 + lg*4 + reg;
    int sI = srcd[localrow], dI = srcd[64+localrow];
    #pragma unroll
    for (int nt=0;nt<4;nt++){
      int col = nt*16 + lr;
      float m = xs0[(size_t)sI*64+col] + xd0[(size_t)dI*64+col];
      s0s[localrow*72+col] = (__bf16)(sacc[nt][reg]*m);
    }
  }
  __syncthreads();

  bf16x8 sa0 = *(const bf16x8*)&s0s[(w*16+lr)*72 + lg*8];
  bf16x8 sa1 = *(const bf16x8*)&s0s[(w*16+lr)*72 + 32 + lg*8];

  #pragma unroll
  for (int half=0;half<2;half++){
    for (int i=tid;i<8192;i+=256){
      int k=i>>7, j=i&127;
      wbuf[j*72+k] = (__bf16)W_alpha[(size_t)k*256 + half*128 + j];
    }
    __syncthreads();
    float lg0[4]={0.f,0.f,0.f,0.f}, lg1[4]={0.f,0.f,0.f,0.f};
    #pragma unroll
    for (int nt=0;nt<8;nt++){
      f32x4 tacc = (f32x4){0.f,0.f,0.f,0.f};
      bf16x8 b0 = *(const bf16x8*)&wbuf[(nt*16+lr)*72 + lg*8];
      bf16x8 b1 = *(const bf16x8*)&wbuf[(nt*16+lr)*72 + 32 + lg*8];
      tacc = __builtin_amdgcn_mfma_f32_16x16x32_bf16(sa0, b0, tacc, 0, 0, 0);
      tacc = __builtin_amdgcn_mfma_f32_16x16x32_bf16(sa1, b1, tacc, 0, 0, 0);
      int gj = half*128 + nt*16 + lr;
      float vaj = va_l[gj];
      #pragma unroll
      for (int reg=0;reg<4;reg++){
        float t = tacc[reg];
        t = (t>0.0f) ? t : 0.2f*t;
        if (nt<4) lg0[reg] += t*vaj; else lg1[reg] += t*vaj;
      }
    }
    #pragma unroll
    for (int reg=0;reg<4;reg++){
      #pragma unroll
      for (int m=1;m<16;m<<=1){
        lg0[reg] += __shfl_xor(lg0[reg], m);
        lg1[reg] += __shfl_xor(lg1[reg], m);
      }
    }
    if (lr==0){
      #pragma unroll
      for (int reg=0;reg<4;reg++){
        int e = eb + w*16 + lg*4 + reg;
        logits_g[(size_t)e*4 + half*2 + 0] = lg0[reg];
        logits_g[(size_t)e*4 + half*2 + 1] = lg1[reg];
      }
    }
    __syncthreads();
  }

  for (int i=tid;i<4096;i+=256){
    int k=i>>6, c=i&63;
    wbuf[c*72+k] = (__bf16)Wv[(size_t)k*64+c];
  }
  __syncthreads();
  #pragma unroll
  for (int nt=0;nt<4;nt++){
    f32x4 vacc = (f32x4){0.f,0.f,0.f,0.f};
    bf16x8 b0 = *(const bf16x8*)&wbuf[(nt*16+lr)*72 + lg*8];
    bf16x8 b1 = *(const bf16x8*)&wbuf[(nt*16+lr)*72 + 32 + lg*8];
    vacc = __builtin_amdgcn_mfma_f32_16x16x32_bf16(sa0, b0, vacc, 0, 0, 0);
    vacc = __builtin_amdgcn_mfma_f32_16x16x32_bf16(sa1, b1, vacc, 0, 0, 0);
    #pragma unroll
    for (int reg=0;reg<4;reg++){
      int e = eb + w*16 + lg*4 + reg;
      v0g[(size_t)e*64 + nt*16 + lr] = (__bf16)vacc[reg];
    }
  }
}

// ---------- gather-only: softmax + bf16 gather -> agg (1 node/block, grid 8000) ----------
__global__ void __launch_bounds__(256) k_gather(const int* __restrict__ off, const int* __restrict__ csr,
                       const int* __restrict__ ei,
                       const float* __restrict__ logits_g, const __bf16* __restrict__ v0g,
                       const __bf16* __restrict__ vs, const __bf16* __restrict__ vd,
                       __bf16* __restrict__ agg){
  __shared__ float alph[MAXDEG*HH];
  __shared__ int   eidl[MAXDEG];
  __shared__ int   srcl[MAXDEG];
  __shared__ float salpha[HH];
  int tid = threadIdx.x;
  int n = blockIdx.x;
  int o0 = off[n];
  int deg = off[n+1]-o0;
  if (deg > MAXDEG) deg = MAXDEG;
  if (tid < deg){
    int e = csr[o0+tid];
    eidl[tid]=e;
    srcl[tid]=ei[e];
    float4 lgv = *(const float4*)(logits_g + (size_t)e*4);
    float* ap = &alph[tid*4];
    ap[0]=lgv.x; ap[1]=lgv.y; ap[2]=lgv.z; ap[3]=lgv.w;
  }
  __syncthreads();
  if (tid < 64){
    int h = tid>>4, i0 = tid&15;
    float m = -1e30f;
    for (int i=i0;i<deg;i+=16) m = fmaxf(m, alph[i*4+h]);
    #pragma unroll
    for (int s=1;s<16;s<<=1) m = fmaxf(m, __shfl_xor(m, s));
    float ds = 0.0f;
    for (int i=i0;i<deg;i+=16){
      float wv = expf(alph[i*4+h]-m);
      alph[i*4+h]=wv; ds += wv;
    }
    #pragma unroll
    for (int s=1;s<16;s<<=1) ds += __shfl_xor(ds, s);
    float inv = 1.0f/(ds+1e-9f);
    for (int i=i0;i<deg;i+=16) alph[i*4+h] *= inv;
    if (i0==0) salpha[h] = ds*inv;
  }
  __syncthreads();
  // gather: thread owns (l = tid>>4, quad = tid&15); unroll x2 for MLP
  {
    int l = tid>>4, quad = tid&15;
    int h = quad>>2;
    float a0=0.f,a1=0.f,a2=0.f,a3=0.f;
    if (l==0){
      int i=0;
      for (;i+1<deg;i+=2){
        float aA = alph[i*4+h], aB = alph[(i+1)*4+h];
        bf16x4 vA = *(const bf16x4*)(v0g + (size_t)eidl[i]*64 + quad*4);
        bf16x4 vB = *(const bf16x4*)(v0g + (size_t)eidl[i+1]*64 + quad*4);
        a0 += aA*(float)vA[0] + aB*(float)vB[0];
        a1 += aA*(float)vA[1] + aB*(float)vB[1];
        a2 += aA*(float)vA[2] + aB*(float)vB[2];
        a3 += aA*(float)vA[3] + aB*(float)vB[3];
      }
      if (i<deg){
        float a = alph[i*4+h];
        bf16x4 vv = *(const bf16x4*)(v0g + (size_t)eidl[i]*64 + quad*4);
        a0 += a*(float)vv[0]; a1 += a*(float)vv[1]; a2 += a*(float)vv[2]; a3 += a*(float)vv[3];
      }
    } else {
      int i=0;
      for (;i+1<deg;i+=2){
        float aA = alph[i*4+h], aB = alph[(i+1)*4+h];
        bf16x4 vA = *(const bf16x4*)(vs + (size_t)srcl[i]*1024 + tid*4);
        bf16x4 vB = *(const bf16x4*)(vs + (size_t)srcl[i+1]*1024 + tid*4);
        a0 += aA*(float)vA[0] + aB*(float)vB[0];
        a1 += aA*(float)vA[1] + aB*(float)vB[1];
        a2 += aA*(float)vA[2] + aB*(float)vB[2];
        a3 += aA*(float)vA[3] + aB*(float)vB[3];
      }
      if (i<deg){
        float a = alph[i*4+h];
        bf16x4 vv = *(const bf16x4*)(vs + (size_t)srcl[i]*1024 + tid*4);
        a0 += a*(float)vv[0]; a1 += a*(float)vv[1]; a2 += a*(float)vv[2]; a3 += a*(float)vv[3];
      }
      float sa = salpha[h];
      bf16x4 vv = *(const bf16x4*)(vd + (size_t)n*1024 + tid*4);
      a0 += sa*(float)vv[0]; a1 += sa*(float)vv[1]; a2 += sa*(float)vv[2]; a3 += sa*(float)vv[3];
    }
    bf16x4 t = {(__bf16)a0,(__bf16)a1,(__bf16)a2,(__bf16)a3};
    *(bf16x4*)(agg + (size_t)n*1024 + tid*4) = t;
  }
}

// ---------- Wo + residual + rms + gated FFN + out (4 nodes/block, grid 2000) ----------
__global__ void __launch_bounds__(256) k_woffn(const __bf16* __restrict__ agg,
                       const float* __restrict__ x, const float* __restrict__ Wo,
                       const float* __restrict__ Wg, const float* __restrict__ Wh,
                       const float* __restrict__ Wf, float* __restrict__ out){
  __shared__ __bf16 wbuf[64*72];         // 9216B: WoT -> WhT.h -> WfT.h (rotating)
  __shared__ __bf16 aggyb[64*72];        // 9216B: agg -> ybuf
  __shared__ __bf16 hbuf[64*72];         // 9216B
  __shared__ float  gl[512];             // 2048B
  int tid = threadIdx.x;
  int w = tid>>6, lane = tid&63, lr = lane&15, lg = lane>>4;
  int n0 = blockIdx.x*4;

  // ---- phase 1: stage WoT + load agg tile ----
  for (int i=tid;i<4096;i+=256){
    int k=i>>6, c=i&63;
    wbuf[c*72+k] = (__bf16)Wo[i];
  }
  for (int i=tid;i<512;i+=256){
    bf16x8 v = *(const bf16x8*)(agg + (size_t)n0*1024 + i*8);
    *(bf16x8*)&aggyb[(i>>3)*72 + (i&7)*8] = v;
  }
  __syncthreads();

  // ---- phase 2: x1 = x + agg@Wo (regs), wave w = node w; rms (wave-local) ----
  f32x4 x1r[4];
  float scl_w;
  {
    bf16x8 a0 = *(const bf16x8*)&aggyb[(w*16+lr)*72 + lg*8];
    bf16x8 a1 = *(const bf16x8*)&aggyb[(w*16+lr)*72 + 32 + lg*8];
    const float* xr = x + (size_t)(n0+w)*1024;
    float ss = 0.0f;
    #pragma unroll
    for (int nt=0;nt<4;nt++){
      f32x4 o = (f32x4){0.f,0.f,0.f,0.f};
      bf16x8 b0 = *(const bf16x8*)&wbuf[(nt*16+lr)*72 + lg*8];
      bf16x8 b1 = *(const bf16x8*)&wbuf[(nt*16+lr)*72 + 32 + lg*8];
      o = __builtin_amdgcn_mfma_f32_16x16x32_bf16(a0, b0, o, 0, 0, 0);
      o = __builtin_amdgcn_mfma_f32_16x16x32_bf16(a1, b1, o, 0, 0, 0);
      #pragma unroll
      for (int r=0;r<4;r++){
        float xv = xr[(lg*4+r)*64 + nt*16 + lr] + o[r];
        o[r] = xv;
        ss += xv*xv;
      }
      x1r[nt] = o;
    }
    #pragma unroll
    for (int m=32;m>=1;m>>=1) ss += __shfl_xor(ss, m);
    scl_w = 1.0f/sqrtf(ss*(1.0f/1024.0f)+1e-6f);
  }
  __syncthreads();   // aggyb + wbuf consumed

  // ---- phase 3: ybuf = bf16(x1*scl) into aggyb ----
  #pragma unroll
  for (int nt=0;nt<4;nt++){
    #pragma unroll
    for (int r=0;r<4;r++){
      aggyb[(w*16+lg*4+r)*72 + nt*16+lr] = (__bf16)(x1r[nt][r]*scl_w);
    }
  }
  __syncthreads();

  // ---- phase 3b: gate ----
  {
    int c = tid&127, half = tid>>7;
    #pragma unroll
    for (int q=0;q<2;q++){
      int nd = half*2+q;
      float acc = 0.0f;
      #pragma unroll 8
      for (int k=0;k<64;k++) acc += (float)aggyb[(nd*16)*72 + k] * Wg[k*128+c];
      gl[nd*128+c] = silu_f(acc);
    }
  }

  // ---- phases 4-5: FFN in two halves ----
  f32x4 o2[4];
  #pragma unroll
  for (int nt=0;nt<4;nt++) o2[nt] = (f32x4){0.f,0.f,0.f,0.f};
  #pragma unroll
  for (int hf=0; hf<2; hf++){
    __syncthreads();
    for (int i=tid;i<4096;i+=256){
      int k=i>>6, j=i&63;
      wbuf[j*72+k] = (__bf16)Wh[(size_t)k*128 + hf*64 + j];
    }
    __syncthreads();
    {
      bf16x8 a0 = *(const bf16x8*)&aggyb[(w*16+lr)*72 + lg*8];
      bf16x8 a1 = *(const bf16x8*)&aggyb[(w*16+lr)*72 + 32 + lg*8];
      #pragma unroll
      for (int nt=0;nt<4;nt++){
        f32x4 o = (f32x4){0.f,0.f,0.f,0.f};
        bf16x8 b0 = *(const bf16x8*)&wbuf[(nt*16+lr)*72 + lg*8];
        bf16x8 b1 = *(const bf16x8*)&wbuf[(nt*16+lr)*72 + 32 + lg*8];
        o = __builtin_amdgcn_mfma_f32_16x16x32_bf16(a0, b0, o, 0, 0, 0);
        o = __builtin_amdgcn_mfma_f32_16x16x32_bf16(a1, b1, o, 0, 0, 0);
        int col = nt*16+lr;
        float g = gl[w*128 + hf*64 + col];
        #pragma unroll
        for (int r=0;r<4;r++){
          hbuf[(w*16+lg*4+r)*72 + col] = (__bf16)(o[r]*g);
        }
      }
    }
    __syncthreads();
    for (int i=tid;i<4096;i+=256){
      int k=i>>6, j=i&63;
      wbuf[j*72+k] = (__bf16)Wf[(size_t)(hf*64+k)*64 + j];
    }
    __syncthreads();
    {
      bf16x8 a0 = *(const bf16x8*)&hbuf[(w*16+lr)*72 + lg*8];
      bf16x8 a1 = *(const bf16x8*)&hbuf[(w*16+lr)*72 + 32 + lg*8];
      #pragma unroll
      for (int nt=0;nt<4;nt++){
        bf16x8 b0 = *(const bf16x8*)&wbuf[(nt*16+lr)*72 + lg*8];
        bf16x8 b1 = *(const bf16x8*)&wbuf[(nt*16+lr)*72 + 32 + lg*8];
        o2[nt] = __builtin_amdgcn_mfma_f32_16x16x32_bf16(a0, b0, o2[nt], 0, 0, 0);
        o2[nt] = __builtin_amdgcn_mfma_f32_16x16x32_bf16(a1, b1, o2[nt], 0, 0, 0);
      }
    }
  }

  // ---- final store: out = x1 + o2 ----
  {
    float* outr = out + (size_t)(n0+w)*1024;
    #pragma unroll
    for (int nt=0;nt<4;nt++){
      #pragma unroll
      for (int r=0;r<4;r++){
        outr[(lg*4+r)*64 + nt*16+lr] = x1r[nt][r] + o2[nt][r];
      }
    }
  }
}

extern "C" void kernel_launch(void* const* d_in, const int* in_sizes, int n_in,
                              void* d_out, int out_size, void* d_ws, size_t ws_size,
                              hipStream_t stream) {
  (void)in_sizes; (void)n_in; (void)out_size; (void)ws_size;
  const float* pos = (const float*)d_in[0];
  const float* x   = (const float*)d_in[1];
  const float* Wsrc= (const float*)d_in[2];
  const float* Wdst= (const float*)d_in[3];
  const float* W1  = (const float*)d_in[4];
  const float* b1  = (const float*)d_in[5];
  const float* W2  = (const float*)d_in[6];
  const float* b2  = (const float*)d_in[7];
  const float* We  = (const float*)d_in[8];
  const float* Wa  = (const float*)d_in[9];
  const float* va  = (const float*)d_in[10];
  const float* Wv  = (const float*)d_in[11];
  const float* Wo  = (const float*)d_in[12];
  const float* Wg  = (const float*)d_in[13];
  const float* Wh  = (const float*)d_in[14];
  const float* Wf  = (const float*)d_in[15];
  const int*   ei  = (const int*)d_in[16];
  float* out = (float*)d_out;

  char* wp = (char*)d_ws;
  auto alloc = [&](size_t bytes)->char*{
    char* p = wp;
    wp += ((bytes + 255)/256)*256;
    return p;
  };
  __bf16* wsv = (__bf16*)alloc(4096*2);
  __bf16* wdv = (__bf16*)alloc(4096*2);
  float* xs0  = (float*)alloc((size_t)NN*64*4);
  float* xd0  = (float*)alloc((size_t)NN*64*4);
  __bf16* vs  = (__bf16*)alloc((size_t)NN*1024*2);
  __bf16* vd  = (__bf16*)alloc((size_t)NN*1024*2);
  __bf16* agg = (__bf16*)alloc((size_t)NN*1024*2);
  __bf16* e2g = (__bf16*)alloc((size_t)EE*ECH*2);
  __bf16* v0g = (__bf16*)alloc((size_t)EE*64*2);
  float* lgts = (float*)alloc((size_t)EE*HH*4);
  int* deg    = (int*)alloc((size_t)NN*4);
  int* cursor = (int*)alloc((size_t)NN*4);
  int* off    = (int*)alloc((size_t)(NN+1)*4);
  int* csr    = (int*)alloc((size_t)EE*4);

  hipMemsetAsync(deg, 0, NN*sizeof(int), stream);
  hipMemsetAsync(cursor, 0, NN*sizeof(int), stream);

  k_fusew<<<32,256,0,stream>>>(Wsrc,Wdst,Wv,wsv,wdv);
  k_pre<<<NN/4,256,0,stream>>>(x,Wsrc,Wdst,wsv,wdv,xs0,xd0,vs,vd);
  k_edgeA<<<EE/64,256,0,stream>>>(pos,ei,W1,b1,W2,b2,e2g);
  k_hist<<<EE/256,256,0,stream>>>(ei,deg);
  k_scan<<<1,1024,0,stream>>>(deg,off);
  k_fill<<<EE/256,256,0,stream>>>(ei,off,cursor,csr);
  k_edgeB<<<EE/64,256,0,stream>>>(e2g,ei,xs0,xd0,We,Wa,va,Wv,lgts,v0g);
  k_gather<<<NN,256,0,stream>>>(off,csr,ei,lgts,v0g,vs,vd,agg);
  k_woffn<<<NN/4,256,0,stream>>>(agg,x,Wo,Wg,Wh,Wf,out);
}